// Round 1
// baseline (1852.125 us; speedup 1.0000x reference)
//
#include <hip/hip_runtime.h>

#define H 64
#define W 128
#define P 8192        // H*W
#define DD 81
#define NS 663552     // DD*P
#define C1 96
#define C2 128
#define C3 64
#define EPSF 1e-5f

// ---- workspace layout (float offsets unless noted) ----
#define S1SUM 0
#define S1SSQ 96
#define S2SUM 192
#define S2SSQ 320
#define S3SUM 448
#define S3SSQ 512
#define S1S 576
#define S1T 672
#define S2S 768
#define S2T 896
#define S3S 1024
#define S3T 1088
#define STATS_FLOATS 2048
#define A_OFF 2048
#define G_OFF (A_OFF + P * C1)
#define W2T_OFF (G_OFF + P * C1)
#define W3T_OFF (W2T_OFF + C1 * C2)
#define COST_OFF (W3T_OFF + C2 * C3)
#define FLOAT_END (COST_OFF + NS)
#define Y2_BYTE ((size_t)FLOAT_END * 4)
#define Y3_BYTE (Y2_BYTE + (size_t)NS * C2 * 2)
#define WS_NEEDED (Y3_BYTE + (size_t)NS * C3 * 2)

__device__ __forceinline__ unsigned short f2bf(float f) {
  unsigned u = __float_as_uint(f);
  return (unsigned short)((u + 0x7fffu + ((u >> 16) & 1u)) >> 16);
}

struct Tap4 { int o[4]; float w[4]; };

__device__ __forceinline__ Tap4 make_taps(float cx, float cy) {
  Tap4 tp;
  float x0f = floorf(cx), y0f = floorf(cy);
  float fx = cx - x0f, fy = cy - y0f;
  int ix0 = (int)x0f, iy0 = (int)y0f;
  int ix1 = ix0 + 1, iy1 = iy0 + 1;
  float vx0 = (ix0 >= 0 && ix0 < W) ? 1.f : 0.f;
  float vx1 = (ix1 >= 0 && ix1 < W) ? 1.f : 0.f;
  float vy0 = (iy0 >= 0 && iy0 < H) ? 1.f : 0.f;
  float vy1 = (iy1 >= 0 && iy1 < H) ? 1.f : 0.f;
  int cx0 = min(max(ix0, 0), W - 1), cx1 = min(max(ix1, 0), W - 1);
  int cy0 = min(max(iy0, 0), H - 1), cy1 = min(max(iy1, 0), H - 1);
  tp.w[0] = (1.f - fy) * (1.f - fx) * vy0 * vx0;
  tp.w[1] = (1.f - fy) * fx * vy0 * vx1;
  tp.w[2] = fy * (1.f - fx) * vy1 * vx0;
  tp.w[3] = fy * fx * vy1 * vx1;
  tp.o[0] = (cy0 * W + cx0) * C1;
  tp.o[1] = (cy0 * W + cx1) * C1;
  tp.o[2] = (cy1 * W + cx0) * C1;
  tp.o[3] = (cy1 * W + cx1) * C1;
  return tp;
}

__device__ __forceinline__ void red16v(float& v) {
  v += __shfl_xor(v, 4);
  v += __shfl_xor(v, 8);
  v += __shfl_xor(v, 16);
  v += __shfl_xor(v, 32);
}

// a = w1[:, :128] @ f1, g = w1[:, 128:] @ f2   (both stored pixel-major [p][c1])
__global__ __launch_bounds__(256) void k_prep(const float* __restrict__ f1,
                                              const float* __restrict__ f2,
                                              const float* __restrict__ w1,
                                              float* __restrict__ ws) {
  __shared__ float tile[128][64];
  int t = threadIdx.x;
  int p0 = blockIdx.x * 64;
  int px = t & 63, q = t >> 6;
  int c0 = q * 24;
  for (int pass = 0; pass < 2; ++pass) {
    const float* src = pass ? f2 : f1;
    float* dst = ws + (pass ? G_OFF : A_OFF);
    int koff = pass ? 128 : 0;
    __syncthreads();
    for (int idx = t; idx < 8192; idx += 256) {
      int kk = idx >> 6, xx = idx & 63;
      tile[kk][xx] = src[kk * P + p0 + xx];
    }
    __syncthreads();
    float acc[24];
#pragma unroll
    for (int i = 0; i < 24; ++i) acc[i] = 0.f;
    for (int kk = 0; kk < 128; ++kk) {
      float fv = tile[kk][px];
#pragma unroll
      for (int i = 0; i < 24; ++i)
        acc[i] += w1[(c0 + i) * 256 + koff + kk] * fv;
    }
    float* orow = dst + (size_t)(p0 + px) * C1 + c0;
#pragma unroll
    for (int i = 0; i < 24; i += 4)
      *(float4*)(orow + i) = make_float4(acc[i], acc[i + 1], acc[i + 2], acc[i + 3]);
  }
}

__global__ void k_transpose(const float* __restrict__ w2, const float* __restrict__ w3,
                            float* __restrict__ ws) {
  int idx = blockIdx.x * blockDim.x + threadIdx.x;
  int total = C1 * C2 + C2 * C3;
  for (; idx < total; idx += gridDim.x * blockDim.x) {
    if (idx < C1 * C2) {
      int c = idx >> 7, o = idx & 127;
      ws[W2T_OFF + c * C2 + o] = w2[o * C1 + c];
    } else {
      int r = idx - C1 * C2;
      int c = r >> 6, o = r & 63;
      ws[W3T_OFF + c * C3 + o] = w3[o * C2 + c];
    }
  }
}

// per-channel sum/sumsq of y1 = a + bilinear(g)
__global__ __launch_bounds__(256) void k_stats1(const float* __restrict__ coords,
                                                float* __restrict__ ws) {
  int t = threadIdx.x;
  int cg = t & 3, ch0 = cg * 24;
  int slane = blockIdx.x * 64 + (t >> 2);
  float4 sum[6], ssq[6];
#pragma unroll
  for (int i = 0; i < 6; ++i) { sum[i] = make_float4(0, 0, 0, 0); ssq[i] = make_float4(0, 0, 0, 0); }
  for (int it = 0; it < 16; ++it) {
    int n = slane + it * 41472;
    int k = n >> 13, p = n & 8191;
    float cx = coords[p] + (float)(k / 9) - 4.0f;
    float cy = coords[P + p] + (float)(k % 9) - 4.0f;
    Tap4 tp = make_taps(cx, cy);
    const float4* a4 = (const float4*)(ws + A_OFF + (size_t)p * C1 + ch0);
    const float4* g0 = (const float4*)(ws + G_OFF + tp.o[0] + ch0);
    const float4* g1 = (const float4*)(ws + G_OFF + tp.o[1] + ch0);
    const float4* g2 = (const float4*)(ws + G_OFF + tp.o[2] + ch0);
    const float4* g3 = (const float4*)(ws + G_OFF + tp.o[3] + ch0);
    float w0 = tp.w[0], w1v = tp.w[1], w2v = tp.w[2], w3v = tp.w[3];
#pragma unroll
    for (int i = 0; i < 6; ++i) {
      float4 av = a4[i], q0 = g0[i], q1 = g1[i], q2 = g2[i], q3 = g3[i];
      float yx = av.x + w0 * q0.x + w1v * q1.x + w2v * q2.x + w3v * q3.x;
      float yy = av.y + w0 * q0.y + w1v * q1.y + w2v * q2.y + w3v * q3.y;
      float yz = av.z + w0 * q0.z + w1v * q1.z + w2v * q2.z + w3v * q3.z;
      float yw = av.w + w0 * q0.w + w1v * q1.w + w2v * q2.w + w3v * q3.w;
      sum[i].x += yx; ssq[i].x += yx * yx;
      sum[i].y += yy; ssq[i].y += yy * yy;
      sum[i].z += yz; ssq[i].z += yz * yz;
      sum[i].w += yw; ssq[i].w += yw * yw;
    }
  }
#pragma unroll
  for (int i = 0; i < 6; ++i) {
    red16v(sum[i].x); red16v(sum[i].y); red16v(sum[i].z); red16v(sum[i].w);
    red16v(ssq[i].x); red16v(ssq[i].y); red16v(ssq[i].z); red16v(ssq[i].w);
  }
  if ((t & 63) < 4) {
#pragma unroll
    for (int i = 0; i < 6; ++i) {
      atomicAdd(&ws[S1SUM + ch0 + i * 4 + 0], sum[i].x);
      atomicAdd(&ws[S1SUM + ch0 + i * 4 + 1], sum[i].y);
      atomicAdd(&ws[S1SUM + ch0 + i * 4 + 2], sum[i].z);
      atomicAdd(&ws[S1SUM + ch0 + i * 4 + 3], sum[i].w);
      atomicAdd(&ws[S1SSQ + ch0 + i * 4 + 0], ssq[i].x);
      atomicAdd(&ws[S1SSQ + ch0 + i * 4 + 1], ssq[i].y);
      atomicAdd(&ws[S1SSQ + ch0 + i * 4 + 2], ssq[i].z);
      atomicAdd(&ws[S1SSQ + ch0 + i * 4 + 3], ssq[i].w);
    }
  }
}

__global__ void k_finalize(float* __restrict__ ws, int sumO, int ssqO,
                           const float* __restrict__ gamma, const float* __restrict__ beta,
                           int sO, int tO, int C) {
  int c = threadIdx.x;
  if (c < C) {
    float mean = ws[sumO + c] * (1.0f / (float)NS);
    float var = ws[ssqO + c] * (1.0f / (float)NS) - mean * mean;
    float s = gamma[c] * rsqrtf(var + EPSF);
    ws[sO + c] = s;
    ws[tO + c] = beta[c] - mean * s;
  }
}

// layer2: build x1 tile (bn1+relu of recomputed y1), GEMM 128x128 <- W2 @ x1, stats of y2, store y2 bf16
__global__ __launch_bounds__(256) void k_layer2(const float* __restrict__ coords,
                                                float* __restrict__ ws,
                                                unsigned short* __restrict__ y2) {
  __shared__ float x1s[C1][128];   // 48KB
  __shared__ float red[1024];      // 4KB, aliased as tap scratch
  int* tapO = (int*)red;
  float* tapW = red + 512;
  int t = threadIdx.x;
  int b = blockIdx.x;
  int k = b >> 6, yrow = b & 63;
  int p0 = yrow * 128;
  int n0 = k * P + p0;
  if (t < 128) {
    int p = p0 + t;
    float cx = coords[p] + (float)(k / 9) - 4.0f;
    float cy = coords[P + p] + (float)(k % 9) - 4.0f;
    Tap4 tp = make_taps(cx, cy);
#pragma unroll
    for (int i = 0; i < 4; ++i) { tapO[t * 4 + i] = tp.o[i]; tapW[t * 4 + i] = tp.w[i]; }
  }
  __syncthreads();
  {
    int s = t >> 1;
    int ch0 = (t & 1) * 48;
    int p = p0 + s;
    float w0 = tapW[s * 4 + 0], w1v = tapW[s * 4 + 1], w2v = tapW[s * 4 + 2], w3v = tapW[s * 4 + 3];
    const float4* a4 = (const float4*)(ws + A_OFF + (size_t)p * C1 + ch0);
    const float4* g0 = (const float4*)(ws + G_OFF + tapO[s * 4 + 0] + ch0);
    const float4* g1 = (const float4*)(ws + G_OFF + tapO[s * 4 + 1] + ch0);
    const float4* g2 = (const float4*)(ws + G_OFF + tapO[s * 4 + 2] + ch0);
    const float4* g3 = (const float4*)(ws + G_OFF + tapO[s * 4 + 3] + ch0);
    const float4* s14 = (const float4*)(ws + S1S + ch0);
    const float4* t14 = (const float4*)(ws + S1T + ch0);
#pragma unroll
    for (int i = 0; i < 12; ++i) {
      float4 av = a4[i], q0 = g0[i], q1 = g1[i], q2 = g2[i], q3 = g3[i];
      float4 sc = s14[i], tc = t14[i];
      int c = ch0 + i * 4;
      x1s[c + 0][s] = fmaxf(0.f, sc.x * (av.x + w0 * q0.x + w1v * q1.x + w2v * q2.x + w3v * q3.x) + tc.x);
      x1s[c + 1][s] = fmaxf(0.f, sc.y * (av.y + w0 * q0.y + w1v * q1.y + w2v * q2.y + w3v * q3.y) + tc.y);
      x1s[c + 2][s] = fmaxf(0.f, sc.z * (av.z + w0 * q0.z + w1v * q1.z + w2v * q2.z + w3v * q3.z) + tc.z);
      x1s[c + 3][s] = fmaxf(0.f, sc.w * (av.w + w0 * q0.w + w1v * q1.w + w2v * q2.w + w3v * q3.w) + tc.w);
    }
  }
  __syncthreads();
  int tm = t & 15, ts = t >> 4;
  int o0 = tm * 8, s0 = ts * 8;
  float acc[8][8];
#pragma unroll
  for (int i = 0; i < 8; ++i)
#pragma unroll
    for (int j = 0; j < 8; ++j) acc[i][j] = 0.f;
  const float* w2t = ws + W2T_OFF;
#pragma unroll 2
  for (int c = 0; c < C1; ++c) {
    float4 wa = *(const float4*)(w2t + c * C2 + o0);
    float4 wb = *(const float4*)(w2t + c * C2 + o0 + 4);
    float4 xa = *(const float4*)&x1s[c][s0];
    float4 xb = *(const float4*)&x1s[c][s0 + 4];
    float wv[8] = {wa.x, wa.y, wa.z, wa.w, wb.x, wb.y, wb.z, wb.w};
    float xv[8] = {xa.x, xa.y, xa.z, xa.w, xb.x, xb.y, xb.z, xb.w};
#pragma unroll
    for (int i = 0; i < 8; ++i)
#pragma unroll
      for (int j = 0; j < 8; ++j) acc[i][j] += wv[i] * xv[j];
  }
  float ssum[8], sssq[8];
#pragma unroll
  for (int i = 0; i < 8; ++i) { ssum[i] = 0.f; sssq[i] = 0.f; }
#pragma unroll
  for (int j = 0; j < 8; ++j) {
    unsigned short hv[8];
#pragma unroll
    for (int i = 0; i < 8; ++i) {
      float v = acc[i][j];
      ssum[i] += v; sssq[i] += v * v;
      hv[i] = f2bf(v);
    }
    uint4 pk;
    pk.x = (unsigned)hv[0] | ((unsigned)hv[1] << 16);
    pk.y = (unsigned)hv[2] | ((unsigned)hv[3] << 16);
    pk.z = (unsigned)hv[4] | ((unsigned)hv[5] << 16);
    pk.w = (unsigned)hv[6] | ((unsigned)hv[7] << 16);
    *(uint4*)(y2 + (size_t)(n0 + s0 + j) * C2 + o0) = pk;
  }
#pragma unroll
  for (int i = 0; i < 8; ++i) {
    ssum[i] += __shfl_xor(ssum[i], 16); ssum[i] += __shfl_xor(ssum[i], 32);
    sssq[i] += __shfl_xor(sssq[i], 16); sssq[i] += __shfl_xor(sssq[i], 32);
  }
  __syncthreads();
  int lane = t & 63, wvid = t >> 6;
  if (lane < 16) {
#pragma unroll
    for (int i = 0; i < 8; ++i) {
      red[wvid * 256 + lane * 16 + i] = ssum[i];
      red[wvid * 256 + lane * 16 + 8 + i] = sssq[i];
    }
  }
  __syncthreads();
  {
    int tm2 = t >> 4, v = t & 15;
    float tot = red[tm2 * 16 + v] + red[256 + tm2 * 16 + v] + red[512 + tm2 * 16 + v] + red[768 + tm2 * 16 + v];
    int ch = tm2 * 8 + (v & 7);
    atomicAdd(&ws[(v < 8 ? S2SUM : S2SSQ) + ch], tot);
  }
}

// layer3: x2 = bn2+relu(y2), y3 = W3 @ x2, stats of y3, store y3 bf16
__global__ __launch_bounds__(256) void k_layer3(const unsigned short* __restrict__ y2,
                                                float* __restrict__ ws,
                                                unsigned short* __restrict__ y3) {
  __shared__ float x2s[C2][64];    // 32KB (aliased as reduce scratch at the end)
  int t = threadIdx.x;
  int b = blockIdx.x;
  int k = b >> 7, tile = b & 127;
  int n0 = k * P + tile * 64;
  {
    int s = t & 63, ch0 = (t >> 6) * 32;
    const uint4* row = (const uint4*)(y2 + (size_t)(n0 + s) * C2 + ch0);
    const float* s2p = ws + S2S;
    const float* t2p = ws + S2T;
#pragma unroll
    for (int j = 0; j < 4; ++j) {
      uint4 v = row[j];
      unsigned arr[4] = {v.x, v.y, v.z, v.w};
#pragma unroll
      for (int e = 0; e < 4; ++e) {
        int c = ch0 + j * 8 + e * 2;
        float f0 = __uint_as_float((arr[e] & 0xffffu) << 16);
        float f1 = __uint_as_float(arr[e] & 0xffff0000u);
        x2s[c][s] = fmaxf(0.f, s2p[c] * f0 + t2p[c]);
        x2s[c + 1][s] = fmaxf(0.f, s2p[c + 1] * f1 + t2p[c + 1]);
      }
    }
  }
  __syncthreads();
  int tm = t & 15, ts = t >> 4;
  int o0 = tm * 4, s0 = ts * 4;
  float acc[4][4];
#pragma unroll
  for (int i = 0; i < 4; ++i)
#pragma unroll
    for (int j = 0; j < 4; ++j) acc[i][j] = 0.f;
  const float* w3t = ws + W3T_OFF;
#pragma unroll 4
  for (int c = 0; c < C2; ++c) {
    float4 wa = *(const float4*)(w3t + c * C3 + o0);
    float4 xa = *(const float4*)&x2s[c][s0];
    float wv[4] = {wa.x, wa.y, wa.z, wa.w};
    float xv[4] = {xa.x, xa.y, xa.z, xa.w};
#pragma unroll
    for (int i = 0; i < 4; ++i)
#pragma unroll
      for (int j = 0; j < 4; ++j) acc[i][j] += wv[i] * xv[j];
  }
  float ssum[4], sssq[4];
#pragma unroll
  for (int i = 0; i < 4; ++i) { ssum[i] = 0.f; sssq[i] = 0.f; }
#pragma unroll
  for (int j = 0; j < 4; ++j) {
    unsigned short hv[4];
#pragma unroll
    for (int i = 0; i < 4; ++i) {
      float v = acc[i][j];
      ssum[i] += v; sssq[i] += v * v;
      hv[i] = f2bf(v);
    }
    uint2 pk;
    pk.x = (unsigned)hv[0] | ((unsigned)hv[1] << 16);
    pk.y = (unsigned)hv[2] | ((unsigned)hv[3] << 16);
    *(uint2*)(y3 + (size_t)(n0 + s0 + j) * C3 + o0) = pk;
  }
#pragma unroll
  for (int i = 0; i < 4; ++i) {
    ssum[i] += __shfl_xor(ssum[i], 16); ssum[i] += __shfl_xor(ssum[i], 32);
    sssq[i] += __shfl_xor(sssq[i], 16); sssq[i] += __shfl_xor(sssq[i], 32);
  }
  __syncthreads();   // all x2s reads done before aliasing as reduce scratch
  float* red = (float*)x2s;
  int lane = t & 63, wvid = t >> 6;
  if (lane < 16) {
#pragma unroll
    for (int i = 0; i < 4; ++i) {
      red[wvid * 128 + lane * 8 + i] = ssum[i];
      red[wvid * 128 + lane * 8 + 4 + i] = sssq[i];
    }
  }
  __syncthreads();
  if (t < 128) {
    int tm2 = t >> 3, v = t & 7;
    float tot = red[tm2 * 8 + v] + red[128 + tm2 * 8 + v] + red[256 + tm2 * 8 + v] + red[384 + tm2 * 8 + v];
    int ch = tm2 * 4 + (v & 3);
    atomicAdd(&ws[(v < 4 ? S3SUM : S3SSQ) + ch], tot);
  }
}

// layer4: cost = w4 . relu(bn3(y3)) + b4
__global__ __launch_bounds__(256) void k_layer4(const unsigned short* __restrict__ y3,
                                                float* __restrict__ ws,
                                                const float* __restrict__ w4,
                                                const float* __restrict__ b4) {
  int n = blockIdx.x * 256 + threadIdx.x;
  const float* s3p = ws + S3S;
  const float* t3p = ws + S3T;
  const uint4* row = (const uint4*)(y3 + (size_t)n * C3);
  float acc = 0.f;
#pragma unroll
  for (int j = 0; j < 8; ++j) {
    uint4 v = row[j];
    unsigned arr[4] = {v.x, v.y, v.z, v.w};
#pragma unroll
    for (int e = 0; e < 4; ++e) {
      int c = j * 8 + e * 2;
      float f0 = __uint_as_float((arr[e] & 0xffffu) << 16);
      float f1 = __uint_as_float(arr[e] & 0xffff0000u);
      acc += fmaxf(0.f, s3p[c] * f0 + t3p[c]) * w4[c];
      acc += fmaxf(0.f, s3p[c + 1] * f1 + t3p[c + 1]) * w4[c + 1];
    }
  }
  ws[COST_OFF + n] = acc + b4[0];
}

// DAP: out[l,p] = sum_k wdap[l,k] * cost[k,p]
__global__ __launch_bounds__(256) void k_dap(const float* __restrict__ ws,
                                             const float* __restrict__ wdap,
                                             float* __restrict__ out) {
  __shared__ float wd[DD * DD];
  int t = threadIdx.x;
  for (int i = t; i < DD * DD; i += 256) wd[i] = wdap[i];
  __syncthreads();
  int p = blockIdx.x * 64 + (t & 63);
  int lg = t >> 6;
  const float* cost = ws + COST_OFF;
  float cr[81];
#pragma unroll
  for (int kk = 0; kk < 81; ++kk) cr[kk] = cost[kk * P + p];
  int l0 = lg * 21;
  int l1 = min(81, l0 + 21);
  for (int l = l0; l < l1; ++l) {
    float acc = 0.f;
#pragma unroll
    for (int kk = 0; kk < 81; ++kk) acc += wd[l * 81 + kk] * cr[kk];
    out[(size_t)l * P + p] = acc;
  }
}

__global__ void k_marker(float* out) { out[0] = 1.0e30f; }

extern "C" void kernel_launch(void* const* d_in, const int* in_sizes, int n_in,
                              void* d_out, int out_size, void* d_ws, size_t ws_size,
                              hipStream_t stream) {
  const float* f1 = (const float*)d_in[0];
  const float* f2 = (const float*)d_in[1];
  const float* coords = (const float*)d_in[2];
  const float* w1 = (const float*)d_in[3];
  const float* g1 = (const float*)d_in[4];
  const float* be1 = (const float*)d_in[5];
  const float* w2 = (const float*)d_in[6];
  const float* g2 = (const float*)d_in[7];
  const float* be2 = (const float*)d_in[8];
  const float* w3 = (const float*)d_in[9];
  const float* g3 = (const float*)d_in[10];
  const float* be3 = (const float*)d_in[11];
  const float* w4 = (const float*)d_in[12];
  const float* b4 = (const float*)d_in[13];
  const float* wdap = (const float*)d_in[14];
  float* out = (float*)d_out;
  float* ws = (float*)d_ws;

  if (ws_size < WS_NEEDED) {  // signal insufficient workspace distinctly
    k_marker<<<1, 1, 0, stream>>>(out);
    return;
  }
  unsigned short* y2 = (unsigned short*)((char*)d_ws + Y2_BYTE);
  unsigned short* y3 = (unsigned short*)((char*)d_ws + Y3_BYTE);

  hipMemsetAsync(d_ws, 0, STATS_FLOATS * 4, stream);
  k_prep<<<128, 256, 0, stream>>>(f1, f2, w1, ws);
  k_transpose<<<64, 256, 0, stream>>>(w2, w3, ws);
  k_stats1<<<648, 256, 0, stream>>>(coords, ws);
  k_finalize<<<1, 128, 0, stream>>>(ws, S1SUM, S1SSQ, g1, be1, S1S, S1T, C1);
  k_layer2<<<5184, 256, 0, stream>>>(coords, ws, y2);
  k_finalize<<<1, 128, 0, stream>>>(ws, S2SUM, S2SSQ, g2, be2, S2S, S2T, C2);
  k_layer3<<<10368, 256, 0, stream>>>(y2, ws, y3);
  k_finalize<<<1, 128, 0, stream>>>(ws, S3SUM, S3SSQ, g3, be3, S3S, S3T, C3);
  k_layer4<<<2592, 256, 0, stream>>>(y3, ws, w4, b4);
  k_dap<<<128, 256, 0, stream>>>(ws, wdap, out);
}

// Round 2
// 907.873 us; speedup vs baseline: 2.0401x; 2.0401x over previous
//
#include <hip/hip_runtime.h>

#define H 64
#define W 128
#define P 8192        // H*W
#define DD 81
#define NS 663552     // DD*P
#define C1 96
#define C2 128
#define C3 64
#define EPSF 1e-5f
#define NSLOT 128

// ---- workspace layout (float offsets unless noted) ----
// slot-replicated stats accumulators: [NSLOT][C]
#define S1SUM 0
#define S1SSQ (S1SUM + NSLOT * C1)          // 12288
#define S2SUM (S1SSQ + NSLOT * C1)          // 24576
#define S2SSQ (S2SUM + NSLOT * C2)          // 40960
#define S3SUM (S2SSQ + NSLOT * C2)          // 57344
#define S3SSQ (S3SUM + NSLOT * C3)          // 65536
#define STATS_ZERO_FLOATS (S3SSQ + NSLOT * C3)  // 73728
#define S1S 73728
#define S1T (S1S + C1)
#define S2S (S1T + C1)
#define S2T (S2S + C2)
#define S3S (S2T + C2)
#define S3T (S3S + C3)
#define A_OFF 81920
#define G_OFF (A_OFF + P * C1)
#define W2T_OFF (G_OFF + P * C1)
#define W3T_OFF (W2T_OFF + C1 * C2)
#define COST_OFF (W3T_OFF + C2 * C3)
#define FLOAT_END (COST_OFF + NS)
#define Y2_BYTE ((size_t)FLOAT_END * 4)
#define Y3_BYTE (Y2_BYTE + (size_t)NS * C2 * 2)
#define WS_NEEDED (Y3_BYTE + (size_t)NS * C3 * 2)

__device__ __forceinline__ unsigned short f2bf(float f) {
  unsigned u = __float_as_uint(f);
  return (unsigned short)((u + 0x7fffu + ((u >> 16) & 1u)) >> 16);
}

struct Tap4 { int o[4]; float w[4]; };

__device__ __forceinline__ Tap4 make_taps(float cx, float cy) {
  Tap4 tp;
  float x0f = floorf(cx), y0f = floorf(cy);
  float fx = cx - x0f, fy = cy - y0f;
  int ix0 = (int)x0f, iy0 = (int)y0f;
  int ix1 = ix0 + 1, iy1 = iy0 + 1;
  float vx0 = (ix0 >= 0 && ix0 < W) ? 1.f : 0.f;
  float vx1 = (ix1 >= 0 && ix1 < W) ? 1.f : 0.f;
  float vy0 = (iy0 >= 0 && iy0 < H) ? 1.f : 0.f;
  float vy1 = (iy1 >= 0 && iy1 < H) ? 1.f : 0.f;
  int cx0 = min(max(ix0, 0), W - 1), cx1 = min(max(ix1, 0), W - 1);
  int cy0 = min(max(iy0, 0), H - 1), cy1 = min(max(iy1, 0), H - 1);
  tp.w[0] = (1.f - fy) * (1.f - fx) * vy0 * vx0;
  tp.w[1] = (1.f - fy) * fx * vy0 * vx1;
  tp.w[2] = fy * (1.f - fx) * vy1 * vx0;
  tp.w[3] = fy * fx * vy1 * vx1;
  tp.o[0] = (cy0 * W + cx0) * C1;
  tp.o[1] = (cy0 * W + cx1) * C1;
  tp.o[2] = (cy1 * W + cx0) * C1;
  tp.o[3] = (cy1 * W + cx1) * C1;
  return tp;
}

// a = w1[:, :128] @ f1, g = w1[:, 128:] @ f2   (both stored pixel-major [p][c1])
__global__ __launch_bounds__(256) void k_prep(const float* __restrict__ f1,
                                              const float* __restrict__ f2,
                                              const float* __restrict__ w1,
                                              float* __restrict__ ws) {
  __shared__ float tile[128][64];
  int t = threadIdx.x;
  int p0 = blockIdx.x * 64;
  int px = t & 63, q = t >> 6;
  int c0 = q * 24;
  for (int pass = 0; pass < 2; ++pass) {
    const float* src = pass ? f2 : f1;
    float* dst = ws + (pass ? G_OFF : A_OFF);
    int koff = pass ? 128 : 0;
    __syncthreads();
    for (int idx = t; idx < 8192; idx += 256) {
      int kk = idx >> 6, xx = idx & 63;
      tile[kk][xx] = src[kk * P + p0 + xx];
    }
    __syncthreads();
    float acc[24];
#pragma unroll
    for (int i = 0; i < 24; ++i) acc[i] = 0.f;
    for (int kk = 0; kk < 128; ++kk) {
      float fv = tile[kk][px];
#pragma unroll
      for (int i = 0; i < 24; ++i)
        acc[i] += w1[(c0 + i) * 256 + koff + kk] * fv;
    }
    float* orow = dst + (size_t)(p0 + px) * C1 + c0;
#pragma unroll
    for (int i = 0; i < 24; i += 4)
      *(float4*)(orow + i) = make_float4(acc[i], acc[i + 1], acc[i + 2], acc[i + 3]);
  }
}

__global__ void k_transpose(const float* __restrict__ w2, const float* __restrict__ w3,
                            float* __restrict__ ws) {
  int idx = blockIdx.x * blockDim.x + threadIdx.x;
  int total = C1 * C2 + C2 * C3;
  for (; idx < total; idx += gridDim.x * blockDim.x) {
    if (idx < C1 * C2) {
      int c = idx >> 7, o = idx & 127;
      ws[W2T_OFF + c * C2 + o] = w2[o * C1 + c];
    } else {
      int r = idx - C1 * C2;
      int c = r >> 6, o = r & 63;
      ws[W3T_OFF + c * C3 + o] = w3[o * C2 + c];
    }
  }
}

// per-channel sum/sumsq of y1 = a + bilinear(g); one block = 128 pixels x 1 displacement
// k fastest in blockIdx -> resident blocks share a/g rows (L2-local gather)
__global__ __launch_bounds__(256) void k_stats1(const float* __restrict__ coords,
                                                float* __restrict__ ws) {
  __shared__ float m[96][129];   // padded transpose buffer, 49.5KB
  __shared__ float pr[2][96];
  int t = threadIdx.x;
  int b = blockIdx.x;
  int k = b % 81, ptile = b / 81;
  int s = t >> 1, hh = t & 1, ch0 = hh * 48;
  int p = ptile * 128 + s;
  float cx = coords[p] + (float)(k / 9) - 4.0f;
  float cy = coords[P + p] + (float)(k % 9) - 4.0f;
  Tap4 tp = make_taps(cx, cy);
  const float4* a4 = (const float4*)(ws + A_OFF + (size_t)p * C1 + ch0);
  const float4* g0 = (const float4*)(ws + G_OFF + tp.o[0] + ch0);
  const float4* g1 = (const float4*)(ws + G_OFF + tp.o[1] + ch0);
  const float4* g2 = (const float4*)(ws + G_OFF + tp.o[2] + ch0);
  const float4* g3 = (const float4*)(ws + G_OFF + tp.o[3] + ch0);
  float w0 = tp.w[0], w1v = tp.w[1], w2v = tp.w[2], w3v = tp.w[3];
  float4 y[12];
#pragma unroll
  for (int i = 0; i < 12; ++i) {
    float4 av = a4[i], q0 = g0[i], q1 = g1[i], q2 = g2[i], q3 = g3[i];
    y[i].x = av.x + w0 * q0.x + w1v * q1.x + w2v * q2.x + w3v * q3.x;
    y[i].y = av.y + w0 * q0.y + w1v * q1.y + w2v * q2.y + w3v * q3.y;
    y[i].z = av.z + w0 * q0.z + w1v * q1.z + w2v * q2.z + w3v * q3.z;
    y[i].w = av.w + w0 * q0.w + w1v * q1.w + w2v * q2.w + w3v * q3.w;
  }
  int slot = b & (NSLOT - 1);
  // ---- phase 1: sums ----
#pragma unroll
  for (int i = 0; i < 12; ++i) {
    m[ch0 + 4 * i + 0][s] = y[i].x;
    m[ch0 + 4 * i + 1][s] = y[i].y;
    m[ch0 + 4 * i + 2][s] = y[i].z;
    m[ch0 + 4 * i + 3][s] = y[i].w;
  }
  __syncthreads();
  {
    int c = t & 127, seg = t >> 7;
    if (c < 96) {
      float acc = 0.f;
#pragma unroll 8
      for (int j = 0; j < 64; ++j) acc += m[c][seg * 64 + j];
      pr[seg][c] = acc;
    }
  }
  __syncthreads();
  if (t < 96) atomicAdd(&ws[S1SUM + slot * C1 + t], pr[0][t] + pr[1][t]);
  __syncthreads();
  // ---- phase 2: squares ----
#pragma unroll
  for (int i = 0; i < 12; ++i) {
    m[ch0 + 4 * i + 0][s] = y[i].x * y[i].x;
    m[ch0 + 4 * i + 1][s] = y[i].y * y[i].y;
    m[ch0 + 4 * i + 2][s] = y[i].z * y[i].z;
    m[ch0 + 4 * i + 3][s] = y[i].w * y[i].w;
  }
  __syncthreads();
  {
    int c = t & 127, seg = t >> 7;
    if (c < 96) {
      float acc = 0.f;
#pragma unroll 8
      for (int j = 0; j < 64; ++j) acc += m[c][seg * 64 + j];
      pr[seg][c] = acc;
    }
  }
  __syncthreads();
  if (t < 96) atomicAdd(&ws[S1SSQ + slot * C1 + t], pr[0][t] + pr[1][t]);
}

// finalize: sum NSLOT slot copies, compute scale/shift
__global__ void k_finalize(float* __restrict__ ws, int sumO, int ssqO,
                           const float* __restrict__ gamma, const float* __restrict__ beta,
                           int sO, int tO, int C) {
  int c = threadIdx.x;
  if (c < C) {
    float su = 0.f, sq = 0.f;
    for (int s = 0; s < NSLOT; ++s) { su += ws[sumO + s * C + c]; sq += ws[ssqO + s * C + c]; }
    float mean = su * (1.0f / (float)NS);
    float var = sq * (1.0f / (float)NS) - mean * mean;
    float sc = gamma[c] * rsqrtf(var + EPSF);
    ws[sO + c] = sc;
    ws[tO + c] = beta[c] - mean * sc;
  }
}

// layer2: build x1 tile (bn1+relu of recomputed y1), GEMM 128x128 <- W2 @ x1, stats of y2, store y2 bf16
__global__ __launch_bounds__(256) void k_layer2(const float* __restrict__ coords,
                                                float* __restrict__ ws,
                                                unsigned short* __restrict__ y2) {
  __shared__ float x1s[C1][128];   // 48KB
  __shared__ float red[1024];      // 4KB, aliased as tap scratch
  int* tapO = (int*)red;
  float* tapW = red + 512;
  int t = threadIdx.x;
  int b = blockIdx.x;
  int k = b % 81, yrow = b / 81;   // k fastest: resident blocks share gather rows
  int p0 = yrow * 128;
  int n0 = k * P + p0;
  if (t < 128) {
    int p = p0 + t;
    float cx = coords[p] + (float)(k / 9) - 4.0f;
    float cy = coords[P + p] + (float)(k % 9) - 4.0f;
    Tap4 tp = make_taps(cx, cy);
#pragma unroll
    for (int i = 0; i < 4; ++i) { tapO[t * 4 + i] = tp.o[i]; tapW[t * 4 + i] = tp.w[i]; }
  }
  __syncthreads();
  {
    int s = t >> 1;
    int ch0 = (t & 1) * 48;
    int p = p0 + s;
    float w0 = tapW[s * 4 + 0], w1v = tapW[s * 4 + 1], w2v = tapW[s * 4 + 2], w3v = tapW[s * 4 + 3];
    const float4* a4 = (const float4*)(ws + A_OFF + (size_t)p * C1 + ch0);
    const float4* g0 = (const float4*)(ws + G_OFF + tapO[s * 4 + 0] + ch0);
    const float4* g1 = (const float4*)(ws + G_OFF + tapO[s * 4 + 1] + ch0);
    const float4* g2 = (const float4*)(ws + G_OFF + tapO[s * 4 + 2] + ch0);
    const float4* g3 = (const float4*)(ws + G_OFF + tapO[s * 4 + 3] + ch0);
    const float4* s14 = (const float4*)(ws + S1S + ch0);
    const float4* t14 = (const float4*)(ws + S1T + ch0);
#pragma unroll
    for (int i = 0; i < 12; ++i) {
      float4 av = a4[i], q0 = g0[i], q1 = g1[i], q2 = g2[i], q3 = g3[i];
      float4 sc = s14[i], tc = t14[i];
      int c = ch0 + i * 4;
      x1s[c + 0][s] = fmaxf(0.f, sc.x * (av.x + w0 * q0.x + w1v * q1.x + w2v * q2.x + w3v * q3.x) + tc.x);
      x1s[c + 1][s] = fmaxf(0.f, sc.y * (av.y + w0 * q0.y + w1v * q1.y + w2v * q2.y + w3v * q3.y) + tc.y);
      x1s[c + 2][s] = fmaxf(0.f, sc.z * (av.z + w0 * q0.z + w1v * q1.z + w2v * q2.z + w3v * q3.z) + tc.z);
      x1s[c + 3][s] = fmaxf(0.f, sc.w * (av.w + w0 * q0.w + w1v * q1.w + w2v * q2.w + w3v * q3.w) + tc.w);
    }
  }
  __syncthreads();
  int tm = t & 15, ts = t >> 4;
  int o0 = tm * 8, s0 = ts * 8;
  float acc[8][8];
#pragma unroll
  for (int i = 0; i < 8; ++i)
#pragma unroll
    for (int j = 0; j < 8; ++j) acc[i][j] = 0.f;
  const float* w2t = ws + W2T_OFF;
#pragma unroll 2
  for (int c = 0; c < C1; ++c) {
    float4 wa = *(const float4*)(w2t + c * C2 + o0);
    float4 wb = *(const float4*)(w2t + c * C2 + o0 + 4);
    float4 xa = *(const float4*)&x1s[c][s0];
    float4 xb = *(const float4*)&x1s[c][s0 + 4];
    float wv[8] = {wa.x, wa.y, wa.z, wa.w, wb.x, wb.y, wb.z, wb.w};
    float xv[8] = {xa.x, xa.y, xa.z, xa.w, xb.x, xb.y, xb.z, xb.w};
#pragma unroll
    for (int i = 0; i < 8; ++i)
#pragma unroll
      for (int j = 0; j < 8; ++j) acc[i][j] += wv[i] * xv[j];
  }
  float ssum[8], sssq[8];
#pragma unroll
  for (int i = 0; i < 8; ++i) { ssum[i] = 0.f; sssq[i] = 0.f; }
#pragma unroll
  for (int j = 0; j < 8; ++j) {
    unsigned short hv[8];
#pragma unroll
    for (int i = 0; i < 8; ++i) {
      float v = acc[i][j];
      ssum[i] += v; sssq[i] += v * v;
      hv[i] = f2bf(v);
    }
    uint4 pk;
    pk.x = (unsigned)hv[0] | ((unsigned)hv[1] << 16);
    pk.y = (unsigned)hv[2] | ((unsigned)hv[3] << 16);
    pk.z = (unsigned)hv[4] | ((unsigned)hv[5] << 16);
    pk.w = (unsigned)hv[6] | ((unsigned)hv[7] << 16);
    *(uint4*)(y2 + (size_t)(n0 + s0 + j) * C2 + o0) = pk;
  }
#pragma unroll
  for (int i = 0; i < 8; ++i) {
    ssum[i] += __shfl_xor(ssum[i], 16); ssum[i] += __shfl_xor(ssum[i], 32);
    sssq[i] += __shfl_xor(sssq[i], 16); sssq[i] += __shfl_xor(sssq[i], 32);
  }
  __syncthreads();
  int lane = t & 63, wvid = t >> 6;
  if (lane < 16) {
#pragma unroll
    for (int i = 0; i < 8; ++i) {
      red[wvid * 256 + lane * 16 + i] = ssum[i];
      red[wvid * 256 + lane * 16 + 8 + i] = sssq[i];
    }
  }
  __syncthreads();
  {
    int tm2 = t >> 4, v = t & 15;
    float tot = red[tm2 * 16 + v] + red[256 + tm2 * 16 + v] + red[512 + tm2 * 16 + v] + red[768 + tm2 * 16 + v];
    int ch = tm2 * 8 + (v & 7);
    int slot = b & (NSLOT - 1);
    atomicAdd(&ws[(v < 8 ? S2SUM : S2SSQ) + slot * C2 + ch], tot);
  }
}

// layer3: x2 = bn2+relu(y2), y3 = W3 @ x2, stats of y3, store y3 bf16
__global__ __launch_bounds__(256) void k_layer3(const unsigned short* __restrict__ y2,
                                                float* __restrict__ ws,
                                                unsigned short* __restrict__ y3) {
  __shared__ float x2s[C2][64];    // 32KB (aliased as reduce scratch at the end)
  int t = threadIdx.x;
  int b = blockIdx.x;
  int k = b % 81, tile = b / 81;
  int n0 = k * P + tile * 64;
  {
    int s = t & 63, ch0 = (t >> 6) * 32;
    const uint4* row = (const uint4*)(y2 + (size_t)(n0 + s) * C2 + ch0);
    const float* s2p = ws + S2S;
    const float* t2p = ws + S2T;
#pragma unroll
    for (int j = 0; j < 4; ++j) {
      uint4 v = row[j];
      unsigned arr[4] = {v.x, v.y, v.z, v.w};
#pragma unroll
      for (int e = 0; e < 4; ++e) {
        int c = ch0 + j * 8 + e * 2;
        float f0 = __uint_as_float((arr[e] & 0xffffu) << 16);
        float f1 = __uint_as_float(arr[e] & 0xffff0000u);
        x2s[c][s] = fmaxf(0.f, s2p[c] * f0 + t2p[c]);
        x2s[c + 1][s] = fmaxf(0.f, s2p[c + 1] * f1 + t2p[c + 1]);
      }
    }
  }
  __syncthreads();
  int tm = t & 15, ts = t >> 4;
  int o0 = tm * 4, s0 = ts * 4;
  float acc[4][4];
#pragma unroll
  for (int i = 0; i < 4; ++i)
#pragma unroll
    for (int j = 0; j < 4; ++j) acc[i][j] = 0.f;
  const float* w3t = ws + W3T_OFF;
#pragma unroll 4
  for (int c = 0; c < C2; ++c) {
    float4 wa = *(const float4*)(w3t + c * C3 + o0);
    float4 xa = *(const float4*)&x2s[c][s0];
    float wv[4] = {wa.x, wa.y, wa.z, wa.w};
    float xv[4] = {xa.x, xa.y, xa.z, xa.w};
#pragma unroll
    for (int i = 0; i < 4; ++i)
#pragma unroll
      for (int j = 0; j < 4; ++j) acc[i][j] += wv[i] * xv[j];
  }
  float ssum[4], sssq[4];
#pragma unroll
  for (int i = 0; i < 4; ++i) { ssum[i] = 0.f; sssq[i] = 0.f; }
#pragma unroll
  for (int j = 0; j < 4; ++j) {
    unsigned short hv[4];
#pragma unroll
    for (int i = 0; i < 4; ++i) {
      float v = acc[i][j];
      ssum[i] += v; sssq[i] += v * v;
      hv[i] = f2bf(v);
    }
    uint2 pk;
    pk.x = (unsigned)hv[0] | ((unsigned)hv[1] << 16);
    pk.y = (unsigned)hv[2] | ((unsigned)hv[3] << 16);
    *(uint2*)(y3 + (size_t)(n0 + s0 + j) * C3 + o0) = pk;
  }
#pragma unroll
  for (int i = 0; i < 4; ++i) {
    ssum[i] += __shfl_xor(ssum[i], 16); ssum[i] += __shfl_xor(ssum[i], 32);
    sssq[i] += __shfl_xor(sssq[i], 16); sssq[i] += __shfl_xor(sssq[i], 32);
  }
  __syncthreads();   // all x2s reads done before aliasing as reduce scratch
  float* red = (float*)x2s;
  int lane = t & 63, wvid = t >> 6;
  if (lane < 16) {
#pragma unroll
    for (int i = 0; i < 4; ++i) {
      red[wvid * 128 + lane * 8 + i] = ssum[i];
      red[wvid * 128 + lane * 8 + 4 + i] = sssq[i];
    }
  }
  __syncthreads();
  if (t < 128) {
    int tm2 = t >> 3, v = t & 7;
    float tot = red[tm2 * 8 + v] + red[128 + tm2 * 8 + v] + red[256 + tm2 * 8 + v] + red[384 + tm2 * 8 + v];
    int ch = tm2 * 4 + (v & 3);
    int slot = b & (NSLOT - 1);
    atomicAdd(&ws[(v < 4 ? S3SUM : S3SSQ) + slot * C3 + ch], tot);
  }
}

// layer4: cost = w4 . relu(bn3(y3)) + b4
__global__ __launch_bounds__(256) void k_layer4(const unsigned short* __restrict__ y3,
                                                float* __restrict__ ws,
                                                const float* __restrict__ w4,
                                                const float* __restrict__ b4) {
  int n = blockIdx.x * 256 + threadIdx.x;
  const float* s3p = ws + S3S;
  const float* t3p = ws + S3T;
  const uint4* row = (const uint4*)(y3 + (size_t)n * C3);
  float acc = 0.f;
#pragma unroll
  for (int j = 0; j < 8; ++j) {
    uint4 v = row[j];
    unsigned arr[4] = {v.x, v.y, v.z, v.w};
#pragma unroll
    for (int e = 0; e < 4; ++e) {
      int c = j * 8 + e * 2;
      float f0 = __uint_as_float((arr[e] & 0xffffu) << 16);
      float f1 = __uint_as_float(arr[e] & 0xffff0000u);
      acc += fmaxf(0.f, s3p[c] * f0 + t3p[c]) * w4[c];
      acc += fmaxf(0.f, s3p[c + 1] * f1 + t3p[c + 1]) * w4[c + 1];
    }
  }
  ws[COST_OFF + n] = acc + b4[0];
}

// DAP: out[l,p] = sum_k wdap[l,k] * cost[k,p]
__global__ __launch_bounds__(256) void k_dap(const float* __restrict__ ws,
                                             const float* __restrict__ wdap,
                                             float* __restrict__ out) {
  __shared__ float wd[DD * DD];
  int t = threadIdx.x;
  for (int i = t; i < DD * DD; i += 256) wd[i] = wdap[i];
  __syncthreads();
  int p = blockIdx.x * 64 + (t & 63);
  int lg = t >> 6;
  const float* cost = ws + COST_OFF;
  float cr[81];
#pragma unroll
  for (int kk = 0; kk < 81; ++kk) cr[kk] = cost[kk * P + p];
  int l0 = lg * 21;
  int l1 = min(81, l0 + 21);
  for (int l = l0; l < l1; ++l) {
    float acc = 0.f;
#pragma unroll
    for (int kk = 0; kk < 81; ++kk) acc += wd[l * 81 + kk] * cr[kk];
    out[(size_t)l * P + p] = acc;
  }
}

__global__ void k_marker(float* out) { out[0] = 1.0e30f; }

extern "C" void kernel_launch(void* const* d_in, const int* in_sizes, int n_in,
                              void* d_out, int out_size, void* d_ws, size_t ws_size,
                              hipStream_t stream) {
  const float* f1 = (const float*)d_in[0];
  const float* f2 = (const float*)d_in[1];
  const float* coords = (const float*)d_in[2];
  const float* w1 = (const float*)d_in[3];
  const float* g1 = (const float*)d_in[4];
  const float* be1 = (const float*)d_in[5];
  const float* w2 = (const float*)d_in[6];
  const float* g2 = (const float*)d_in[7];
  const float* be2 = (const float*)d_in[8];
  const float* w3 = (const float*)d_in[9];
  const float* g3 = (const float*)d_in[10];
  const float* be3 = (const float*)d_in[11];
  const float* w4 = (const float*)d_in[12];
  const float* b4 = (const float*)d_in[13];
  const float* wdap = (const float*)d_in[14];
  float* out = (float*)d_out;
  float* ws = (float*)d_ws;

  if (ws_size < WS_NEEDED) {  // signal insufficient workspace distinctly
    k_marker<<<1, 1, 0, stream>>>(out);
    return;
  }
  unsigned short* y2 = (unsigned short*)((char*)d_ws + Y2_BYTE);
  unsigned short* y3 = (unsigned short*)((char*)d_ws + Y3_BYTE);

  hipMemsetAsync(d_ws, 0, (size_t)STATS_ZERO_FLOATS * 4, stream);
  k_prep<<<128, 256, 0, stream>>>(f1, f2, w1, ws);
  k_transpose<<<64, 256, 0, stream>>>(w2, w3, ws);
  k_stats1<<<5184, 256, 0, stream>>>(coords, ws);
  k_finalize<<<1, 128, 0, stream>>>(ws, S1SUM, S1SSQ, g1, be1, S1S, S1T, C1);
  k_layer2<<<5184, 256, 0, stream>>>(coords, ws, y2);
  k_finalize<<<1, 128, 0, stream>>>(ws, S2SUM, S2SSQ, g2, be2, S2S, S2T, C2);
  k_layer3<<<10368, 256, 0, stream>>>(y2, ws, y3);
  k_finalize<<<1, 128, 0, stream>>>(ws, S3SUM, S3SSQ, g3, be3, S3S, S3T, C3);
  k_layer4<<<2592, 256, 0, stream>>>(y3, ws, w4, b4);
  k_dap<<<128, 256, 0, stream>>>(ws, wdap, out);
}

// Round 3
// 457.136 us; speedup vs baseline: 4.0516x; 1.9860x over previous
//
#include <hip/hip_runtime.h>

#define H 64
#define W 128
#define P 8192        // H*W
#define DD 81
#define NS 663552     // DD*P
#define C1 96
#define C2 128
#define C3 64
#define EPSF 1e-5f
#define NSLOT 128

typedef __attribute__((ext_vector_type(8))) short bf16x8;
typedef __attribute__((ext_vector_type(4))) float f32x4;

// ---- workspace layout ----
// float-indexed region
#define S1SUM 0
#define S1SSQ (S1SUM + NSLOT * C1)              // 12288
#define S2SUM (S1SSQ + NSLOT * C1)              // 24576
#define S2SSQ (S2SUM + NSLOT * C2)              // 40960
#define S3SUM (S2SSQ + NSLOT * C2)              // 57344
#define S3SSQ (S3SUM + NSLOT * C3)              // 65536
#define STATS_ZERO_FLOATS (S3SSQ + NSLOT * C3)  // 73728
#define S1S 73728
#define S1T (S1S + C1)
#define S2S (S1T + C1)
#define S2T (S2S + C2)
#define S3S (S2T + C2)
#define S3T (S3S + C3)
#define COST_OFF 74304
#define FLOAT_END (COST_OFF + NS)               // 737856
// byte-indexed region
#define A_BYTE   ((size_t)FLOAT_END * 4)                 // 2951424
#define G_BYTE   (A_BYTE + (size_t)P * 96 * 2)           // +1572864
#define W2BF_BYTE (G_BYTE + (size_t)P * 96 * 2)
#define W3BF_BYTE (W2BF_BYTE + (size_t)C2 * C1 * 2)
#define Y2_BYTE  (W3BF_BYTE + (size_t)C3 * C2 * 2)
#define Y3_BYTE  (Y2_BYTE + (size_t)NS * C2 * 2)
#define WS_NEEDED (Y3_BYTE + (size_t)NS * C3 * 2)

__device__ __forceinline__ unsigned short f2bf(float f) {
  unsigned u = __float_as_uint(f);
  return (unsigned short)((u + 0x7fffu + ((u >> 16) & 1u)) >> 16);
}
__device__ __forceinline__ float bflo(unsigned u) { return __uint_as_float(u << 16); }
__device__ __forceinline__ float bfhi(unsigned u) { return __uint_as_float(u & 0xffff0000u); }

struct Tap4 { int o[4]; float w[4]; };

__device__ __forceinline__ Tap4 make_taps(float cx, float cy) {
  Tap4 tp;
  float x0f = floorf(cx), y0f = floorf(cy);
  float fx = cx - x0f, fy = cy - y0f;
  int ix0 = (int)x0f, iy0 = (int)y0f;
  int ix1 = ix0 + 1, iy1 = iy0 + 1;
  float vx0 = (ix0 >= 0 && ix0 < W) ? 1.f : 0.f;
  float vx1 = (ix1 >= 0 && ix1 < W) ? 1.f : 0.f;
  float vy0 = (iy0 >= 0 && iy0 < H) ? 1.f : 0.f;
  float vy1 = (iy1 >= 0 && iy1 < H) ? 1.f : 0.f;
  int cx0 = min(max(ix0, 0), W - 1), cx1 = min(max(ix1, 0), W - 1);
  int cy0 = min(max(iy0, 0), H - 1), cy1 = min(max(iy1, 0), H - 1);
  tp.w[0] = (1.f - fy) * (1.f - fx) * vy0 * vx0;
  tp.w[1] = (1.f - fy) * fx * vy0 * vx1;
  tp.w[2] = fy * (1.f - fx) * vy1 * vx0;
  tp.w[3] = fy * fx * vy1 * vx1;
  tp.o[0] = (cy0 * W + cx0) * 96;
  tp.o[1] = (cy0 * W + cx1) * 96;
  tp.o[2] = (cy1 * W + cx0) * 96;
  tp.o[3] = (cy1 * W + cx1) * 96;
  return tp;
}

// a = w1[:, :128] @ f1, g = w1[:, 128:] @ f2  -> bf16, pixel-major [p][96]
__global__ __launch_bounds__(256) void k_prep(const float* __restrict__ f1,
                                              const float* __restrict__ f2,
                                              const float* __restrict__ w1,
                                              unsigned short* __restrict__ abf,
                                              unsigned short* __restrict__ gbf) {
  __shared__ float tile[128][64];
  int t = threadIdx.x;
  int p0 = blockIdx.x * 64;
  int px = t & 63, q = t >> 6;
  int c0 = q * 24;
  for (int pass = 0; pass < 2; ++pass) {
    const float* src = pass ? f2 : f1;
    unsigned short* dst = pass ? gbf : abf;
    int koff = pass ? 128 : 0;
    __syncthreads();
    for (int idx = t; idx < 8192; idx += 256) {
      int kk = idx >> 6, xx = idx & 63;
      tile[kk][xx] = src[kk * P + p0 + xx];
    }
    __syncthreads();
    float acc[24];
#pragma unroll
    for (int i = 0; i < 24; ++i) acc[i] = 0.f;
    for (int kk = 0; kk < 128; ++kk) {
      float fv = tile[kk][px];
#pragma unroll
      for (int i = 0; i < 24; ++i)
        acc[i] += w1[(c0 + i) * 256 + koff + kk] * fv;
    }
    unsigned short* orow = dst + (size_t)(p0 + px) * 96 + c0;
#pragma unroll
    for (int i = 0; i < 24; i += 8) {
      uint4 pk;
      pk.x = (unsigned)f2bf(acc[i + 0]) | ((unsigned)f2bf(acc[i + 1]) << 16);
      pk.y = (unsigned)f2bf(acc[i + 2]) | ((unsigned)f2bf(acc[i + 3]) << 16);
      pk.z = (unsigned)f2bf(acc[i + 4]) | ((unsigned)f2bf(acc[i + 5]) << 16);
      pk.w = (unsigned)f2bf(acc[i + 6]) | ((unsigned)f2bf(acc[i + 7]) << 16);
      *(uint4*)(orow + i) = pk;
    }
  }
}

// convert w2 (128x96) and w3 (64x128) to bf16 row-major
__global__ void k_wprep(const float* __restrict__ w2, const float* __restrict__ w3,
                        unsigned short* __restrict__ w2bf, unsigned short* __restrict__ w3bf) {
  int idx = blockIdx.x * 256 + threadIdx.x;
  if (idx < C2 * C1) w2bf[idx] = f2bf(w2[idx]);
  else if (idx < C2 * C1 + C3 * C2) w3bf[idx - C2 * C1] = f2bf(w3[idx - C2 * C1]);
}

// per-channel sum/sumsq of y1 = a + bilinear(g); one block = 128 pixels x 1 displacement
__global__ __launch_bounds__(256) void k_stats1(const float* __restrict__ coords,
                                                float* __restrict__ ws,
                                                const unsigned short* __restrict__ abf,
                                                const unsigned short* __restrict__ gbf) {
  __shared__ float m[96][129];
  __shared__ float pr[2][96];
  int t = threadIdx.x, b = blockIdx.x;
  int k = b % 81, ptile = b / 81;
  int s = t >> 1, hh = t & 1, ch0 = hh * 48;
  int p = ptile * 128 + s;
  float cx = coords[p] + (float)(k / 9) - 4.0f;
  float cy = coords[P + p] + (float)(k % 9) - 4.0f;
  Tap4 tp = make_taps(cx, cy);
  const uint4* A4 = (const uint4*)(abf + (size_t)p * 96 + ch0);
  const uint4* G0 = (const uint4*)(gbf + tp.o[0] + ch0);
  const uint4* G1 = (const uint4*)(gbf + tp.o[1] + ch0);
  const uint4* G2 = (const uint4*)(gbf + tp.o[2] + ch0);
  const uint4* G3 = (const uint4*)(gbf + tp.o[3] + ch0);
  float w0 = tp.w[0], w1v = tp.w[1], w2v = tp.w[2], w3v = tp.w[3];
  float y[48];
#pragma unroll
  for (int i = 0; i < 6; ++i) {
    uint4 av = A4[i], v0 = G0[i], v1 = G1[i], v2 = G2[i], v3 = G3[i];
    unsigned au[4] = {av.x, av.y, av.z, av.w};
    unsigned b0[4] = {v0.x, v0.y, v0.z, v0.w};
    unsigned b1[4] = {v1.x, v1.y, v1.z, v1.w};
    unsigned b2[4] = {v2.x, v2.y, v2.z, v2.w};
    unsigned b3[4] = {v3.x, v3.y, v3.z, v3.w};
#pragma unroll
    for (int e = 0; e < 4; ++e) {
      y[i * 8 + e * 2 + 0] = bflo(au[e]) + w0 * bflo(b0[e]) + w1v * bflo(b1[e]) + w2v * bflo(b2[e]) + w3v * bflo(b3[e]);
      y[i * 8 + e * 2 + 1] = bfhi(au[e]) + w0 * bfhi(b0[e]) + w1v * bfhi(b1[e]) + w2v * bfhi(b2[e]) + w3v * bfhi(b3[e]);
    }
  }
  int slot = b & (NSLOT - 1);
#pragma unroll
  for (int j = 0; j < 48; ++j) m[ch0 + j][s] = y[j];
  __syncthreads();
  {
    int c = t & 127, seg = t >> 7;
    if (c < 96) {
      float acc = 0.f;
#pragma unroll 8
      for (int j = 0; j < 64; ++j) acc += m[c][seg * 64 + j];
      pr[seg][c] = acc;
    }
  }
  __syncthreads();
  if (t < 96) atomicAdd(&ws[S1SUM + slot * C1 + t], pr[0][t] + pr[1][t]);
  __syncthreads();
#pragma unroll
  for (int j = 0; j < 48; ++j) m[ch0 + j][s] = y[j] * y[j];
  __syncthreads();
  {
    int c = t & 127, seg = t >> 7;
    if (c < 96) {
      float acc = 0.f;
#pragma unroll 8
      for (int j = 0; j < 64; ++j) acc += m[c][seg * 64 + j];
      pr[seg][c] = acc;
    }
  }
  __syncthreads();
  if (t < 96) atomicAdd(&ws[S1SSQ + slot * C1 + t], pr[0][t] + pr[1][t]);
}

__global__ void k_finalize(float* __restrict__ ws, int sumO, int ssqO,
                           const float* __restrict__ gamma, const float* __restrict__ beta,
                           int sO, int tO, int C) {
  int c = threadIdx.x;
  if (c < C) {
    float su = 0.f, sq = 0.f;
    for (int s = 0; s < NSLOT; ++s) { su += ws[sumO + s * C + c]; sq += ws[ssqO + s * C + c]; }
    float mean = su * (1.0f / (float)NS);
    float var = sq * (1.0f / (float)NS) - mean * mean;
    float sc = gamma[c] * rsqrtf(var + EPSF);
    ws[sO + c] = sc;
    ws[tO + c] = beta[c] - mean * sc;
  }
}

// layer2: x1 (bn1+relu, bf16 LDS) -> MFMA y2 = W2 @ x1 -> stats2 + y2 bf16 store
__global__ __launch_bounds__(256) void k_layer2(const float* __restrict__ coords,
                                                float* __restrict__ ws,
                                                const unsigned short* __restrict__ abf,
                                                const unsigned short* __restrict__ gbf,
                                                const unsigned short* __restrict__ w2bf,
                                                unsigned short* __restrict__ y2) {
  __shared__ unsigned short lds[128 * 136];   // x1t [128 pix][136 (96 used)] then y2stage [128][136 (128 used)]
  __shared__ float sred[256];                 // [0..127] sum, [128..255] ssq
  int t = threadIdx.x, b = blockIdx.x;
  int k = b % 81, yrow = b / 81;
  int p0 = yrow * 128;
  int n0 = k * P + p0;
  int slot = b & (NSLOT - 1);
  sred[t] = 0.f;
  {
    int s = t >> 1, hh = t & 1, ch0 = hh * 48;
    int p = p0 + s;
    float cx = coords[p] + (float)(k / 9) - 4.0f;
    float cy = coords[P + p] + (float)(k % 9) - 4.0f;
    Tap4 tp = make_taps(cx, cy);
    const uint4* A4 = (const uint4*)(abf + (size_t)p * 96 + ch0);
    const uint4* G0 = (const uint4*)(gbf + tp.o[0] + ch0);
    const uint4* G1 = (const uint4*)(gbf + tp.o[1] + ch0);
    const uint4* G2 = (const uint4*)(gbf + tp.o[2] + ch0);
    const uint4* G3 = (const uint4*)(gbf + tp.o[3] + ch0);
    const float* s1p = ws + S1S;
    const float* t1p = ws + S1T;
    float w0 = tp.w[0], w1v = tp.w[1], w2v = tp.w[2], w3v = tp.w[3];
#pragma unroll
    for (int i = 0; i < 6; ++i) {
      uint4 av = A4[i], v0 = G0[i], v1 = G1[i], v2 = G2[i], v3 = G3[i];
      unsigned au[4] = {av.x, av.y, av.z, av.w};
      unsigned b0[4] = {v0.x, v0.y, v0.z, v0.w};
      unsigned b1[4] = {v1.x, v1.y, v1.z, v1.w};
      unsigned b2[4] = {v2.x, v2.y, v2.z, v2.w};
      unsigned b3[4] = {v3.x, v3.y, v3.z, v3.w};
      unsigned pk[4];
#pragma unroll
      for (int e = 0; e < 4; ++e) {
        int c = ch0 + i * 8 + e * 2;
        float ya = bflo(au[e]) + w0 * bflo(b0[e]) + w1v * bflo(b1[e]) + w2v * bflo(b2[e]) + w3v * bflo(b3[e]);
        float yb = bfhi(au[e]) + w0 * bfhi(b0[e]) + w1v * bfhi(b1[e]) + w2v * bfhi(b2[e]) + w3v * bfhi(b3[e]);
        float xa = fmaxf(0.f, s1p[c] * ya + t1p[c]);
        float xb = fmaxf(0.f, s1p[c + 1] * yb + t1p[c + 1]);
        pk[e] = (unsigned)f2bf(xa) | ((unsigned)f2bf(xb) << 16);
      }
      uint4 pkv; pkv.x = pk[0]; pkv.y = pk[1]; pkv.z = pk[2]; pkv.w = pk[3];
      *(uint4*)&lds[s * 136 + ch0 + i * 8] = pkv;
    }
  }
  __syncthreads();
  int l = t & 63, wv = t >> 6;
  int o0w = wv * 32;
  int lr = l & 15, lh = l >> 4;
  bf16x8 af[2][3];
#pragma unroll
  for (int m = 0; m < 2; ++m)
#pragma unroll
    for (int kk = 0; kk < 3; ++kk)
      af[m][kk] = *(const bf16x8*)(const void*)(w2bf + (size_t)(o0w + m * 16 + lr) * 96 + kk * 32 + lh * 8);
  f32x4 acc[2][8];
  f32x4 zero4 = {0.f, 0.f, 0.f, 0.f};
#pragma unroll
  for (int m = 0; m < 2; ++m)
#pragma unroll
    for (int n = 0; n < 8; ++n) acc[m][n] = zero4;
#pragma unroll
  for (int kk = 0; kk < 3; ++kk)
#pragma unroll
    for (int n = 0; n < 8; ++n) {
      bf16x8 bfr = *(const bf16x8*)(const void*)&lds[(n * 16 + lr) * 136 + kk * 32 + lh * 8];
      acc[0][n] = __builtin_amdgcn_mfma_f32_16x16x32_bf16(af[0][kk], bfr, acc[0][n], 0, 0, 0);
      acc[1][n] = __builtin_amdgcn_mfma_f32_16x16x32_bf16(af[1][kk], bfr, acc[1][n], 0, 0, 0);
    }
  // stats from fp32 accumulators
  float ssum[8], sssq[8];
#pragma unroll
  for (int i = 0; i < 8; ++i) { ssum[i] = 0.f; sssq[i] = 0.f; }
#pragma unroll
  for (int m = 0; m < 2; ++m)
#pragma unroll
    for (int n = 0; n < 8; ++n) {
      f32x4 v = acc[m][n];
#pragma unroll
      for (int r = 0; r < 4; ++r) { float x = v[r]; ssum[m * 4 + r] += x; sssq[m * 4 + r] += x * x; }
    }
#pragma unroll
  for (int msk = 1; msk < 16; msk <<= 1)
#pragma unroll
    for (int i = 0; i < 8; ++i) { ssum[i] += __shfl_xor(ssum[i], msk); sssq[i] += __shfl_xor(sssq[i], msk); }
  if (lr == 0) {
#pragma unroll
    for (int m = 0; m < 2; ++m)
#pragma unroll
      for (int r = 0; r < 4; ++r) {
        int o = o0w + m * 16 + lh * 4 + r;
        atomicAdd(&sred[o], ssum[m * 4 + r]);
        atomicAdd(&sred[128 + o], sssq[m * 4 + r]);
      }
  }
  __syncthreads();   // all x1t reads complete
#pragma unroll
  for (int m = 0; m < 2; ++m)
#pragma unroll
    for (int n = 0; n < 8; ++n) {
      f32x4 v = acc[m][n];
      uint2 pk;
      pk.x = (unsigned)f2bf(v[0]) | ((unsigned)f2bf(v[1]) << 16);
      pk.y = (unsigned)f2bf(v[2]) | ((unsigned)f2bf(v[3]) << 16);
      int row = n * 16 + lr, col = o0w + m * 16 + lh * 4;
      *(uint2*)&lds[row * 136 + col] = pk;
    }
  __syncthreads();
  {
    int row = t >> 1, half = t & 1;
    const uint4* src = (const uint4*)&lds[row * 136 + half * 64];
    uint4* dst = (uint4*)(y2 + (size_t)(n0 + row) * 128 + half * 64);
#pragma unroll
    for (int j = 0; j < 8; ++j) dst[j] = src[j];
  }
  if (t < 128) atomicAdd(&ws[S2SUM + slot * C2 + t], sred[t]);
  else atomicAdd(&ws[S2SSQ + slot * C2 + (t - 128)], sred[t]);
}

// layer3: x2 = bn2+relu(y2) bf16 LDS -> MFMA y3 = W3 @ x2 -> stats3 + y3 bf16 store
__global__ __launch_bounds__(256) void k_layer3(const unsigned short* __restrict__ y2,
                                                float* __restrict__ ws,
                                                const unsigned short* __restrict__ w3bf,
                                                unsigned short* __restrict__ y3) {
  __shared__ unsigned short lds[128 * 136];   // x2t [128][136 (128 used)] then y3stage [128][72 (64 used)]
  __shared__ float sred[128];                 // [0..63] sum, [64..127] ssq
  int t = threadIdx.x, b = blockIdx.x;
  int k = b % 81, ptile = b / 81;
  int n0 = k * P + ptile * 128;
  int slot = b & (NSLOT - 1);
  if (t < 128) sred[t] = 0.f;
  {
    int s = t >> 1, hh = t & 1;
    const uint4* row = (const uint4*)(y2 + (size_t)(n0 + s) * 128 + hh * 64);
    const float* s2p = ws + S2S;
    const float* t2p = ws + S2T;
#pragma unroll
    for (int i = 0; i < 8; ++i) {
      uint4 v = row[i];
      unsigned a[4] = {v.x, v.y, v.z, v.w};
      unsigned pk[4];
#pragma unroll
      for (int e = 0; e < 4; ++e) {
        int c = hh * 64 + i * 8 + e * 2;
        float xa = fmaxf(0.f, s2p[c] * bflo(a[e]) + t2p[c]);
        float xb = fmaxf(0.f, s2p[c + 1] * bfhi(a[e]) + t2p[c + 1]);
        pk[e] = (unsigned)f2bf(xa) | ((unsigned)f2bf(xb) << 16);
      }
      uint4 pkv; pkv.x = pk[0]; pkv.y = pk[1]; pkv.z = pk[2]; pkv.w = pk[3];
      *(uint4*)&lds[s * 136 + hh * 64 + i * 8] = pkv;
    }
  }
  __syncthreads();
  int l = t & 63, wv = t >> 6;
  int o0w = (wv & 1) * 32, sc0 = (wv >> 1) * 64;
  int lr = l & 15, lh = l >> 4;
  bf16x8 af[2][4];
#pragma unroll
  for (int m = 0; m < 2; ++m)
#pragma unroll
    for (int kk = 0; kk < 4; ++kk)
      af[m][kk] = *(const bf16x8*)(const void*)(w3bf + (size_t)(o0w + m * 16 + lr) * 128 + kk * 32 + lh * 8);
  f32x4 acc[2][4];
  f32x4 zero4 = {0.f, 0.f, 0.f, 0.f};
#pragma unroll
  for (int m = 0; m < 2; ++m)
#pragma unroll
    for (int n = 0; n < 4; ++n) acc[m][n] = zero4;
#pragma unroll
  for (int kk = 0; kk < 4; ++kk)
#pragma unroll
    for (int n = 0; n < 4; ++n) {
      bf16x8 bfr = *(const bf16x8*)(const void*)&lds[(sc0 + n * 16 + lr) * 136 + kk * 32 + lh * 8];
      acc[0][n] = __builtin_amdgcn_mfma_f32_16x16x32_bf16(af[0][kk], bfr, acc[0][n], 0, 0, 0);
      acc[1][n] = __builtin_amdgcn_mfma_f32_16x16x32_bf16(af[1][kk], bfr, acc[1][n], 0, 0, 0);
    }
  float ssum[8], sssq[8];
#pragma unroll
  for (int i = 0; i < 8; ++i) { ssum[i] = 0.f; sssq[i] = 0.f; }
#pragma unroll
  for (int m = 0; m < 2; ++m)
#pragma unroll
    for (int n = 0; n < 4; ++n) {
      f32x4 v = acc[m][n];
#pragma unroll
      for (int r = 0; r < 4; ++r) { float x = v[r]; ssum[m * 4 + r] += x; sssq[m * 4 + r] += x * x; }
    }
#pragma unroll
  for (int msk = 1; msk < 16; msk <<= 1)
#pragma unroll
    for (int i = 0; i < 8; ++i) { ssum[i] += __shfl_xor(ssum[i], msk); sssq[i] += __shfl_xor(sssq[i], msk); }
  if (lr == 0) {
#pragma unroll
    for (int m = 0; m < 2; ++m)
#pragma unroll
      for (int r = 0; r < 4; ++r) {
        int o = o0w + m * 16 + lh * 4 + r;
        atomicAdd(&sred[o], ssum[m * 4 + r]);
        atomicAdd(&sred[64 + o], sssq[m * 4 + r]);
      }
  }
  __syncthreads();
#pragma unroll
  for (int m = 0; m < 2; ++m)
#pragma unroll
    for (int n = 0; n < 4; ++n) {
      f32x4 v = acc[m][n];
      uint2 pk;
      pk.x = (unsigned)f2bf(v[0]) | ((unsigned)f2bf(v[1]) << 16);
      pk.y = (unsigned)f2bf(v[2]) | ((unsigned)f2bf(v[3]) << 16);
      int row = sc0 + n * 16 + lr, col = o0w + m * 16 + lh * 4;
      *(uint2*)&lds[row * 72 + col] = pk;
    }
  __syncthreads();
  {
    int row = t >> 1, half = t & 1;
    const uint4* src = (const uint4*)&lds[row * 72 + half * 32];
    uint4* dst = (uint4*)(y3 + (size_t)(n0 + row) * 64 + half * 32);
#pragma unroll
    for (int j = 0; j < 4; ++j) dst[j] = src[j];
  }
  if (t < 64) atomicAdd(&ws[S3SUM + slot * C3 + t], sred[t]);
  else if (t < 128) atomicAdd(&ws[S3SSQ + slot * C3 + (t - 64)], sred[t]);
}

// layer4: cost = w4 . relu(bn3(y3)) + b4
__global__ __launch_bounds__(256) void k_layer4(const unsigned short* __restrict__ y3,
                                                float* __restrict__ ws,
                                                const float* __restrict__ w4,
                                                const float* __restrict__ b4) {
  int n = blockIdx.x * 256 + threadIdx.x;
  const float* s3p = ws + S3S;
  const float* t3p = ws + S3T;
  const uint4* row = (const uint4*)(y3 + (size_t)n * C3);
  float acc = 0.f;
#pragma unroll
  for (int j = 0; j < 8; ++j) {
    uint4 v = row[j];
    unsigned arr[4] = {v.x, v.y, v.z, v.w};
#pragma unroll
    for (int e = 0; e < 4; ++e) {
      int c = j * 8 + e * 2;
      acc += fmaxf(0.f, s3p[c] * bflo(arr[e]) + t3p[c]) * w4[c];
      acc += fmaxf(0.f, s3p[c + 1] * bfhi(arr[e]) + t3p[c + 1]) * w4[c + 1];
    }
  }
  ws[COST_OFF + n] = acc + b4[0];
}

// DAP: out[l,p] = sum_k wdap[l,k] * cost[k,p]
__global__ __launch_bounds__(256) void k_dap(const float* __restrict__ ws,
                                             const float* __restrict__ wdap,
                                             float* __restrict__ out) {
  __shared__ float wd[DD * DD];
  int t = threadIdx.x;
  for (int i = t; i < DD * DD; i += 256) wd[i] = wdap[i];
  __syncthreads();
  int p = blockIdx.x * 64 + (t & 63);
  int lg = t >> 6;
  const float* cost = ws + COST_OFF;
  float cr[81];
#pragma unroll
  for (int kk = 0; kk < 81; ++kk) cr[kk] = cost[kk * P + p];
  int l0 = lg * 21;
  int l1 = min(81, l0 + 21);
  for (int l = l0; l < l1; ++l) {
    float acc = 0.f;
#pragma unroll
    for (int kk = 0; kk < 81; ++kk) acc += wd[l * 81 + kk] * cr[kk];
    out[(size_t)l * P + p] = acc;
  }
}

__global__ void k_marker(float* out) { out[0] = 1.0e30f; }

extern "C" void kernel_launch(void* const* d_in, const int* in_sizes, int n_in,
                              void* d_out, int out_size, void* d_ws, size_t ws_size,
                              hipStream_t stream) {
  const float* f1 = (const float*)d_in[0];
  const float* f2 = (const float*)d_in[1];
  const float* coords = (const float*)d_in[2];
  const float* w1 = (const float*)d_in[3];
  const float* g1 = (const float*)d_in[4];
  const float* be1 = (const float*)d_in[5];
  const float* w2 = (const float*)d_in[6];
  const float* g2 = (const float*)d_in[7];
  const float* be2 = (const float*)d_in[8];
  const float* w3 = (const float*)d_in[9];
  const float* g3 = (const float*)d_in[10];
  const float* be3 = (const float*)d_in[11];
  const float* w4 = (const float*)d_in[12];
  const float* b4 = (const float*)d_in[13];
  const float* wdap = (const float*)d_in[14];
  float* out = (float*)d_out;
  float* ws = (float*)d_ws;

  if (ws_size < WS_NEEDED) {
    k_marker<<<1, 1, 0, stream>>>(out);
    return;
  }
  unsigned short* abf = (unsigned short*)((char*)d_ws + A_BYTE);
  unsigned short* gbf = (unsigned short*)((char*)d_ws + G_BYTE);
  unsigned short* w2bf = (unsigned short*)((char*)d_ws + W2BF_BYTE);
  unsigned short* w3bf = (unsigned short*)((char*)d_ws + W3BF_BYTE);
  unsigned short* y2 = (unsigned short*)((char*)d_ws + Y2_BYTE);
  unsigned short* y3 = (unsigned short*)((char*)d_ws + Y3_BYTE);

  hipMemsetAsync(d_ws, 0, (size_t)STATS_ZERO_FLOATS * 4, stream);
  k_prep<<<128, 256, 0, stream>>>(f1, f2, w1, abf, gbf);
  k_wprep<<<80, 256, 0, stream>>>(w2, w3, w2bf, w3bf);
  k_stats1<<<5184, 256, 0, stream>>>(coords, ws, abf, gbf);
  k_finalize<<<1, 128, 0, stream>>>(ws, S1SUM, S1SSQ, g1, be1, S1S, S1T, C1);
  k_layer2<<<5184, 256, 0, stream>>>(coords, ws, abf, gbf, w2bf, y2);
  k_finalize<<<1, 128, 0, stream>>>(ws, S2SUM, S2SSQ, g2, be2, S2S, S2T, C2);
  k_layer3<<<5184, 256, 0, stream>>>(y2, ws, w3bf, y3);
  k_finalize<<<1, 128, 0, stream>>>(ws, S3SUM, S3SSQ, g3, be3, S3S, S3T, C3);
  k_layer4<<<2592, 256, 0, stream>>>(y3, ws, w4, b4);
  k_dap<<<128, 256, 0, stream>>>(ws, wdap, out);
}

// Round 4
// 431.707 us; speedup vs baseline: 4.2902x; 1.0589x over previous
//
#include <hip/hip_runtime.h>

#define H 64
#define W 128
#define P 8192        // H*W
#define DD 81
#define NS 663552     // DD*P
#define C1 96
#define C2 128
#define C3 64
#define EPSF 1e-5f
#define NSLOT 128

typedef __attribute__((ext_vector_type(8))) short bf16x8;
typedef __attribute__((ext_vector_type(4))) float f32x4;

// ---- workspace layout ----
// float-indexed region
#define S1SUM 0
#define S1SSQ (S1SUM + NSLOT * C1)
#define S2SUM (S1SSQ + NSLOT * C1)
#define S2SSQ (S2SUM + NSLOT * C2)
#define S3SUM (S2SSQ + NSLOT * C2)
#define S3SSQ (S3SUM + NSLOT * C3)
#define STATS_ZERO_FLOATS (S3SSQ + NSLOT * C3)  // 73728
#define S1S 73728
#define S1T (S1S + C1)
#define S2S (S1T + C1)
#define S2T (S2S + C2)
#define S3S (S2T + C2)
#define S3T (S3S + C3)
#define COST_OFF 74304
#define FLOAT_END (COST_OFF + NS)
// byte-indexed region
#define A_BYTE   ((size_t)FLOAT_END * 4)
#define G_BYTE   (A_BYTE + (size_t)P * 96 * 2)
#define W2BF_BYTE (G_BYTE + (size_t)P * 96 * 2)
#define W3BF_BYTE (W2BF_BYTE + (size_t)C2 * C1 * 2)
#define Y1_BYTE  (W3BF_BYTE + (size_t)C3 * C2 * 2)
#define Y3_BYTE  (Y1_BYTE + (size_t)NS * C1 * 2)
#define WS_NEEDED (Y3_BYTE + (size_t)NS * C3 * 2)

__device__ __forceinline__ unsigned short f2bf(float f) {
  unsigned u = __float_as_uint(f);
  return (unsigned short)((u + 0x7fffu + ((u >> 16) & 1u)) >> 16);
}
__device__ __forceinline__ float bflo(unsigned u) { return __uint_as_float(u << 16); }
__device__ __forceinline__ float bfhi(unsigned u) { return __uint_as_float(u & 0xffff0000u); }

struct Tap4 { int o[4]; float w[4]; };

__device__ __forceinline__ Tap4 make_taps(float cx, float cy) {
  Tap4 tp;
  float x0f = floorf(cx), y0f = floorf(cy);
  float fx = cx - x0f, fy = cy - y0f;
  int ix0 = (int)x0f, iy0 = (int)y0f;
  int ix1 = ix0 + 1, iy1 = iy0 + 1;
  float vx0 = (ix0 >= 0 && ix0 < W) ? 1.f : 0.f;
  float vx1 = (ix1 >= 0 && ix1 < W) ? 1.f : 0.f;
  float vy0 = (iy0 >= 0 && iy0 < H) ? 1.f : 0.f;
  float vy1 = (iy1 >= 0 && iy1 < H) ? 1.f : 0.f;
  int cx0 = min(max(ix0, 0), W - 1), cx1 = min(max(ix1, 0), W - 1);
  int cy0 = min(max(iy0, 0), H - 1), cy1 = min(max(iy1, 0), H - 1);
  tp.w[0] = (1.f - fy) * (1.f - fx) * vy0 * vx0;
  tp.w[1] = (1.f - fy) * fx * vy0 * vx1;
  tp.w[2] = fy * (1.f - fx) * vy1 * vx0;
  tp.w[3] = fy * fx * vy1 * vx1;
  tp.o[0] = (cy0 * W + cx0) * 96;
  tp.o[1] = (cy0 * W + cx1) * 96;
  tp.o[2] = (cy1 * W + cx0) * 96;
  tp.o[3] = (cy1 * W + cx1) * 96;
  return tp;
}

// a = w1[:, :128] @ f1, g = w1[:, 128:] @ f2  -> bf16, pixel-major [p][96]
__global__ __launch_bounds__(256) void k_prep(const float* __restrict__ f1,
                                              const float* __restrict__ f2,
                                              const float* __restrict__ w1,
                                              unsigned short* __restrict__ abf,
                                              unsigned short* __restrict__ gbf) {
  __shared__ float tile[128][64];
  int t = threadIdx.x;
  int p0 = blockIdx.x * 64;
  int px = t & 63, q = t >> 6;
  int c0 = q * 24;
  for (int pass = 0; pass < 2; ++pass) {
    const float* src = pass ? f2 : f1;
    unsigned short* dst = pass ? gbf : abf;
    int koff = pass ? 128 : 0;
    __syncthreads();
    for (int idx = t; idx < 8192; idx += 256) {
      int kk = idx >> 6, xx = idx & 63;
      tile[kk][xx] = src[kk * P + p0 + xx];
    }
    __syncthreads();
    float acc[24];
#pragma unroll
    for (int i = 0; i < 24; ++i) acc[i] = 0.f;
    for (int kk = 0; kk < 128; ++kk) {
      float fv = tile[kk][px];
#pragma unroll
      for (int i = 0; i < 24; ++i)
        acc[i] += w1[(c0 + i) * 256 + koff + kk] * fv;
    }
    unsigned short* orow = dst + (size_t)(p0 + px) * 96 + c0;
#pragma unroll
    for (int i = 0; i < 24; i += 8) {
      uint4 pk;
      pk.x = (unsigned)f2bf(acc[i + 0]) | ((unsigned)f2bf(acc[i + 1]) << 16);
      pk.y = (unsigned)f2bf(acc[i + 2]) | ((unsigned)f2bf(acc[i + 3]) << 16);
      pk.z = (unsigned)f2bf(acc[i + 4]) | ((unsigned)f2bf(acc[i + 5]) << 16);
      pk.w = (unsigned)f2bf(acc[i + 6]) | ((unsigned)f2bf(acc[i + 7]) << 16);
      *(uint4*)(orow + i) = pk;
    }
  }
}

__global__ void k_wprep(const float* __restrict__ w2, const float* __restrict__ w3,
                        unsigned short* __restrict__ w2bf, unsigned short* __restrict__ w3bf) {
  int idx = blockIdx.x * 256 + threadIdx.x;
  if (idx < C2 * C1) w2bf[idx] = f2bf(w2[idx]);
  else if (idx < C2 * C1 + C3 * C2) w3bf[idx - C2 * C1] = f2bf(w3[idx - C2 * C1]);
}

// gather once: y1 = a + bilinear(g) -> bf16 store + stats1
__global__ __launch_bounds__(256) void k_sample(const float* __restrict__ coords,
                                                float* __restrict__ ws,
                                                const unsigned short* __restrict__ abf,
                                                const unsigned short* __restrict__ gbf,
                                                unsigned short* __restrict__ y1) {
  __shared__ float m[96][129];
  __shared__ float pr[2][96];
  int t = threadIdx.x, b = blockIdx.x;
  int k = b % 81, ptile = b / 81;
  int s = t >> 1, hh = t & 1, ch0 = hh * 48;
  int p = ptile * 128 + s;
  float cx = coords[p] + (float)(k / 9) - 4.0f;
  float cy = coords[P + p] + (float)(k % 9) - 4.0f;
  Tap4 tp = make_taps(cx, cy);
  const uint4* A4 = (const uint4*)(abf + (size_t)p * 96 + ch0);
  const uint4* G0 = (const uint4*)(gbf + tp.o[0] + ch0);
  const uint4* G1 = (const uint4*)(gbf + tp.o[1] + ch0);
  const uint4* G2 = (const uint4*)(gbf + tp.o[2] + ch0);
  const uint4* G3 = (const uint4*)(gbf + tp.o[3] + ch0);
  float w0 = tp.w[0], w1v = tp.w[1], w2v = tp.w[2], w3v = tp.w[3];
  float y[48];
#pragma unroll
  for (int i = 0; i < 6; ++i) {
    uint4 av = A4[i], v0 = G0[i], v1 = G1[i], v2 = G2[i], v3 = G3[i];
    unsigned au[4] = {av.x, av.y, av.z, av.w};
    unsigned b0[4] = {v0.x, v0.y, v0.z, v0.w};
    unsigned b1[4] = {v1.x, v1.y, v1.z, v1.w};
    unsigned b2[4] = {v2.x, v2.y, v2.z, v2.w};
    unsigned b3[4] = {v3.x, v3.y, v3.z, v3.w};
#pragma unroll
    for (int e = 0; e < 4; ++e) {
      y[i * 8 + e * 2 + 0] = bflo(au[e]) + w0 * bflo(b0[e]) + w1v * bflo(b1[e]) + w2v * bflo(b2[e]) + w3v * bflo(b3[e]);
      y[i * 8 + e * 2 + 1] = bfhi(au[e]) + w0 * bfhi(b0[e]) + w1v * bfhi(b1[e]) + w2v * bfhi(b2[e]) + w3v * bfhi(b3[e]);
    }
  }
  // store y1 bf16 (coalesced: lane pairs cover 192B per pixel)
  {
    unsigned short* yrow = y1 + ((size_t)k * P + p) * 96 + ch0;
#pragma unroll
    for (int i = 0; i < 6; ++i) {
      uint4 pk;
      pk.x = (unsigned)f2bf(y[i * 8 + 0]) | ((unsigned)f2bf(y[i * 8 + 1]) << 16);
      pk.y = (unsigned)f2bf(y[i * 8 + 2]) | ((unsigned)f2bf(y[i * 8 + 3]) << 16);
      pk.z = (unsigned)f2bf(y[i * 8 + 4]) | ((unsigned)f2bf(y[i * 8 + 5]) << 16);
      pk.w = (unsigned)f2bf(y[i * 8 + 6]) | ((unsigned)f2bf(y[i * 8 + 7]) << 16);
      *(uint4*)(yrow + i * 8) = pk;
    }
  }
  int slot = b & (NSLOT - 1);
#pragma unroll
  for (int j = 0; j < 48; ++j) m[ch0 + j][s] = y[j];
  __syncthreads();
  {
    int c = t & 127, seg = t >> 7;
    if (c < 96) {
      float acc = 0.f;
#pragma unroll 8
      for (int j = 0; j < 64; ++j) acc += m[c][seg * 64 + j];
      pr[seg][c] = acc;
    }
  }
  __syncthreads();
  if (t < 96) atomicAdd(&ws[S1SUM + slot * C1 + t], pr[0][t] + pr[1][t]);
  __syncthreads();
#pragma unroll
  for (int j = 0; j < 48; ++j) m[ch0 + j][s] = y[j] * y[j];
  __syncthreads();
  {
    int c = t & 127, seg = t >> 7;
    if (c < 96) {
      float acc = 0.f;
#pragma unroll 8
      for (int j = 0; j < 64; ++j) acc += m[c][seg * 64 + j];
      pr[seg][c] = acc;
    }
  }
  __syncthreads();
  if (t < 96) atomicAdd(&ws[S1SSQ + slot * C1 + t], pr[0][t] + pr[1][t]);
}

__global__ void k_finalize(float* __restrict__ ws, int sumO, int ssqO,
                           const float* __restrict__ gamma, const float* __restrict__ beta,
                           int sO, int tO, int C) {
  int c = threadIdx.x;
  if (c < C) {
    float su = 0.f, sq = 0.f;
    for (int s = 0; s < NSLOT; ++s) { su += ws[sumO + s * C + c]; sq += ws[ssqO + s * C + c]; }
    float mean = su * (1.0f / (float)NS);
    float var = sq * (1.0f / (float)NS) - mean * mean;
    float sc = gamma[c] * rsqrtf(var + EPSF);
    ws[sO + c] = sc;
    ws[tO + c] = beta[c] - mean * sc;
  }
}

// build x1 (bn1+relu of dense y1) into swizzled LDS; thread (s=t>>1, hh=t&1)
__device__ __forceinline__ void build_x1(const unsigned short* __restrict__ y1,
                                         const float* __restrict__ ws,
                                         unsigned short* lds, size_t n0, int t) {
  int s = t >> 1, hh = t & 1;
  const uint4* row = (const uint4*)(y1 + (n0 + s) * 96 + hh * 48);
  const float* s1p = ws + S1S;
  const float* t1p = ws + S1T;
  char* base = (char*)lds + s * 256;
#pragma unroll
  for (int i = 0; i < 6; ++i) {
    uint4 v = row[i];
    unsigned a[4] = {v.x, v.y, v.z, v.w};
    unsigned pk[4];
#pragma unroll
    for (int e = 0; e < 4; ++e) {
      int c = hh * 48 + i * 8 + e * 2;
      float xa = fmaxf(0.f, s1p[c] * bflo(a[e]) + t1p[c]);
      float xb = fmaxf(0.f, s1p[c + 1] * bfhi(a[e]) + t1p[c + 1]);
      pk[e] = (unsigned)f2bf(xa) | ((unsigned)f2bf(xb) << 16);
    }
    uint4 pkv; pkv.x = pk[0]; pkv.y = pk[1]; pkv.z = pk[2]; pkv.w = pk[3];
    *(uint4*)(base + ((hh * 96 + i * 16) ^ ((s & 7) << 4))) = pkv;
  }
}

// layer2 stats pass: y1 -> x1 -> MFMA1 -> stats2 (no y2 store)
__global__ __launch_bounds__(256) void k_l2stats(const unsigned short* __restrict__ y1,
                                                 float* __restrict__ ws,
                                                 const unsigned short* __restrict__ w2bf) {
  __shared__ unsigned short lds[128 * 128];
  __shared__ float sred[256];
  int t = threadIdx.x, b = blockIdx.x;
  size_t n0 = (size_t)b * 128;
  int slot = b & (NSLOT - 1);
  sred[t] = 0.f;
  build_x1(y1, ws, lds, n0, t);
  __syncthreads();
  int l = t & 63, wv = t >> 6;
  int o0w = wv * 32;
  int lr = l & 15, lh = l >> 4;
  bf16x8 af[2][3];
#pragma unroll
  for (int m = 0; m < 2; ++m)
#pragma unroll
    for (int kk = 0; kk < 3; ++kk)
      af[m][kk] = *(const bf16x8*)(const void*)(w2bf + (size_t)(o0w + m * 16 + lr) * 96 + kk * 32 + lh * 8);
  f32x4 acc[2][8];
  f32x4 zero4 = {0.f, 0.f, 0.f, 0.f};
#pragma unroll
  for (int m = 0; m < 2; ++m)
#pragma unroll
    for (int n = 0; n < 8; ++n) acc[m][n] = zero4;
#pragma unroll
  for (int kk = 0; kk < 3; ++kk)
#pragma unroll
    for (int n = 0; n < 8; ++n) {
      bf16x8 bfr = *(const bf16x8*)(const void*)((const char*)lds + (n * 16 + lr) * 256 + ((kk * 64 + lh * 16) ^ ((lr & 7) << 4)));
      acc[0][n] = __builtin_amdgcn_mfma_f32_16x16x32_bf16(af[0][kk], bfr, acc[0][n], 0, 0, 0);
      acc[1][n] = __builtin_amdgcn_mfma_f32_16x16x32_bf16(af[1][kk], bfr, acc[1][n], 0, 0, 0);
    }
  float ssum[8], sssq[8];
#pragma unroll
  for (int i = 0; i < 8; ++i) { ssum[i] = 0.f; sssq[i] = 0.f; }
#pragma unroll
  for (int m = 0; m < 2; ++m)
#pragma unroll
    for (int n = 0; n < 8; ++n) {
      f32x4 v = acc[m][n];
#pragma unroll
      for (int r = 0; r < 4; ++r) { float x = v[r]; ssum[m * 4 + r] += x; sssq[m * 4 + r] += x * x; }
    }
#pragma unroll
  for (int msk = 1; msk < 16; msk <<= 1)
#pragma unroll
    for (int i = 0; i < 8; ++i) { ssum[i] += __shfl_xor(ssum[i], msk); sssq[i] += __shfl_xor(sssq[i], msk); }
  if (lr == 0) {
#pragma unroll
    for (int m = 0; m < 2; ++m)
#pragma unroll
      for (int r = 0; r < 4; ++r) {
        int o = o0w + m * 16 + lh * 4 + r;
        atomicAdd(&sred[o], ssum[m * 4 + r]);
        atomicAdd(&sred[128 + o], sssq[m * 4 + r]);
      }
  }
  __syncthreads();
  if (t < 128) atomicAdd(&ws[S2SUM + slot * C2 + t], sred[t]);
  else atomicAdd(&ws[S2SSQ + slot * C2 + (t - 128)], sred[t]);
}

// fused layers 2+3: y1 -> x1 -> MFMA1 (y2 fp32 regs) -> bn2+relu -> x2 LDS -> MFMA2 -> y3 + stats3
__global__ __launch_bounds__(256) void k_l23(const unsigned short* __restrict__ y1,
                                             float* __restrict__ ws,
                                             const unsigned short* __restrict__ w2bf,
                                             const unsigned short* __restrict__ w3bf,
                                             unsigned short* __restrict__ y3) {
  __shared__ unsigned short lds[128 * 128];   // x1 -> x2 -> y3 stage
  __shared__ float sred[128];
  int t = threadIdx.x, b = blockIdx.x;
  size_t n0 = (size_t)b * 128;
  int slot = b & (NSLOT - 1);
  if (t < 128) sred[t] = 0.f;
  build_x1(y1, ws, lds, n0, t);
  __syncthreads();
  int l = t & 63, wv = t >> 6;
  int o0w = wv * 32;
  int lr = l & 15, lh = l >> 4;
  // ---- MFMA1: y2 = W2 @ x1 ----
  bf16x8 af[2][3];
#pragma unroll
  for (int m = 0; m < 2; ++m)
#pragma unroll
    for (int kk = 0; kk < 3; ++kk)
      af[m][kk] = *(const bf16x8*)(const void*)(w2bf + (size_t)(o0w + m * 16 + lr) * 96 + kk * 32 + lh * 8);
  f32x4 acc[2][8];
  f32x4 zero4 = {0.f, 0.f, 0.f, 0.f};
#pragma unroll
  for (int m = 0; m < 2; ++m)
#pragma unroll
    for (int n = 0; n < 8; ++n) acc[m][n] = zero4;
#pragma unroll
  for (int kk = 0; kk < 3; ++kk)
#pragma unroll
    for (int n = 0; n < 8; ++n) {
      bf16x8 bfr = *(const bf16x8*)(const void*)((const char*)lds + (n * 16 + lr) * 256 + ((kk * 64 + lh * 16) ^ ((lr & 7) << 4)));
      acc[0][n] = __builtin_amdgcn_mfma_f32_16x16x32_bf16(af[0][kk], bfr, acc[0][n], 0, 0, 0);
      acc[1][n] = __builtin_amdgcn_mfma_f32_16x16x32_bf16(af[1][kk], bfr, acc[1][n], 0, 0, 0);
    }
  __syncthreads();   // all x1 reads done; reuse lds for x2
  // ---- bn2+relu -> x2 (bf16) into swizzled LDS ----
  float s2v[2][4], t2v[2][4];
#pragma unroll
  for (int m = 0; m < 2; ++m)
#pragma unroll
    for (int r = 0; r < 4; ++r) {
      int c = o0w + m * 16 + lh * 4 + r;
      s2v[m][r] = ws[S2S + c];
      t2v[m][r] = ws[S2T + c];
    }
#pragma unroll
  for (int m = 0; m < 2; ++m)
#pragma unroll
    for (int n = 0; n < 8; ++n) {
      f32x4 v = acc[m][n];
      float x0 = fmaxf(0.f, s2v[m][0] * v[0] + t2v[m][0]);
      float x1v = fmaxf(0.f, s2v[m][1] * v[1] + t2v[m][1]);
      float x2v = fmaxf(0.f, s2v[m][2] * v[2] + t2v[m][2]);
      float x3 = fmaxf(0.f, s2v[m][3] * v[3] + t2v[m][3]);
      uint2 pk;
      pk.x = (unsigned)f2bf(x0) | ((unsigned)f2bf(x1v) << 16);
      pk.y = (unsigned)f2bf(x2v) | ((unsigned)f2bf(x3) << 16);
      int row = n * 16 + lr;
      *(uint2*)((char*)lds + row * 256 + ((o0w * 2 + m * 32 + lh * 8) ^ ((lr & 7) << 4))) = pk;
    }
  __syncthreads();
  // ---- MFMA2: y3 = W3 @ x2 ----
  int o2 = wv * 16;
  bf16x8 af2[4];
#pragma unroll
  for (int kk = 0; kk < 4; ++kk)
    af2[kk] = *(const bf16x8*)(const void*)(w3bf + (size_t)(o2 + lr) * 128 + kk * 32 + lh * 8);
  f32x4 acc2[8];
#pragma unroll
  for (int n = 0; n < 8; ++n) acc2[n] = zero4;
#pragma unroll
  for (int kk = 0; kk < 4; ++kk)
#pragma unroll
    for (int n = 0; n < 8; ++n) {
      bf16x8 bfr = *(const bf16x8*)(const void*)((const char*)lds + (n * 16 + lr) * 256 + ((kk * 64 + lh * 16) ^ ((lr & 7) << 4)));
      acc2[n] = __builtin_amdgcn_mfma_f32_16x16x32_bf16(af2[kk], bfr, acc2[n], 0, 0, 0);
    }
  // ---- stats3 ----
  float ssum[4], sssq[4];
#pragma unroll
  for (int i = 0; i < 4; ++i) { ssum[i] = 0.f; sssq[i] = 0.f; }
#pragma unroll
  for (int n = 0; n < 8; ++n) {
    f32x4 v = acc2[n];
#pragma unroll
    for (int r = 0; r < 4; ++r) { float x = v[r]; ssum[r] += x; sssq[r] += x * x; }
  }
#pragma unroll
  for (int msk = 1; msk < 16; msk <<= 1)
#pragma unroll
    for (int i = 0; i < 4; ++i) { ssum[i] += __shfl_xor(ssum[i], msk); sssq[i] += __shfl_xor(sssq[i], msk); }
  if (lr == 0) {
#pragma unroll
    for (int r = 0; r < 4; ++r) {
      int o = o2 + lh * 4 + r;
      atomicAdd(&sred[o], ssum[r]);
      atomicAdd(&sred[64 + o], sssq[r]);
    }
  }
  __syncthreads();   // x2 reads done; reuse lds as y3 stage [128][72]
#pragma unroll
  for (int n = 0; n < 8; ++n) {
    f32x4 v = acc2[n];
    uint2 pk;
    pk.x = (unsigned)f2bf(v[0]) | ((unsigned)f2bf(v[1]) << 16);
    pk.y = (unsigned)f2bf(v[2]) | ((unsigned)f2bf(v[3]) << 16);
    int row = n * 16 + lr, col = o2 + lh * 4;
    *(uint2*)&lds[row * 72 + col] = pk;
  }
  __syncthreads();
  {
    int row = t >> 1, half = t & 1;
    const uint4* src = (const uint4*)&lds[row * 72 + half * 32];
    uint4* dst = (uint4*)(y3 + (n0 + row) * 64 + half * 32);
#pragma unroll
    for (int j = 0; j < 4; ++j) dst[j] = src[j];
  }
  if (t < 64) atomicAdd(&ws[S3SUM + slot * C3 + t], sred[t]);
  else if (t < 128) atomicAdd(&ws[S3SSQ + slot * C3 + (t - 64)], sred[t]);
}

// layer4: cost = w4 . relu(bn3(y3)) + b4
__global__ __launch_bounds__(256) void k_layer4(const unsigned short* __restrict__ y3,
                                                float* __restrict__ ws,
                                                const float* __restrict__ w4,
                                                const float* __restrict__ b4) {
  int n = blockIdx.x * 256 + threadIdx.x;
  const float* s3p = ws + S3S;
  const float* t3p = ws + S3T;
  const uint4* row = (const uint4*)(y3 + (size_t)n * C3);
  float acc = 0.f;
#pragma unroll
  for (int j = 0; j < 8; ++j) {
    uint4 v = row[j];
    unsigned arr[4] = {v.x, v.y, v.z, v.w};
#pragma unroll
    for (int e = 0; e < 4; ++e) {
      int c = j * 8 + e * 2;
      acc += fmaxf(0.f, s3p[c] * bflo(arr[e]) + t3p[c]) * w4[c];
      acc += fmaxf(0.f, s3p[c + 1] * bfhi(arr[e]) + t3p[c + 1]) * w4[c + 1];
    }
  }
  ws[COST_OFF + n] = acc + b4[0];
}

// DAP: out[l,p] = sum_k wdap[l,k] * cost[k,p]
__global__ __launch_bounds__(256) void k_dap(const float* __restrict__ ws,
                                             const float* __restrict__ wdap,
                                             float* __restrict__ out) {
  __shared__ float wd[DD * DD];
  int t = threadIdx.x;
  for (int i = t; i < DD * DD; i += 256) wd[i] = wdap[i];
  __syncthreads();
  int p = blockIdx.x * 64 + (t & 63);
  int lg = t >> 6;
  const float* cost = ws + COST_OFF;
  float cr[81];
#pragma unroll
  for (int kk = 0; kk < 81; ++kk) cr[kk] = cost[kk * P + p];
  int l0 = lg * 21;
  int l1 = min(81, l0 + 21);
  for (int l = l0; l < l1; ++l) {
    float acc = 0.f;
#pragma unroll
    for (int kk = 0; kk < 81; ++kk) acc += wd[l * 81 + kk] * cr[kk];
    out[(size_t)l * P + p] = acc;
  }
}

__global__ void k_marker(float* out) { out[0] = 1.0e30f; }

extern "C" void kernel_launch(void* const* d_in, const int* in_sizes, int n_in,
                              void* d_out, int out_size, void* d_ws, size_t ws_size,
                              hipStream_t stream) {
  const float* f1 = (const float*)d_in[0];
  const float* f2 = (const float*)d_in[1];
  const float* coords = (const float*)d_in[2];
  const float* w1 = (const float*)d_in[3];
  const float* g1 = (const float*)d_in[4];
  const float* be1 = (const float*)d_in[5];
  const float* w2 = (const float*)d_in[6];
  const float* g2 = (const float*)d_in[7];
  const float* be2 = (const float*)d_in[8];
  const float* w3 = (const float*)d_in[9];
  const float* g3 = (const float*)d_in[10];
  const float* be3 = (const float*)d_in[11];
  const float* w4 = (const float*)d_in[12];
  const float* b4 = (const float*)d_in[13];
  const float* wdap = (const float*)d_in[14];
  float* out = (float*)d_out;
  float* ws = (float*)d_ws;

  if (ws_size < WS_NEEDED) {
    k_marker<<<1, 1, 0, stream>>>(out);
    return;
  }
  unsigned short* abf = (unsigned short*)((char*)d_ws + A_BYTE);
  unsigned short* gbf = (unsigned short*)((char*)d_ws + G_BYTE);
  unsigned short* w2bf = (unsigned short*)((char*)d_ws + W2BF_BYTE);
  unsigned short* w3bf = (unsigned short*)((char*)d_ws + W3BF_BYTE);
  unsigned short* y1 = (unsigned short*)((char*)d_ws + Y1_BYTE);
  unsigned short* y3 = (unsigned short*)((char*)d_ws + Y3_BYTE);

  hipMemsetAsync(d_ws, 0, (size_t)STATS_ZERO_FLOATS * 4, stream);
  k_prep<<<128, 256, 0, stream>>>(f1, f2, w1, abf, gbf);
  k_wprep<<<80, 256, 0, stream>>>(w2, w3, w2bf, w3bf);
  k_sample<<<5184, 256, 0, stream>>>(coords, ws, abf, gbf, y1);
  k_finalize<<<1, 128, 0, stream>>>(ws, S1SUM, S1SSQ, g1, be1, S1S, S1T, C1);
  k_l2stats<<<5184, 256, 0, stream>>>(y1, ws, w2bf);
  k_finalize<<<1, 128, 0, stream>>>(ws, S2SUM, S2SSQ, g2, be2, S2S, S2T, C2);
  k_l23<<<5184, 256, 0, stream>>>(y1, ws, w2bf, w3bf, y3);
  k_finalize<<<1, 128, 0, stream>>>(ws, S3SUM, S3SSQ, g3, be3, S3S, S3T, C3);
  k_layer4<<<2592, 256, 0, stream>>>(y3, ws, w4, b4);
  k_dap<<<128, 256, 0, stream>>>(ws, wdap, out);
}

// Round 5
// 413.543 us; speedup vs baseline: 4.4787x; 1.0439x over previous
//
#include <hip/hip_runtime.h>

#define H 64
#define W 128
#define P 8192        // H*W
#define DD 81
#define NS 663552     // DD*P
#define C1 96
#define C2 128
#define C3 64
#define EPSF 1e-5f
#define NSLOT 128

// LDS row strides in shorts (odd multiples of 8 shorts = odd x 16B -> even bank phases)
#define X1S 104       // 208B = 13*16B
#define X2S 136       // 272B = 17*16B
#define Y3S 72        // 144B = 9*16B

typedef __attribute__((ext_vector_type(8))) short bf16x8;
typedef __attribute__((ext_vector_type(4))) float f32x4;

// ---- workspace layout ----
// float-indexed region
#define S1SUM 0
#define S1SSQ (S1SUM + NSLOT * C1)
#define S2SUM (S1SSQ + NSLOT * C1)
#define S2SSQ (S2SUM + NSLOT * C2)
#define S3SUM (S2SSQ + NSLOT * C2)
#define S3SSQ (S3SUM + NSLOT * C3)
#define STATS_ZERO_FLOATS (S3SSQ + NSLOT * C3)  // 73728
#define S1Sc 73728
#define S1Tc (S1Sc + C1)
#define S2Sc (S1Tc + C1)
#define S2Tc (S2Sc + C2)
#define S3Sc (S2Tc + C2)
#define S3Tc (S3Sc + C3)
#define COST_OFF 74304
#define FLOAT_END (COST_OFF + NS)
// byte-indexed region
#define A_BYTE   ((size_t)FLOAT_END * 4)
#define G_BYTE   (A_BYTE + (size_t)P * 96 * 2)
#define W2BF_BYTE (G_BYTE + (size_t)P * 96 * 2)
#define W3BF_BYTE (W2BF_BYTE + (size_t)C2 * C1 * 2)
#define Y1_BYTE  (W3BF_BYTE + (size_t)C3 * C2 * 2)
#define Y3_BYTE  (Y1_BYTE + (size_t)NS * C1 * 2)
#define WS_NEEDED (Y3_BYTE + (size_t)NS * C3 * 2)

__device__ __forceinline__ unsigned short f2bf(float f) {
  unsigned u = __float_as_uint(f);
  return (unsigned short)((u + 0x7fffu + ((u >> 16) & 1u)) >> 16);
}
__device__ __forceinline__ float bflo(unsigned u) { return __uint_as_float(u << 16); }
__device__ __forceinline__ float bfhi(unsigned u) { return __uint_as_float(u & 0xffff0000u); }
__device__ __forceinline__ float bfu(unsigned short v) { return __uint_as_float((unsigned)v << 16); }

struct Tap4 { int o[4]; float w[4]; };

__device__ __forceinline__ Tap4 make_taps(float cx, float cy) {
  Tap4 tp;
  float x0f = floorf(cx), y0f = floorf(cy);
  float fx = cx - x0f, fy = cy - y0f;
  int ix0 = (int)x0f, iy0 = (int)y0f;
  int ix1 = ix0 + 1, iy1 = iy0 + 1;
  float vx0 = (ix0 >= 0 && ix0 < W) ? 1.f : 0.f;
  float vx1 = (ix1 >= 0 && ix1 < W) ? 1.f : 0.f;
  float vy0 = (iy0 >= 0 && iy0 < H) ? 1.f : 0.f;
  float vy1 = (iy1 >= 0 && iy1 < H) ? 1.f : 0.f;
  int cx0 = min(max(ix0, 0), W - 1), cx1 = min(max(ix1, 0), W - 1);
  int cy0 = min(max(iy0, 0), H - 1), cy1 = min(max(iy1, 0), H - 1);
  tp.w[0] = (1.f - fy) * (1.f - fx) * vy0 * vx0;
  tp.w[1] = (1.f - fy) * fx * vy0 * vx1;
  tp.w[2] = fy * (1.f - fx) * vy1 * vx0;
  tp.w[3] = fy * fx * vy1 * vx1;
  tp.o[0] = (cy0 * W + cx0) * 96;
  tp.o[1] = (cy0 * W + cx1) * 96;
  tp.o[2] = (cy1 * W + cx0) * 96;
  tp.o[3] = (cy1 * W + cx1) * 96;
  return tp;
}

// a = w1[:, :128] @ f1, g = w1[:, 128:] @ f2  -> bf16, pixel-major [p][96]
__global__ __launch_bounds__(256) void k_prep(const float* __restrict__ f1,
                                              const float* __restrict__ f2,
                                              const float* __restrict__ w1,
                                              unsigned short* __restrict__ abf,
                                              unsigned short* __restrict__ gbf) {
  __shared__ float tile[128][64];
  int t = threadIdx.x;
  int p0 = blockIdx.x * 64;
  int px = t & 63, q = t >> 6;
  int c0 = q * 24;
  for (int pass = 0; pass < 2; ++pass) {
    const float* src = pass ? f2 : f1;
    unsigned short* dst = pass ? gbf : abf;
    int koff = pass ? 128 : 0;
    __syncthreads();
    for (int idx = t; idx < 8192; idx += 256) {
      int kk = idx >> 6, xx = idx & 63;
      tile[kk][xx] = src[kk * P + p0 + xx];
    }
    __syncthreads();
    float acc[24];
#pragma unroll
    for (int i = 0; i < 24; ++i) acc[i] = 0.f;
    for (int kk = 0; kk < 128; ++kk) {
      float fv = tile[kk][px];
#pragma unroll
      for (int i = 0; i < 24; ++i)
        acc[i] += w1[(c0 + i) * 256 + koff + kk] * fv;
    }
    unsigned short* orow = dst + (size_t)(p0 + px) * 96 + c0;
#pragma unroll
    for (int i = 0; i < 24; i += 8) {
      uint4 pk;
      pk.x = (unsigned)f2bf(acc[i + 0]) | ((unsigned)f2bf(acc[i + 1]) << 16);
      pk.y = (unsigned)f2bf(acc[i + 2]) | ((unsigned)f2bf(acc[i + 3]) << 16);
      pk.z = (unsigned)f2bf(acc[i + 4]) | ((unsigned)f2bf(acc[i + 5]) << 16);
      pk.w = (unsigned)f2bf(acc[i + 6]) | ((unsigned)f2bf(acc[i + 7]) << 16);
      *(uint4*)(orow + i) = pk;
    }
  }
}

__global__ void k_wprep(const float* __restrict__ w2, const float* __restrict__ w3,
                        unsigned short* __restrict__ w2bf, unsigned short* __restrict__ w3bf) {
  int idx = blockIdx.x * 256 + threadIdx.x;
  if (idx < C2 * C1) w2bf[idx] = f2bf(w2[idx]);
  else if (idx < C2 * C1 + C3 * C2) w3bf[idx - C2 * C1] = f2bf(w3[idx - C2 * C1]);
}

// gather once: y1 = a + bilinear(g) -> bf16 global store + stats1 (LDS column sums)
__global__ __launch_bounds__(256) void k_sample(const float* __restrict__ coords,
                                                float* __restrict__ ws,
                                                const unsigned short* __restrict__ abf,
                                                const unsigned short* __restrict__ gbf,
                                                unsigned short* __restrict__ y1) {
  __shared__ unsigned short yt[128 * X1S];   // 26.6KB
  int t = threadIdx.x, b = blockIdx.x;
  int k = b % 81, ptile = b / 81;
  int s = t >> 1, hh = t & 1, ch0 = hh * 48;
  int p = ptile * 128 + s;
  float cx = coords[p] + (float)(k / 9) - 4.0f;
  float cy = coords[P + p] + (float)(k % 9) - 4.0f;
  Tap4 tp = make_taps(cx, cy);
  const uint4* A4 = (const uint4*)(abf + (size_t)p * 96 + ch0);
  const uint4* G0 = (const uint4*)(gbf + tp.o[0] + ch0);
  const uint4* G1 = (const uint4*)(gbf + tp.o[1] + ch0);
  const uint4* G2 = (const uint4*)(gbf + tp.o[2] + ch0);
  const uint4* G3 = (const uint4*)(gbf + tp.o[3] + ch0);
  float w0 = tp.w[0], w1v = tp.w[1], w2v = tp.w[2], w3v = tp.w[3];
  unsigned short* yrow = y1 + ((size_t)k * P + p) * 96 + ch0;
  unsigned short* lbase = yt + s * X1S + ch0;
#pragma unroll
  for (int i = 0; i < 6; ++i) {
    uint4 av = A4[i], v0 = G0[i], v1 = G1[i], v2 = G2[i], v3 = G3[i];
    unsigned au[4] = {av.x, av.y, av.z, av.w};
    unsigned b0[4] = {v0.x, v0.y, v0.z, v0.w};
    unsigned b1[4] = {v1.x, v1.y, v1.z, v1.w};
    unsigned b2[4] = {v2.x, v2.y, v2.z, v2.w};
    unsigned b3[4] = {v3.x, v3.y, v3.z, v3.w};
    unsigned pk[4];
#pragma unroll
    for (int e = 0; e < 4; ++e) {
      float ya = bflo(au[e]) + w0 * bflo(b0[e]) + w1v * bflo(b1[e]) + w2v * bflo(b2[e]) + w3v * bflo(b3[e]);
      float yb = bfhi(au[e]) + w0 * bfhi(b0[e]) + w1v * bfhi(b1[e]) + w2v * bfhi(b2[e]) + w3v * bfhi(b3[e]);
      pk[e] = (unsigned)f2bf(ya) | ((unsigned)f2bf(yb) << 16);
    }
    uint4 pkv; pkv.x = pk[0]; pkv.y = pk[1]; pkv.z = pk[2]; pkv.w = pk[3];
    *(uint4*)(yrow + i * 8) = pkv;
    *(uint4*)(lbase + i * 8) = pkv;
  }
  __syncthreads();
  if (t < 192) {
    int ch = t % 96, half = t / 96;
    float su = 0.f, sq = 0.f;
    const unsigned short* col = yt + half * 64 * X1S + ch;
#pragma unroll 8
    for (int j = 0; j < 64; ++j) {
      float f = bfu(col[j * X1S]);
      su += f;
      sq = fmaf(f, f, sq);
    }
    int slot = b & (NSLOT - 1);
    atomicAdd(&ws[S1SUM + slot * C1 + ch], su);
    atomicAdd(&ws[S1SSQ + slot * C1 + ch], sq);
  }
}

__global__ void k_finalize(float* __restrict__ ws, int sumO, int ssqO,
                           const float* __restrict__ gamma, const float* __restrict__ beta,
                           int sO, int tO, int C) {
  int c = threadIdx.x;
  if (c < C) {
    float su = 0.f, sq = 0.f;
    for (int s = 0; s < NSLOT; ++s) { su += ws[sumO + s * C + c]; sq += ws[ssqO + s * C + c]; }
    float mean = su * (1.0f / (float)NS);
    float var = sq * (1.0f / (float)NS) - mean * mean;
    float sc = gamma[c] * rsqrtf(var + EPSF);
    ws[sO + c] = sc;
    ws[tO + c] = beta[c] - mean * sc;
  }
}

// build x1 (bn1+relu of dense y1) into [128][X1S] LDS tile
__device__ __forceinline__ void build_x1(const unsigned short* __restrict__ y1,
                                         const float* __restrict__ ws,
                                         unsigned short* lds, size_t n0, int t) {
  int s = t >> 1, hh = t & 1;
  const uint4* row = (const uint4*)(y1 + (n0 + s) * 96 + hh * 48);
  const float* s1p = ws + S1Sc;
  const float* t1p = ws + S1Tc;
  unsigned short* base = lds + s * X1S + hh * 48;
#pragma unroll
  for (int i = 0; i < 6; ++i) {
    uint4 v = row[i];
    unsigned a[4] = {v.x, v.y, v.z, v.w};
    unsigned pk[4];
#pragma unroll
    for (int e = 0; e < 4; ++e) {
      int c = hh * 48 + i * 8 + e * 2;
      float xa = fmaxf(0.f, fmaf(s1p[c], bflo(a[e]), t1p[c]));
      float xb = fmaxf(0.f, fmaf(s1p[c + 1], bfhi(a[e]), t1p[c + 1]));
      pk[e] = (unsigned)f2bf(xa) | ((unsigned)f2bf(xb) << 16);
    }
    uint4 pkv; pkv.x = pk[0]; pkv.y = pk[1]; pkv.z = pk[2]; pkv.w = pk[3];
    *(uint4*)(base + i * 8) = pkv;
  }
}

// layer2 stats pass: y1 -> x1 -> MFMA1 -> stats2 (no y2 store)
__global__ __launch_bounds__(256) void k_l2stats(const unsigned short* __restrict__ y1,
                                                 float* __restrict__ ws,
                                                 const unsigned short* __restrict__ w2bf) {
  __shared__ unsigned short x1t[128 * X1S];
  __shared__ float sred[256];
  int t = threadIdx.x, b = blockIdx.x;
  size_t n0 = (size_t)b * 128;
  int slot = b & (NSLOT - 1);
  sred[t] = 0.f;
  build_x1(y1, ws, x1t, n0, t);
  __syncthreads();
  int l = t & 63, wv = t >> 6;
  int o0w = wv * 32;
  int lr = l & 15, lh = l >> 4;
  bf16x8 af[2][3];
#pragma unroll
  for (int m = 0; m < 2; ++m)
#pragma unroll
    for (int kk = 0; kk < 3; ++kk)
      af[m][kk] = *(const bf16x8*)(const void*)(w2bf + (size_t)(o0w + m * 16 + lr) * 96 + kk * 32 + lh * 8);
  f32x4 acc[2][8];
  f32x4 zero4 = {0.f, 0.f, 0.f, 0.f};
#pragma unroll
  for (int m = 0; m < 2; ++m)
#pragma unroll
    for (int n = 0; n < 8; ++n) acc[m][n] = zero4;
#pragma unroll
  for (int kk = 0; kk < 3; ++kk)
#pragma unroll
    for (int n = 0; n < 8; ++n) {
      bf16x8 bfr = *(const bf16x8*)(const void*)(x1t + (n * 16 + lr) * X1S + kk * 32 + lh * 8);
      acc[0][n] = __builtin_amdgcn_mfma_f32_16x16x32_bf16(af[0][kk], bfr, acc[0][n], 0, 0, 0);
      acc[1][n] = __builtin_amdgcn_mfma_f32_16x16x32_bf16(af[1][kk], bfr, acc[1][n], 0, 0, 0);
    }
  float ssum[8], sssq[8];
#pragma unroll
  for (int i = 0; i < 8; ++i) { ssum[i] = 0.f; sssq[i] = 0.f; }
#pragma unroll
  for (int m = 0; m < 2; ++m)
#pragma unroll
    for (int n = 0; n < 8; ++n) {
      f32x4 v = acc[m][n];
#pragma unroll
      for (int r = 0; r < 4; ++r) { float x = v[r]; ssum[m * 4 + r] += x; sssq[m * 4 + r] = fmaf(x, x, sssq[m * 4 + r]); }
    }
#pragma unroll
  for (int msk = 1; msk < 16; msk <<= 1)
#pragma unroll
    for (int i = 0; i < 8; ++i) { ssum[i] += __shfl_xor(ssum[i], msk); sssq[i] += __shfl_xor(sssq[i], msk); }
  if (lr == 0) {
#pragma unroll
    for (int m = 0; m < 2; ++m)
#pragma unroll
      for (int r = 0; r < 4; ++r) {
        int o = o0w + m * 16 + lh * 4 + r;
        atomicAdd(&sred[o], ssum[m * 4 + r]);
        atomicAdd(&sred[128 + o], sssq[m * 4 + r]);
      }
  }
  __syncthreads();
  if (t < 128) atomicAdd(&ws[S2SUM + slot * C2 + t], sred[t]);
  else atomicAdd(&ws[S2SSQ + slot * C2 + (t - 128)], sred[t]);
}

// fused layers 2+3: y1 -> x1 -> MFMA1 (y2 fp32 regs) -> bn2+relu -> x2 halves -> MFMA2 -> y3 + stats3
__global__ __launch_bounds__(256) void k_l23(const unsigned short* __restrict__ y1,
                                             float* __restrict__ ws,
                                             const unsigned short* __restrict__ w2bf,
                                             const unsigned short* __restrict__ w3bf,
                                             unsigned short* __restrict__ y3) {
  __shared__ unsigned short ldss[128 * X1S];   // x1 [128][104]; later x2-half [64][136]@0, y3 halves
  __shared__ float sred[128];
  int t = threadIdx.x, b = blockIdx.x;
  size_t n0 = (size_t)b * 128;
  int slot = b & (NSLOT - 1);
  if (t < 128) sred[t] = 0.f;
  build_x1(y1, ws, ldss, n0, t);
  __syncthreads();
  int l = t & 63, wv = t >> 6;
  int o0w = wv * 32;
  int lr = l & 15, lh = l >> 4;
  // ---- MFMA1: y2 = W2 @ x1 ----
  bf16x8 af[2][3];
#pragma unroll
  for (int m = 0; m < 2; ++m)
#pragma unroll
    for (int kk = 0; kk < 3; ++kk)
      af[m][kk] = *(const bf16x8*)(const void*)(w2bf + (size_t)(o0w + m * 16 + lr) * 96 + kk * 32 + lh * 8);
  f32x4 acc[2][8];
  f32x4 zero4 = {0.f, 0.f, 0.f, 0.f};
#pragma unroll
  for (int m = 0; m < 2; ++m)
#pragma unroll
    for (int n = 0; n < 8; ++n) acc[m][n] = zero4;
#pragma unroll
  for (int kk = 0; kk < 3; ++kk)
#pragma unroll
    for (int n = 0; n < 8; ++n) {
      bf16x8 bfr = *(const bf16x8*)(const void*)(ldss + (n * 16 + lr) * X1S + kk * 32 + lh * 8);
      acc[0][n] = __builtin_amdgcn_mfma_f32_16x16x32_bf16(af[0][kk], bfr, acc[0][n], 0, 0, 0);
      acc[1][n] = __builtin_amdgcn_mfma_f32_16x16x32_bf16(af[1][kk], bfr, acc[1][n], 0, 0, 0);
    }
  // bn2 params + W3 A-frags
  float s2v[2][4], t2v[2][4];
#pragma unroll
  for (int m = 0; m < 2; ++m)
#pragma unroll
    for (int r = 0; r < 4; ++r) {
      int c = o0w + m * 16 + lh * 4 + r;
      s2v[m][r] = ws[S2Sc + c];
      t2v[m][r] = ws[S2Tc + c];
    }
  int o2 = wv * 16;
  bf16x8 af2[4];
#pragma unroll
  for (int kk = 0; kk < 4; ++kk)
    af2[kk] = *(const bf16x8*)(const void*)(w3bf + (size_t)(o2 + lr) * 128 + kk * 32 + lh * 8);
  unsigned short* x2s = ldss;               // [64][X2S] = 17408B
  unsigned short* y3a = ldss + 8704;        // [64][Y3S] = 9216B at byte 17408
  float ssum[4] = {0.f, 0.f, 0.f, 0.f}, sssq[4] = {0.f, 0.f, 0.f, 0.f};
#pragma unroll
  for (int h = 0; h < 2; ++h) {
    __syncthreads();   // h0: MFMA1 reads done; h1: MFMA2a reads done before overwrite
    // stage x2 half: pixels h*64 .. h*64+63
#pragma unroll
    for (int m = 0; m < 2; ++m)
#pragma unroll
      for (int n2 = 0; n2 < 4; ++n2) {
        f32x4 v = acc[m][h * 4 + n2];
        float x0 = fmaxf(0.f, fmaf(s2v[m][0], v[0], t2v[m][0]));
        float x1v = fmaxf(0.f, fmaf(s2v[m][1], v[1], t2v[m][1]));
        float x2v = fmaxf(0.f, fmaf(s2v[m][2], v[2], t2v[m][2]));
        float x3 = fmaxf(0.f, fmaf(s2v[m][3], v[3], t2v[m][3]));
        uint2 pk;
        pk.x = (unsigned)f2bf(x0) | ((unsigned)f2bf(x1v) << 16);
        pk.y = (unsigned)f2bf(x2v) | ((unsigned)f2bf(x3) << 16);
        *(uint2*)(x2s + (n2 * 16 + lr) * X2S + o0w + m * 16 + lh * 4) = pk;
      }
    __syncthreads();
    // MFMA2 on this half
    f32x4 acc2[4];
#pragma unroll
    for (int n2 = 0; n2 < 4; ++n2) acc2[n2] = zero4;
#pragma unroll
    for (int kk = 0; kk < 4; ++kk)
#pragma unroll
      for (int n2 = 0; n2 < 4; ++n2) {
        bf16x8 bfr = *(const bf16x8*)(const void*)(x2s + (n2 * 16 + lr) * X2S + kk * 32 + lh * 8);
        acc2[n2] = __builtin_amdgcn_mfma_f32_16x16x32_bf16(af2[kk], bfr, acc2[n2], 0, 0, 0);
      }
#pragma unroll
    for (int n2 = 0; n2 < 4; ++n2) {
      f32x4 v = acc2[n2];
#pragma unroll
      for (int r = 0; r < 4; ++r) { float x = v[r]; ssum[r] += x; sssq[r] = fmaf(x, x, sssq[r]); }
    }
    __syncthreads();   // x2 reads done before y3-half stage overwrites (needed for h=1)
    unsigned short* dst = h ? ldss : y3a;   // h0 half at byte 17408, h1 half at byte 0
#pragma unroll
    for (int n2 = 0; n2 < 4; ++n2) {
      f32x4 v = acc2[n2];
      uint2 pk;
      pk.x = (unsigned)f2bf(v[0]) | ((unsigned)f2bf(v[1]) << 16);
      pk.y = (unsigned)f2bf(v[2]) | ((unsigned)f2bf(v[3]) << 16);
      *(uint2*)(dst + (n2 * 16 + lr) * Y3S + o2 + lh * 4) = pk;
    }
  }
  // stats3 reduce
#pragma unroll
  for (int msk = 1; msk < 16; msk <<= 1)
#pragma unroll
    for (int i = 0; i < 4; ++i) { ssum[i] += __shfl_xor(ssum[i], msk); sssq[i] += __shfl_xor(sssq[i], msk); }
  if (lr == 0) {
#pragma unroll
    for (int r = 0; r < 4; ++r) {
      int o = o2 + lh * 4 + r;
      atomicAdd(&sred[o], ssum[r]);
      atomicAdd(&sred[64 + o], sssq[r]);
    }
  }
  __syncthreads();
  // coalesced y3 store from the two staged halves
  {
    int row = t >> 1, hf = t & 1;
    const unsigned short* src = (row < 64) ? (y3a + row * Y3S) : (ldss + (row - 64) * Y3S);
    const uint4* s4 = (const uint4*)(src + hf * 32);
    uint4* dst = (uint4*)(y3 + (n0 + row) * 64 + hf * 32);
#pragma unroll
    for (int j = 0; j < 4; ++j) dst[j] = s4[j];
  }
  if (t < 64) atomicAdd(&ws[S3SUM + slot * C3 + t], sred[t]);
  else if (t < 128) atomicAdd(&ws[S3SSQ + slot * C3 + (t - 64)], sred[t]);
}

// layer4: cost = w4 . relu(bn3(y3)) + b4
__global__ __launch_bounds__(256) void k_layer4(const unsigned short* __restrict__ y3,
                                                float* __restrict__ ws,
                                                const float* __restrict__ w4,
                                                const float* __restrict__ b4) {
  int n = blockIdx.x * 256 + threadIdx.x;
  const float* s3p = ws + S3Sc;
  const float* t3p = ws + S3Tc;
  const uint4* row = (const uint4*)(y3 + (size_t)n * C3);
  float acc = 0.f;
#pragma unroll
  for (int j = 0; j < 8; ++j) {
    uint4 v = row[j];
    unsigned arr[4] = {v.x, v.y, v.z, v.w};
#pragma unroll
    for (int e = 0; e < 4; ++e) {
      int c = j * 8 + e * 2;
      acc += fmaxf(0.f, fmaf(s3p[c], bflo(arr[e]), t3p[c])) * w4[c];
      acc += fmaxf(0.f, fmaf(s3p[c + 1], bfhi(arr[e]), t3p[c + 1])) * w4[c + 1];
    }
  }
  ws[COST_OFF + n] = acc + b4[0];
}

// DAP: out[l,p] = sum_k wdap[l,k] * cost[k,p]
__global__ __launch_bounds__(256) void k_dap(const float* __restrict__ ws,
                                             const float* __restrict__ wdap,
                                             float* __restrict__ out) {
  __shared__ float wd[DD * DD];
  int t = threadIdx.x;
  for (int i = t; i < DD * DD; i += 256) wd[i] = wdap[i];
  __syncthreads();
  int p = blockIdx.x * 64 + (t & 63);
  int lg = t >> 6;
  const float* cost = ws + COST_OFF;
  float cr[81];
#pragma unroll
  for (int kk = 0; kk < 81; ++kk) cr[kk] = cost[kk * P + p];
  int l0 = lg * 21;
  int l1 = min(81, l0 + 21);
  for (int l = l0; l < l1; ++l) {
    float acc = 0.f;
#pragma unroll
    for (int kk = 0; kk < 81; ++kk) acc += wd[l * 81 + kk] * cr[kk];
    out[(size_t)l * P + p] = acc;
  }
}

__global__ void k_marker(float* out) { out[0] = 1.0e30f; }

extern "C" void kernel_launch(void* const* d_in, const int* in_sizes, int n_in,
                              void* d_out, int out_size, void* d_ws, size_t ws_size,
                              hipStream_t stream) {
  const float* f1 = (const float*)d_in[0];
  const float* f2 = (const float*)d_in[1];
  const float* coords = (const float*)d_in[2];
  const float* w1 = (const float*)d_in[3];
  const float* g1 = (const float*)d_in[4];
  const float* be1 = (const float*)d_in[5];
  const float* w2 = (const float*)d_in[6];
  const float* g2 = (const float*)d_in[7];
  const float* be2 = (const float*)d_in[8];
  const float* w3 = (const float*)d_in[9];
  const float* g3 = (const float*)d_in[10];
  const float* be3 = (const float*)d_in[11];
  const float* w4 = (const float*)d_in[12];
  const float* b4 = (const float*)d_in[13];
  const float* wdap = (const float*)d_in[14];
  float* out = (float*)d_out;
  float* ws = (float*)d_ws;

  if (ws_size < WS_NEEDED) {
    k_marker<<<1, 1, 0, stream>>>(out);
    return;
  }
  unsigned short* abf = (unsigned short*)((char*)d_ws + A_BYTE);
  unsigned short* gbf = (unsigned short*)((char*)d_ws + G_BYTE);
  unsigned short* w2bf = (unsigned short*)((char*)d_ws + W2BF_BYTE);
  unsigned short* w3bf = (unsigned short*)((char*)d_ws + W3BF_BYTE);
  unsigned short* y1 = (unsigned short*)((char*)d_ws + Y1_BYTE);
  unsigned short* y3 = (unsigned short*)((char*)d_ws + Y3_BYTE);

  hipMemsetAsync(d_ws, 0, (size_t)STATS_ZERO_FLOATS * 4, stream);
  k_prep<<<128, 256, 0, stream>>>(f1, f2, w1, abf, gbf);
  k_wprep<<<80, 256, 0, stream>>>(w2, w3, w2bf, w3bf);
  k_sample<<<5184, 256, 0, stream>>>(coords, ws, abf, gbf, y1);
  k_finalize<<<1, 128, 0, stream>>>(ws, S1SUM, S1SSQ, g1, be1, S1Sc, S1Tc, C1);
  k_l2stats<<<5184, 256, 0, stream>>>(y1, ws, w2bf);
  k_finalize<<<1, 128, 0, stream>>>(ws, S2SUM, S2SSQ, g2, be2, S2Sc, S2Tc, C2);
  k_l23<<<5184, 256, 0, stream>>>(y1, ws, w2bf, w3bf, y3);
  k_finalize<<<1, 128, 0, stream>>>(ws, S3SUM, S3SSQ, g3, be3, S3Sc, S3Tc, C3);
  k_layer4<<<2592, 256, 0, stream>>>(y3, ws, w4, b4);
  k_dap<<<128, 256, 0, stream>>>(ws, wdap, out);
}

// Round 6
// 387.595 us; speedup vs baseline: 4.7785x; 1.0669x over previous
//
#include <hip/hip_runtime.h>

#define H 64
#define W 128
#define P 8192        // H*W
#define DD 81
#define NS 663552     // DD*P
#define C1 96
#define C2 128
#define C3 64
#define EPSF 1e-5f
#define NSLOT 128

// LDS row strides in shorts (odd multiples of 8 shorts = odd x 16B -> even bank phases)
#define X1S 104       // 208B = 13*16B
#define X2S 136       // 272B = 17*16B
#define Y3S 72        // 144B = 9*16B

typedef __attribute__((ext_vector_type(8))) short bf16x8;
typedef __attribute__((ext_vector_type(4))) float f32x4;

// ---- workspace layout ----
#define S1SUM 0
#define S1SSQ (S1SUM + NSLOT * C1)
#define S2SUM (S1SSQ + NSLOT * C1)
#define S2SSQ (S2SUM + NSLOT * C2)
#define S3SUM (S2SSQ + NSLOT * C2)
#define S3SSQ (S3SUM + NSLOT * C3)
#define STATS_ZERO_FLOATS (S3SSQ + NSLOT * C3)  // 73728
#define S1Sc 73728
#define S1Tc (S1Sc + C1)
#define S2Sc (S1Tc + C1)
#define S2Tc (S2Sc + C2)
#define S3Sc (S2Tc + C2)
#define S3Tc (S3Sc + C3)
#define COST_OFF 74304
#define FLOAT_END (COST_OFF + NS)
// byte-indexed region
#define A_BYTE   ((size_t)FLOAT_END * 4)
#define G_BYTE   (A_BYTE + (size_t)P * 96 * 2)
#define W2BF_BYTE (G_BYTE + (size_t)P * 96 * 2)
#define W3BF_BYTE (W2BF_BYTE + (size_t)C2 * C1 * 2)
#define Y1_BYTE  (W3BF_BYTE + (size_t)C3 * C2 * 2)
#define Y3_BYTE  (Y1_BYTE + (size_t)NS * C1 * 2)
#define WS_NEEDED (Y3_BYTE + (size_t)NS * C3 * 2)

__device__ __forceinline__ unsigned short f2bf(float f) {
  unsigned u = __float_as_uint(f);
  return (unsigned short)((u + 0x7fffu + ((u >> 16) & 1u)) >> 16);
}
__device__ __forceinline__ float bflo(unsigned u) { return __uint_as_float(u << 16); }
__device__ __forceinline__ float bfhi(unsigned u) { return __uint_as_float(u & 0xffff0000u); }
__device__ __forceinline__ float bfu(unsigned short v) { return __uint_as_float((unsigned)v << 16); }

struct Tap4 { int o[4]; float w[4]; };

__device__ __forceinline__ Tap4 make_taps(float cx, float cy) {
  Tap4 tp;
  float x0f = floorf(cx), y0f = floorf(cy);
  float fx = cx - x0f, fy = cy - y0f;
  int ix0 = (int)x0f, iy0 = (int)y0f;
  int ix1 = ix0 + 1, iy1 = iy0 + 1;
  float vx0 = (ix0 >= 0 && ix0 < W) ? 1.f : 0.f;
  float vx1 = (ix1 >= 0 && ix1 < W) ? 1.f : 0.f;
  float vy0 = (iy0 >= 0 && iy0 < H) ? 1.f : 0.f;
  float vy1 = (iy1 >= 0 && iy1 < H) ? 1.f : 0.f;
  int cx0 = min(max(ix0, 0), W - 1), cx1 = min(max(ix1, 0), W - 1);
  int cy0 = min(max(iy0, 0), H - 1), cy1 = min(max(iy1, 0), H - 1);
  tp.w[0] = (1.f - fy) * (1.f - fx) * vy0 * vx0;
  tp.w[1] = (1.f - fy) * fx * vy0 * vx1;
  tp.w[2] = fy * (1.f - fx) * vy1 * vx0;
  tp.w[3] = fy * fx * vy1 * vx1;
  tp.o[0] = (cy0 * W + cx0) * 96;
  tp.o[1] = (cy0 * W + cx1) * 96;
  tp.o[2] = (cy1 * W + cx0) * 96;
  tp.o[3] = (cy1 * W + cx1) * 96;
  return tp;
}

// a = w1[:, :128] @ f1, g = w1[:, 128:] @ f2  -> bf16, pixel-major [p][96]
__global__ __launch_bounds__(256) void k_prep(const float* __restrict__ f1,
                                              const float* __restrict__ f2,
                                              const float* __restrict__ w1,
                                              unsigned short* __restrict__ abf,
                                              unsigned short* __restrict__ gbf) {
  __shared__ float tile[128][64];
  int t = threadIdx.x;
  int p0 = blockIdx.x * 64;
  int px = t & 63, q = t >> 6;
  int c0 = q * 24;
  for (int pass = 0; pass < 2; ++pass) {
    const float* src = pass ? f2 : f1;
    unsigned short* dst = pass ? gbf : abf;
    int koff = pass ? 128 : 0;
    __syncthreads();
    for (int idx = t; idx < 8192; idx += 256) {
      int kk = idx >> 6, xx = idx & 63;
      tile[kk][xx] = src[kk * P + p0 + xx];
    }
    __syncthreads();
    float acc[24];
#pragma unroll
    for (int i = 0; i < 24; ++i) acc[i] = 0.f;
    for (int kk = 0; kk < 128; ++kk) {
      float fv = tile[kk][px];
#pragma unroll
      for (int i = 0; i < 24; ++i)
        acc[i] += w1[(c0 + i) * 256 + koff + kk] * fv;
    }
    unsigned short* orow = dst + (size_t)(p0 + px) * 96 + c0;
#pragma unroll
    for (int i = 0; i < 24; i += 8) {
      uint4 pk;
      pk.x = (unsigned)f2bf(acc[i + 0]) | ((unsigned)f2bf(acc[i + 1]) << 16);
      pk.y = (unsigned)f2bf(acc[i + 2]) | ((unsigned)f2bf(acc[i + 3]) << 16);
      pk.z = (unsigned)f2bf(acc[i + 4]) | ((unsigned)f2bf(acc[i + 5]) << 16);
      pk.w = (unsigned)f2bf(acc[i + 6]) | ((unsigned)f2bf(acc[i + 7]) << 16);
      *(uint4*)(orow + i) = pk;
    }
  }
}

__global__ void k_wprep(const float* __restrict__ w2, const float* __restrict__ w3,
                        unsigned short* __restrict__ w2bf, unsigned short* __restrict__ w3bf) {
  int idx = blockIdx.x * 256 + threadIdx.x;
  if (idx < C2 * C1) w2bf[idx] = f2bf(w2[idx]);
  else if (idx < C2 * C1 + C3 * C2) w3bf[idx - C2 * C1] = f2bf(w3[idx - C2 * C1]);
}

// gather once: all 30 loads hoisted for max memory-level parallelism
__global__ __launch_bounds__(256) void k_sample(const float* __restrict__ coords,
                                                float* __restrict__ ws,
                                                const unsigned short* __restrict__ abf,
                                                const unsigned short* __restrict__ gbf,
                                                unsigned short* __restrict__ y1) {
  __shared__ unsigned short yt[128 * X1S];   // 26.6KB
  int t = threadIdx.x, b = blockIdx.x;
  int k = b % 81, ptile = b / 81;
  int s = t >> 1, hh = t & 1, ch0 = hh * 48;
  int p = ptile * 128 + s;
  float cx = coords[p] + (float)(k / 9) - 4.0f;
  float cy = coords[P + p] + (float)(k % 9) - 4.0f;
  Tap4 tp = make_taps(cx, cy);
  const uint4* A4 = (const uint4*)(abf + (size_t)p * 96 + ch0);
  const uint4* G0 = (const uint4*)(gbf + tp.o[0] + ch0);
  const uint4* G1 = (const uint4*)(gbf + tp.o[1] + ch0);
  const uint4* G2 = (const uint4*)(gbf + tp.o[2] + ch0);
  const uint4* G3 = (const uint4*)(gbf + tp.o[3] + ch0);
  // hoist all loads: 30 uint4 in flight per thread
  uint4 av[6], q0[6], q1[6], q2[6], q3[6];
#pragma unroll
  for (int i = 0; i < 6; ++i) q0[i] = G0[i];
#pragma unroll
  for (int i = 0; i < 6; ++i) q1[i] = G1[i];
#pragma unroll
  for (int i = 0; i < 6; ++i) q2[i] = G2[i];
#pragma unroll
  for (int i = 0; i < 6; ++i) q3[i] = G3[i];
#pragma unroll
  for (int i = 0; i < 6; ++i) av[i] = A4[i];
  float w0 = tp.w[0], w1v = tp.w[1], w2v = tp.w[2], w3v = tp.w[3];
  unsigned short* yrow = y1 + ((size_t)k * P + p) * 96 + ch0;
  unsigned short* lbase = yt + s * X1S + ch0;
#pragma unroll
  for (int i = 0; i < 6; ++i) {
    unsigned au[4] = {av[i].x, av[i].y, av[i].z, av[i].w};
    unsigned b0[4] = {q0[i].x, q0[i].y, q0[i].z, q0[i].w};
    unsigned b1[4] = {q1[i].x, q1[i].y, q1[i].z, q1[i].w};
    unsigned b2[4] = {q2[i].x, q2[i].y, q2[i].z, q2[i].w};
    unsigned b3[4] = {q3[i].x, q3[i].y, q3[i].z, q3[i].w};
    unsigned pk[4];
#pragma unroll
    for (int e = 0; e < 4; ++e) {
      float ya = bflo(au[e]) + w0 * bflo(b0[e]) + w1v * bflo(b1[e]) + w2v * bflo(b2[e]) + w3v * bflo(b3[e]);
      float yb = bfhi(au[e]) + w0 * bfhi(b0[e]) + w1v * bfhi(b1[e]) + w2v * bfhi(b2[e]) + w3v * bfhi(b3[e]);
      pk[e] = (unsigned)f2bf(ya) | ((unsigned)f2bf(yb) << 16);
    }
    uint4 pkv; pkv.x = pk[0]; pkv.y = pk[1]; pkv.z = pk[2]; pkv.w = pk[3];
    *(uint4*)(yrow + i * 8) = pkv;
    *(uint4*)(lbase + i * 8) = pkv;
  }
  __syncthreads();
  if (t < 192) {
    int ch = t % 96, half = t / 96;
    float su = 0.f, sq = 0.f;
    const unsigned short* col = yt + half * 64 * X1S + ch;
#pragma unroll 8
    for (int j = 0; j < 64; ++j) {
      float f = bfu(col[j * X1S]);
      su += f;
      sq = fmaf(f, f, sq);
    }
    int slot = b & (NSLOT - 1);
    atomicAdd(&ws[S1SUM + slot * C1 + ch], su);
    atomicAdd(&ws[S1SSQ + slot * C1 + ch], sq);
  }
}

__global__ void k_finalize(float* __restrict__ ws, int sumO, int ssqO,
                           const float* __restrict__ gamma, const float* __restrict__ beta,
                           int sO, int tO, int C) {
  int c = threadIdx.x;
  if (c < C) {
    float su = 0.f, sq = 0.f;
    for (int s = 0; s < NSLOT; ++s) { su += ws[sumO + s * C + c]; sq += ws[ssqO + s * C + c]; }
    float mean = su * (1.0f / (float)NS);
    float var = sq * (1.0f / (float)NS) - mean * mean;
    float sc = gamma[c] * rsqrtf(var + EPSF);
    ws[sO + c] = sc;
    ws[tO + c] = beta[c] - mean * sc;
  }
}

// build x1 (bn1+relu of dense y1) into [128][X1S] LDS tile
__device__ __forceinline__ void build_x1(const unsigned short* __restrict__ y1,
                                         const float* __restrict__ ws,
                                         unsigned short* lds, size_t n0, int t) {
  int s = t >> 1, hh = t & 1;
  const uint4* row = (const uint4*)(y1 + (n0 + s) * 96 + hh * 48);
  const float* s1p = ws + S1Sc;
  const float* t1p = ws + S1Tc;
  unsigned short* base = lds + s * X1S + hh * 48;
#pragma unroll
  for (int i = 0; i < 6; ++i) {
    uint4 v = row[i];
    unsigned a[4] = {v.x, v.y, v.z, v.w};
    unsigned pk[4];
#pragma unroll
    for (int e = 0; e < 4; ++e) {
      int c = hh * 48 + i * 8 + e * 2;
      float xa = fmaxf(0.f, fmaf(s1p[c], bflo(a[e]), t1p[c]));
      float xb = fmaxf(0.f, fmaf(s1p[c + 1], bfhi(a[e]), t1p[c + 1]));
      pk[e] = (unsigned)f2bf(xa) | ((unsigned)f2bf(xb) << 16);
    }
    uint4 pkv; pkv.x = pk[0]; pkv.y = pk[1]; pkv.z = pk[2]; pkv.w = pk[3];
    *(uint4*)(base + i * 8) = pkv;
  }
}

// layer2 stats pass: y1 -> x1 -> MFMA1 -> stats2 (direct slot atomics, no LDS reduce)
__global__ __launch_bounds__(256) void k_l2stats(const unsigned short* __restrict__ y1,
                                                 float* __restrict__ ws,
                                                 const unsigned short* __restrict__ w2bf) {
  __shared__ unsigned short x1t[128 * X1S];   // 26624B -> 6 blocks/CU
  int t = threadIdx.x, b = blockIdx.x;
  size_t n0 = (size_t)b * 128;
  int slot = b & (NSLOT - 1);
  build_x1(y1, ws, x1t, n0, t);
  __syncthreads();
  int l = t & 63, wv = t >> 6;
  int o0w = wv * 32;
  int lr = l & 15, lh = l >> 4;
  bf16x8 af[2][3];
#pragma unroll
  for (int m = 0; m < 2; ++m)
#pragma unroll
    for (int kk = 0; kk < 3; ++kk)
      af[m][kk] = *(const bf16x8*)(const void*)(w2bf + (size_t)(o0w + m * 16 + lr) * 96 + kk * 32 + lh * 8);
  f32x4 acc[2][8];
  f32x4 zero4 = {0.f, 0.f, 0.f, 0.f};
#pragma unroll
  for (int m = 0; m < 2; ++m)
#pragma unroll
    for (int n = 0; n < 8; ++n) acc[m][n] = zero4;
#pragma unroll
  for (int kk = 0; kk < 3; ++kk)
#pragma unroll
    for (int n = 0; n < 8; ++n) {
      bf16x8 bfr = *(const bf16x8*)(const void*)(x1t + (n * 16 + lr) * X1S + kk * 32 + lh * 8);
      acc[0][n] = __builtin_amdgcn_mfma_f32_16x16x32_bf16(af[0][kk], bfr, acc[0][n], 0, 0, 0);
      acc[1][n] = __builtin_amdgcn_mfma_f32_16x16x32_bf16(af[1][kk], bfr, acc[1][n], 0, 0, 0);
    }
  float ssum[8], sssq[8];
#pragma unroll
  for (int i = 0; i < 8; ++i) { ssum[i] = 0.f; sssq[i] = 0.f; }
#pragma unroll
  for (int m = 0; m < 2; ++m)
#pragma unroll
    for (int n = 0; n < 8; ++n) {
      f32x4 v = acc[m][n];
#pragma unroll
      for (int r = 0; r < 4; ++r) { float x = v[r]; ssum[m * 4 + r] += x; sssq[m * 4 + r] = fmaf(x, x, sssq[m * 4 + r]); }
    }
#pragma unroll
  for (int msk = 1; msk < 16; msk <<= 1)
#pragma unroll
    for (int i = 0; i < 8; ++i) { ssum[i] += __shfl_xor(ssum[i], msk); sssq[i] += __shfl_xor(sssq[i], msk); }
  if (lr == 0) {
#pragma unroll
    for (int m = 0; m < 2; ++m)
#pragma unroll
      for (int r = 0; r < 4; ++r) {
        int o = o0w + m * 16 + lh * 4 + r;
        atomicAdd(&ws[S2SUM + slot * C2 + o], ssum[m * 4 + r]);
        atomicAdd(&ws[S2SSQ + slot * C2 + o], sssq[m * 4 + r]);
      }
  }
}

// fused layers 2+3: y1 -> x1 -> MFMA1 (y2 fp32 regs) -> bn2+relu -> x2 halves -> MFMA2 -> y3 + stats3
__global__ __launch_bounds__(256) void k_l23(const unsigned short* __restrict__ y1,
                                             float* __restrict__ ws,
                                             const unsigned short* __restrict__ w2bf,
                                             const unsigned short* __restrict__ w3bf,
                                             unsigned short* __restrict__ y3) {
  __shared__ unsigned short ldss[128 * X1S];   // 26624B -> 6 blocks/CU
  int t = threadIdx.x, b = blockIdx.x;
  size_t n0 = (size_t)b * 128;
  int slot = b & (NSLOT - 1);
  build_x1(y1, ws, ldss, n0, t);
  __syncthreads();
  int l = t & 63, wv = t >> 6;
  int o0w = wv * 32;
  int lr = l & 15, lh = l >> 4;
  // ---- MFMA1: y2 = W2 @ x1 ----
  bf16x8 af[2][3];
#pragma unroll
  for (int m = 0; m < 2; ++m)
#pragma unroll
    for (int kk = 0; kk < 3; ++kk)
      af[m][kk] = *(const bf16x8*)(const void*)(w2bf + (size_t)(o0w + m * 16 + lr) * 96 + kk * 32 + lh * 8);
  f32x4 acc[2][8];
  f32x4 zero4 = {0.f, 0.f, 0.f, 0.f};
#pragma unroll
  for (int m = 0; m < 2; ++m)
#pragma unroll
    for (int n = 0; n < 8; ++n) acc[m][n] = zero4;
#pragma unroll
  for (int kk = 0; kk < 3; ++kk)
#pragma unroll
    for (int n = 0; n < 8; ++n) {
      bf16x8 bfr = *(const bf16x8*)(const void*)(ldss + (n * 16 + lr) * X1S + kk * 32 + lh * 8);
      acc[0][n] = __builtin_amdgcn_mfma_f32_16x16x32_bf16(af[0][kk], bfr, acc[0][n], 0, 0, 0);
      acc[1][n] = __builtin_amdgcn_mfma_f32_16x16x32_bf16(af[1][kk], bfr, acc[1][n], 0, 0, 0);
    }
  // bn2 params + W3 A-frags
  float s2v[2][4], t2v[2][4];
#pragma unroll
  for (int m = 0; m < 2; ++m)
#pragma unroll
    for (int r = 0; r < 4; ++r) {
      int c = o0w + m * 16 + lh * 4 + r;
      s2v[m][r] = ws[S2Sc + c];
      t2v[m][r] = ws[S2Tc + c];
    }
  int o2 = wv * 16;
  bf16x8 af2[4];
#pragma unroll
  for (int kk = 0; kk < 4; ++kk)
    af2[kk] = *(const bf16x8*)(const void*)(w3bf + (size_t)(o2 + lr) * 128 + kk * 32 + lh * 8);
  unsigned short* x2s = ldss;               // [64][X2S] = 17408B
  unsigned short* y3a = ldss + 8704;        // [64][Y3S] at byte 17408
  float ssum[4] = {0.f, 0.f, 0.f, 0.f}, sssq[4] = {0.f, 0.f, 0.f, 0.f};
#pragma unroll
  for (int h = 0; h < 2; ++h) {
    __syncthreads();
#pragma unroll
    for (int m = 0; m < 2; ++m)
#pragma unroll
      for (int n2 = 0; n2 < 4; ++n2) {
        f32x4 v = acc[m][h * 4 + n2];
        float x0 = fmaxf(0.f, fmaf(s2v[m][0], v[0], t2v[m][0]));
        float x1v = fmaxf(0.f, fmaf(s2v[m][1], v[1], t2v[m][1]));
        float x2v = fmaxf(0.f, fmaf(s2v[m][2], v[2], t2v[m][2]));
        float x3 = fmaxf(0.f, fmaf(s2v[m][3], v[3], t2v[m][3]));
        uint2 pk;
        pk.x = (unsigned)f2bf(x0) | ((unsigned)f2bf(x1v) << 16);
        pk.y = (unsigned)f2bf(x2v) | ((unsigned)f2bf(x3) << 16);
        *(uint2*)(x2s + (n2 * 16 + lr) * X2S + o0w + m * 16 + lh * 4) = pk;
      }
    __syncthreads();
    f32x4 acc2[4];
#pragma unroll
    for (int n2 = 0; n2 < 4; ++n2) acc2[n2] = zero4;
#pragma unroll
    for (int kk = 0; kk < 4; ++kk)
#pragma unroll
      for (int n2 = 0; n2 < 4; ++n2) {
        bf16x8 bfr = *(const bf16x8*)(const void*)(x2s + (n2 * 16 + lr) * X2S + kk * 32 + lh * 8);
        acc2[n2] = __builtin_amdgcn_mfma_f32_16x16x32_bf16(af2[kk], bfr, acc2[n2], 0, 0, 0);
      }
#pragma unroll
    for (int n2 = 0; n2 < 4; ++n2) {
      f32x4 v = acc2[n2];
#pragma unroll
      for (int r = 0; r < 4; ++r) { float x = v[r]; ssum[r] += x; sssq[r] = fmaf(x, x, sssq[r]); }
    }
    __syncthreads();
    unsigned short* dst = h ? ldss : y3a;
#pragma unroll
    for (int n2 = 0; n2 < 4; ++n2) {
      f32x4 v = acc2[n2];
      uint2 pk;
      pk.x = (unsigned)f2bf(v[0]) | ((unsigned)f2bf(v[1]) << 16);
      pk.y = (unsigned)f2bf(v[2]) | ((unsigned)f2bf(v[3]) << 16);
      *(uint2*)(dst + (n2 * 16 + lr) * Y3S + o2 + lh * 4) = pk;
    }
  }
  // stats3: in-wave reduce then direct slot atomics
#pragma unroll
  for (int msk = 1; msk < 16; msk <<= 1)
#pragma unroll
    for (int i = 0; i < 4; ++i) { ssum[i] += __shfl_xor(ssum[i], msk); sssq[i] += __shfl_xor(sssq[i], msk); }
  if (lr == 0) {
#pragma unroll
    for (int r = 0; r < 4; ++r) {
      int o = o2 + lh * 4 + r;
      atomicAdd(&ws[S3SUM + slot * C3 + o], ssum[r]);
      atomicAdd(&ws[S3SSQ + slot * C3 + o], sssq[r]);
    }
  }
  __syncthreads();
  // coalesced y3 store from the two staged halves
  {
    int row = t >> 1, hf = t & 1;
    const unsigned short* src = (row < 64) ? (y3a + row * Y3S) : (ldss + (row - 64) * Y3S);
    const uint4* s4 = (const uint4*)(src + hf * 32);
    uint4* dst = (uint4*)(y3 + (n0 + row) * 64 + hf * 32);
#pragma unroll
    for (int j = 0; j < 4; ++j) dst[j] = s4[j];
  }
}

// layer4: cost = w4 . relu(bn3(y3)) + b4
__global__ __launch_bounds__(256) void k_layer4(const unsigned short* __restrict__ y3,
                                                float* __restrict__ ws,
                                                const float* __restrict__ w4,
                                                const float* __restrict__ b4) {
  int n = blockIdx.x * 256 + threadIdx.x;
  const float* s3p = ws + S3Sc;
  const float* t3p = ws + S3Tc;
  const uint4* row = (const uint4*)(y3 + (size_t)n * C3);
  float acc = 0.f;
#pragma unroll
  for (int j = 0; j < 8; ++j) {
    uint4 v = row[j];
    unsigned arr[4] = {v.x, v.y, v.z, v.w};
#pragma unroll
    for (int e = 0; e < 4; ++e) {
      int c = j * 8 + e * 2;
      acc += fmaxf(0.f, fmaf(s3p[c], bflo(arr[e]), t3p[c])) * w4[c];
      acc += fmaxf(0.f, fmaf(s3p[c + 1], bfhi(arr[e]), t3p[c + 1])) * w4[c + 1];
    }
  }
  ws[COST_OFF + n] = acc + b4[0];
}

// DAP: out[l,p] = sum_k wdap[l,k] * cost[k,p]; 256 blocks x 32 px
__global__ __launch_bounds__(256) void k_dap(const float* __restrict__ ws,
                                             const float* __restrict__ wdap,
                                             float* __restrict__ out) {
  __shared__ float wd[DD * DD];
  int t = threadIdx.x;
  for (int i = t; i < DD * DD; i += 256) wd[i] = wdap[i];
  __syncthreads();
  int p = blockIdx.x * 32 + (t & 31);
  int lg = t >> 5;
  const float* cost = ws + COST_OFF;
  float cr[81];
#pragma unroll
  for (int kk = 0; kk < 81; ++kk) cr[kk] = cost[kk * P + p];
  for (int l = lg; l < 81; l += 8) {
    float acc = 0.f;
#pragma unroll
    for (int kk = 0; kk < 81; ++kk) acc = fmaf(wd[l * 81 + kk], cr[kk], acc);
    out[(size_t)l * P + p] = acc;
  }
}

__global__ void k_marker(float* out) { out[0] = 1.0e30f; }

extern "C" void kernel_launch(void* const* d_in, const int* in_sizes, int n_in,
                              void* d_out, int out_size, void* d_ws, size_t ws_size,
                              hipStream_t stream) {
  const float* f1 = (const float*)d_in[0];
  const float* f2 = (const float*)d_in[1];
  const float* coords = (const float*)d_in[2];
  const float* w1 = (const float*)d_in[3];
  const float* g1 = (const float*)d_in[4];
  const float* be1 = (const float*)d_in[5];
  const float* w2 = (const float*)d_in[6];
  const float* g2 = (const float*)d_in[7];
  const float* be2 = (const float*)d_in[8];
  const float* w3 = (const float*)d_in[9];
  const float* g3 = (const float*)d_in[10];
  const float* be3 = (const float*)d_in[11];
  const float* w4 = (const float*)d_in[12];
  const float* b4 = (const float*)d_in[13];
  const float* wdap = (const float*)d_in[14];
  float* out = (float*)d_out;
  float* ws = (float*)d_ws;

  if (ws_size < WS_NEEDED) {
    k_marker<<<1, 1, 0, stream>>>(out);
    return;
  }
  unsigned short* abf = (unsigned short*)((char*)d_ws + A_BYTE);
  unsigned short* gbf = (unsigned short*)((char*)d_ws + G_BYTE);
  unsigned short* w2bf = (unsigned short*)((char*)d_ws + W2BF_BYTE);
  unsigned short* w3bf = (unsigned short*)((char*)d_ws + W3BF_BYTE);
  unsigned short* y1 = (unsigned short*)((char*)d_ws + Y1_BYTE);
  unsigned short* y3 = (unsigned short*)((char*)d_ws + Y3_BYTE);

  hipMemsetAsync(d_ws, 0, (size_t)STATS_ZERO_FLOATS * 4, stream);
  k_prep<<<128, 256, 0, stream>>>(f1, f2, w1, abf, gbf);
  k_wprep<<<80, 256, 0, stream>>>(w2, w3, w2bf, w3bf);
  k_sample<<<5184, 256, 0, stream>>>(coords, ws, abf, gbf, y1);
  k_finalize<<<1, 128, 0, stream>>>(ws, S1SUM, S1SSQ, g1, be1, S1Sc, S1Tc, C1);
  k_l2stats<<<5184, 256, 0, stream>>>(y1, ws, w2bf);
  k_finalize<<<1, 128, 0, stream>>>(ws, S2SUM, S2SSQ, g2, be2, S2Sc, S2Tc, C2);
  k_l23<<<5184, 256, 0, stream>>>(y1, ws, w2bf, w3bf, y3);
  k_finalize<<<1, 128, 0, stream>>>(ws, S3SUM, S3SSQ, g3, be3, S3Sc, S3Tc, C3);
  k_layer4<<<2592, 256, 0, stream>>>(y3, ws, w4, b4);
  k_dap<<<256, 256, 0, stream>>>(ws, wdap, out);
}

// Round 7
// 330.098 us; speedup vs baseline: 5.6108x; 1.1742x over previous
//
#include <hip/hip_runtime.h>
#include <hip/hip_bf16.h>

#define H 64
#define W 128
#define P 8192        // H*W
#define DD 81
#define NS 663552     // DD*P
#define C1 96
#define C2 128
#define C3 64
#define EPSF 1e-5f
#define NSLOT 128

// LDS row strides in shorts (odd multiples of 8 shorts = odd x 16B -> even bank phases)
#define X1S 104       // 208B = 13*16B
#define X2S 136       // 272B = 17*16B
#define Y3S 72        // 144B = 9*16B

typedef __attribute__((ext_vector_type(8))) short bf16x8;
typedef __attribute__((ext_vector_type(4))) float f32x4;

// ---- workspace layout ----
#define S1SUM 0
#define S1SSQ (S1SUM + NSLOT * C1)
#define S2SUM (S1SSQ + NSLOT * C1)
#define S2SSQ (S2SUM + NSLOT * C2)
#define S3SUM (S2SSQ + NSLOT * C2)
#define S3SSQ (S3SUM + NSLOT * C3)
#define STATS_ZERO_FLOATS (S3SSQ + NSLOT * C3)  // 73728
#define S1Sc 73728
#define S1Tc (S1Sc + C1)
#define S2Sc (S1Tc + C1)
#define S2Tc (S2Sc + C2)
#define S3Sc (S2Tc + C2)
#define S3Tc (S3Sc + C3)
#define COST_OFF 74304
#define FLOAT_END (COST_OFF + NS)
// byte-indexed region. aT/gT/y1T transposed: [chunk of 4ch][pixel][4]
#define A_BYTE   ((size_t)FLOAT_END * 4)
#define G_BYTE   (A_BYTE + (size_t)P * 96 * 2)
#define W2BF_BYTE (G_BYTE + (size_t)P * 96 * 2)
#define W3BF_BYTE (W2BF_BYTE + (size_t)C2 * C1 * 2)
#define Y1_BYTE  (W3BF_BYTE + (size_t)C3 * C2 * 2)
#define Y3_BYTE  (Y1_BYTE + (size_t)NS * C1 * 2)
#define WS_NEEDED (Y3_BYTE + (size_t)NS * C3 * 2)

__device__ __forceinline__ float bflo(unsigned u) { return __uint_as_float(u << 16); }
__device__ __forceinline__ float bfhi(unsigned u) { return __uint_as_float(u & 0xffff0000u); }

__device__ __forceinline__ unsigned pkbf(float a, float b) {
  __hip_bfloat162 h = __float22bfloat162_rn(make_float2(a, b));
  unsigned u; __builtin_memcpy(&u, &h, 4);
  return u;
}

// a = w1[:, :128] @ f1, g = w1[:, 128:] @ f2  -> bf16, transposed [c4][p][4]
__global__ __launch_bounds__(256) void k_prep(const float* __restrict__ f1,
                                              const float* __restrict__ f2,
                                              const float* __restrict__ w1,
                                              unsigned short* __restrict__ aT,
                                              unsigned short* __restrict__ gT) {
  __shared__ float tile[128][64];
  int t = threadIdx.x;
  int p0 = blockIdx.x * 64;
  int px = t & 63, q = t >> 6;
  int c0 = q * 24;
  for (int pass = 0; pass < 2; ++pass) {
    const float* src = pass ? f2 : f1;
    unsigned short* dst = pass ? gT : aT;
    int koff = pass ? 128 : 0;
    __syncthreads();
    for (int idx = t; idx < 8192; idx += 256) {
      int kk = idx >> 6, xx = idx & 63;
      tile[kk][xx] = src[kk * P + p0 + xx];
    }
    __syncthreads();
    float acc[24];
#pragma unroll
    for (int i = 0; i < 24; ++i) acc[i] = 0.f;
    for (int kk = 0; kk < 128; ++kk) {
      float fv = tile[kk][px];
#pragma unroll
      for (int i = 0; i < 24; ++i)
        acc[i] += w1[(c0 + i) * 256 + koff + kk] * fv;
    }
#pragma unroll
    for (int i = 0; i < 24; i += 4) {
      uint2 pk;
      pk.x = pkbf(acc[i + 0], acc[i + 1]);
      pk.y = pkbf(acc[i + 2], acc[i + 3]);
      *(uint2*)(dst + ((size_t)((c0 + i) >> 2) * P + p0 + px) * 4) = pk;
    }
  }
}

__global__ void k_wprep(const float* __restrict__ w2, const float* __restrict__ w3,
                        unsigned short* __restrict__ w2bf, unsigned short* __restrict__ w3bf) {
  int idx = blockIdx.x * 256 + threadIdx.x;
  unsigned short v;
  if (idx < C2 * C1) {
    float f = w2[idx];
    v = (unsigned short)(pkbf(f, 0.f) & 0xffffu);
    w2bf[idx] = v;
  } else if (idx < C2 * C1 + C3 * C2) {
    float f = w3[idx - C2 * C1];
    v = (unsigned short)(pkbf(f, 0.f) & 0xffffu);
    w3bf[idx - C2 * C1] = v;
  }
}

// separable gather: per pixel, 10x10 g-neighborhood -> H-pass -> V-pass -> 81 outputs
// thread = (pixel, 4-channel chunk); block = 64 px x 4 chunks; grid = 128 px-tiles x 6 chunk-groups
__global__ __launch_bounds__(256) void k_sample(const float* __restrict__ coords,
                                                float* __restrict__ ws,
                                                const unsigned short* __restrict__ aT,
                                                const unsigned short* __restrict__ gT,
                                                unsigned short* __restrict__ y1T) {
  int t = threadIdx.x, b = blockIdx.x;
  int cg = b % 6;
  int ptile = b / 6;
  int c = cg * 4 + (t >> 6);   // chunk 0..23, uniform per wave
  int px = t & 63;
  int p = ptile * 64 + px;
  float cx = coords[p], cy = coords[P + p];
  float fx0 = floorf(cx), fy0 = floorf(cy);
  float wx1 = cx - fx0, wx0 = 1.f - wx1;
  float wy1 = cy - fy0, wy0 = 1.f - wy1;
  int ixb = (int)fx0 - 4, iyb = (int)fy0 - 4;
  int colOff[10];
  float vx[10];
#pragma unroll
  for (int j = 0; j < 10; ++j) {
    int ix = ixb + j;
    vx[j] = (ix >= 0 && ix < W) ? 1.f : 0.f;
    colOff[j] = min(max(ix, 0), W - 1);
  }
  float ewx0[9], ewx1[9];
#pragma unroll
  for (int j = 0; j < 9; ++j) { ewx0[j] = wx0 * vx[j]; ewx1[j] = wx1 * vx[j + 1]; }
  int rowOff[10];
  float vy[10];
#pragma unroll
  for (int dy = 0; dy < 10; ++dy) {
    int iy = iyb + dy;
    vy[dy] = (iy >= 0 && iy < H) ? 1.f : 0.f;
    rowOff[dy] = min(max(iy, 0), H - 1) * W;
  }
  float ewy0[9], ewy1[9];
#pragma unroll
  for (int d = 0; d < 9; ++d) { ewy0[d] = wy0 * vy[d]; ewy1[d] = wy1 * vy[d + 1]; }
  float av[4];
  {
    uint2 a2 = *(const uint2*)(aT + ((size_t)c * P + p) * 4);
    av[0] = bflo(a2.x); av[1] = bfhi(a2.x); av[2] = bflo(a2.y); av[3] = bfhi(a2.y);
  }
  const unsigned short* gc = gT + (size_t)c * P * 4;
  float Hb[2][9][4];
  float sum[4] = {0.f, 0.f, 0.f, 0.f}, ssq[4] = {0.f, 0.f, 0.f, 0.f};
#pragma unroll
  for (int dy = 0; dy < 10; ++dy) {
    const int cur = dy & 1, prv = cur ^ 1;
    uint2 gv[10];
    const unsigned short* grow = gc + (size_t)rowOff[dy] * 4;
#pragma unroll
    for (int j = 0; j < 10; ++j) gv[j] = *(const uint2*)(grow + colOff[j] * 4);
#pragma unroll
    for (int j = 0; j < 9; ++j) {
      Hb[cur][j][0] = fmaf(ewx1[j], bflo(gv[j + 1].x), ewx0[j] * bflo(gv[j].x));
      Hb[cur][j][1] = fmaf(ewx1[j], bfhi(gv[j + 1].x), ewx0[j] * bfhi(gv[j].x));
      Hb[cur][j][2] = fmaf(ewx1[j], bflo(gv[j + 1].y), ewx0[j] * bflo(gv[j].y));
      Hb[cur][j][3] = fmaf(ewx1[j], bfhi(gv[j + 1].y), ewx0[j] * bfhi(gv[j].y));
    }
    if (dy >= 1) {
      const int dyk = dy - 1;
      float e0 = ewy0[dyk], e1 = ewy1[dyk];
#pragma unroll
      for (int j = 0; j < 9; ++j) {
        float o0 = fmaf(e0, Hb[prv][j][0], fmaf(e1, Hb[cur][j][0], av[0]));
        float o1 = fmaf(e0, Hb[prv][j][1], fmaf(e1, Hb[cur][j][1], av[1]));
        float o2 = fmaf(e0, Hb[prv][j][2], fmaf(e1, Hb[cur][j][2], av[2]));
        float o3 = fmaf(e0, Hb[prv][j][3], fmaf(e1, Hb[cur][j][3], av[3]));
        sum[0] += o0; ssq[0] = fmaf(o0, o0, ssq[0]);
        sum[1] += o1; ssq[1] = fmaf(o1, o1, ssq[1]);
        sum[2] += o2; ssq[2] = fmaf(o2, o2, ssq[2]);
        sum[3] += o3; ssq[3] = fmaf(o3, o3, ssq[3]);
        uint2 pk;
        pk.x = pkbf(o0, o1);
        pk.y = pkbf(o2, o3);
        int kk = j * 9 + dyk;   // k = xdisp*9 + ydisp (reference order)
        *(uint2*)(y1T + (((size_t)kk * 24 + c) * P + p) * 4) = pk;
      }
    }
  }
  // stats1: wave covers 64 pixels of the same 4 channels
#pragma unroll
  for (int m = 1; m < 64; m <<= 1) {
#pragma unroll
    for (int e = 0; e < 4; ++e) {
      sum[e] += __shfl_xor(sum[e], m);
      ssq[e] += __shfl_xor(ssq[e], m);
    }
  }
  if ((t & 63) == 0) {
    int slot = b & (NSLOT - 1);
#pragma unroll
    for (int e = 0; e < 4; ++e) {
      atomicAdd(&ws[S1SUM + slot * C1 + c * 4 + e], sum[e]);
      atomicAdd(&ws[S1SSQ + slot * C1 + c * 4 + e], ssq[e]);
    }
  }
}

__global__ void k_finalize(float* __restrict__ ws, int sumO, int ssqO,
                           const float* __restrict__ gamma, const float* __restrict__ beta,
                           int sO, int tO, int C) {
  int c = threadIdx.x;
  if (c < C) {
    float su = 0.f, sq = 0.f;
    for (int s = 0; s < NSLOT; ++s) { su += ws[sumO + s * C + c]; sq += ws[ssqO + s * C + c]; }
    float mean = su * (1.0f / (float)NS);
    float var = sq * (1.0f / (float)NS) - mean * mean;
    float sc = gamma[c] * rsqrtf(var + EPSF);
    ws[sO + c] = sc;
    ws[tO + c] = beta[c] - mean * sc;
  }
}

// build x1 (bn1+relu of y1T) into [128][X1S] LDS tile; y1k = k-plane base
__device__ __forceinline__ void build_x1(const unsigned short* __restrict__ y1k,
                                         const float* __restrict__ ws,
                                         unsigned short* lds, int p0, int t) {
  int s = t >> 1, hh = t & 1;
  int p = p0 + s;
  const float* s1p = ws + S1Sc;
  const float* t1p = ws + S1Tc;
  unsigned short* base = lds + s * X1S + hh * 48;
#pragma unroll
  for (int i2 = 0; i2 < 6; ++i2) {
    int c0 = hh * 12 + i2 * 2;
    uint2 va = *(const uint2*)(y1k + ((size_t)c0 * P + p) * 4);
    uint2 vb = *(const uint2*)(y1k + ((size_t)(c0 + 1) * P + p) * 4);
    int cb = c0 * 4;
    float x0 = fmaxf(0.f, fmaf(s1p[cb + 0], bflo(va.x), t1p[cb + 0]));
    float x1 = fmaxf(0.f, fmaf(s1p[cb + 1], bfhi(va.x), t1p[cb + 1]));
    float x2 = fmaxf(0.f, fmaf(s1p[cb + 2], bflo(va.y), t1p[cb + 2]));
    float x3 = fmaxf(0.f, fmaf(s1p[cb + 3], bfhi(va.y), t1p[cb + 3]));
    float x4 = fmaxf(0.f, fmaf(s1p[cb + 4], bflo(vb.x), t1p[cb + 4]));
    float x5 = fmaxf(0.f, fmaf(s1p[cb + 5], bfhi(vb.x), t1p[cb + 5]));
    float x6 = fmaxf(0.f, fmaf(s1p[cb + 6], bflo(vb.y), t1p[cb + 6]));
    float x7 = fmaxf(0.f, fmaf(s1p[cb + 7], bfhi(vb.y), t1p[cb + 7]));
    uint4 pk;
    pk.x = pkbf(x0, x1); pk.y = pkbf(x2, x3); pk.z = pkbf(x4, x5); pk.w = pkbf(x6, x7);
    *(uint4*)(base + i2 * 8) = pk;
  }
}

// layer2 stats pass: y1 -> x1 -> MFMA1 -> stats2
__global__ __launch_bounds__(256) void k_l2stats(const unsigned short* __restrict__ y1T,
                                                 float* __restrict__ ws,
                                                 const unsigned short* __restrict__ w2bf) {
  __shared__ unsigned short x1t[128 * X1S];
  int t = threadIdx.x, b = blockIdx.x;
  int k = b >> 6, p0 = (b & 63) << 7;
  int slot = b & (NSLOT - 1);
  const unsigned short* y1k = y1T + (size_t)k * P * 96;
  build_x1(y1k, ws, x1t, p0, t);
  __syncthreads();
  int l = t & 63, wv = t >> 6;
  int o0w = wv * 32;
  int lr = l & 15, lh = l >> 4;
  bf16x8 af[2][3];
#pragma unroll
  for (int m = 0; m < 2; ++m)
#pragma unroll
    for (int kk = 0; kk < 3; ++kk)
      af[m][kk] = *(const bf16x8*)(const void*)(w2bf + (size_t)(o0w + m * 16 + lr) * 96 + kk * 32 + lh * 8);
  f32x4 acc[2][8];
  f32x4 zero4 = {0.f, 0.f, 0.f, 0.f};
#pragma unroll
  for (int m = 0; m < 2; ++m)
#pragma unroll
    for (int n = 0; n < 8; ++n) acc[m][n] = zero4;
#pragma unroll
  for (int kk = 0; kk < 3; ++kk)
#pragma unroll
    for (int n = 0; n < 8; ++n) {
      bf16x8 bfr = *(const bf16x8*)(const void*)(x1t + (n * 16 + lr) * X1S + kk * 32 + lh * 8);
      acc[0][n] = __builtin_amdgcn_mfma_f32_16x16x32_bf16(af[0][kk], bfr, acc[0][n], 0, 0, 0);
      acc[1][n] = __builtin_amdgcn_mfma_f32_16x16x32_bf16(af[1][kk], bfr, acc[1][n], 0, 0, 0);
    }
  float ssum[8], sssq[8];
#pragma unroll
  for (int i = 0; i < 8; ++i) { ssum[i] = 0.f; sssq[i] = 0.f; }
#pragma unroll
  for (int m = 0; m < 2; ++m)
#pragma unroll
    for (int n = 0; n < 8; ++n) {
      f32x4 v = acc[m][n];
#pragma unroll
      for (int r = 0; r < 4; ++r) { float x = v[r]; ssum[m * 4 + r] += x; sssq[m * 4 + r] = fmaf(x, x, sssq[m * 4 + r]); }
    }
#pragma unroll
  for (int msk = 1; msk < 16; msk <<= 1)
#pragma unroll
    for (int i = 0; i < 8; ++i) { ssum[i] += __shfl_xor(ssum[i], msk); sssq[i] += __shfl_xor(sssq[i], msk); }
  if (lr == 0) {
#pragma unroll
    for (int m = 0; m < 2; ++m)
#pragma unroll
      for (int r = 0; r < 4; ++r) {
        int o = o0w + m * 16 + lh * 4 + r;
        atomicAdd(&ws[S2SUM + slot * C2 + o], ssum[m * 4 + r]);
        atomicAdd(&ws[S2SSQ + slot * C2 + o], sssq[m * 4 + r]);
      }
  }
}

// fused layers 2+3
__global__ __launch_bounds__(256) void k_l23(const unsigned short* __restrict__ y1T,
                                             float* __restrict__ ws,
                                             const unsigned short* __restrict__ w2bf,
                                             const unsigned short* __restrict__ w3bf,
                                             unsigned short* __restrict__ y3) {
  __shared__ unsigned short ldss[128 * X1S];
  int t = threadIdx.x, b = blockIdx.x;
  int k = b >> 6, p0 = (b & 63) << 7;
  size_t n0 = (size_t)k * P + p0;
  int slot = b & (NSLOT - 1);
  const unsigned short* y1k = y1T + (size_t)k * P * 96;
  build_x1(y1k, ws, ldss, p0, t);
  __syncthreads();
  int l = t & 63, wv = t >> 6;
  int o0w = wv * 32;
  int lr = l & 15, lh = l >> 4;
  bf16x8 af[2][3];
#pragma unroll
  for (int m = 0; m < 2; ++m)
#pragma unroll
    for (int kk = 0; kk < 3; ++kk)
      af[m][kk] = *(const bf16x8*)(const void*)(w2bf + (size_t)(o0w + m * 16 + lr) * 96 + kk * 32 + lh * 8);
  f32x4 acc[2][8];
  f32x4 zero4 = {0.f, 0.f, 0.f, 0.f};
#pragma unroll
  for (int m = 0; m < 2; ++m)
#pragma unroll
    for (int n = 0; n < 8; ++n) acc[m][n] = zero4;
#pragma unroll
  for (int kk = 0; kk < 3; ++kk)
#pragma unroll
    for (int n = 0; n < 8; ++n) {
      bf16x8 bfr = *(const bf16x8*)(const void*)(ldss + (n * 16 + lr) * X1S + kk * 32 + lh * 8);
      acc[0][n] = __builtin_amdgcn_mfma_f32_16x16x32_bf16(af[0][kk], bfr, acc[0][n], 0, 0, 0);
      acc[1][n] = __builtin_amdgcn_mfma_f32_16x16x32_bf16(af[1][kk], bfr, acc[1][n], 0, 0, 0);
    }
  float s2v[2][4], t2v[2][4];
#pragma unroll
  for (int m = 0; m < 2; ++m)
#pragma unroll
    for (int r = 0; r < 4; ++r) {
      int cc = o0w + m * 16 + lh * 4 + r;
      s2v[m][r] = ws[S2Sc + cc];
      t2v[m][r] = ws[S2Tc + cc];
    }
  int o2 = wv * 16;
  bf16x8 af2[4];
#pragma unroll
  for (int kk = 0; kk < 4; ++kk)
    af2[kk] = *(const bf16x8*)(const void*)(w3bf + (size_t)(o2 + lr) * 128 + kk * 32 + lh * 8);
  unsigned short* x2s = ldss;               // [64][X2S]
  unsigned short* y3a = ldss + 8704;        // [64][Y3S] at byte 17408
  float ssum[4] = {0.f, 0.f, 0.f, 0.f}, sssq[4] = {0.f, 0.f, 0.f, 0.f};
#pragma unroll
  for (int h = 0; h < 2; ++h) {
    __syncthreads();
#pragma unroll
    for (int m = 0; m < 2; ++m)
#pragma unroll
      for (int n2 = 0; n2 < 4; ++n2) {
        f32x4 v = acc[m][h * 4 + n2];
        float x0 = fmaxf(0.f, fmaf(s2v[m][0], v[0], t2v[m][0]));
        float x1v = fmaxf(0.f, fmaf(s2v[m][1], v[1], t2v[m][1]));
        float x2v = fmaxf(0.f, fmaf(s2v[m][2], v[2], t2v[m][2]));
        float x3 = fmaxf(0.f, fmaf(s2v[m][3], v[3], t2v[m][3]));
        uint2 pk;
        pk.x = pkbf(x0, x1v);
        pk.y = pkbf(x2v, x3);
        *(uint2*)(x2s + (n2 * 16 + lr) * X2S + o0w + m * 16 + lh * 4) = pk;
      }
    __syncthreads();
    f32x4 acc2[4];
#pragma unroll
    for (int n2 = 0; n2 < 4; ++n2) acc2[n2] = zero4;
#pragma unroll
    for (int kk = 0; kk < 4; ++kk)
#pragma unroll
      for (int n2 = 0; n2 < 4; ++n2) {
        bf16x8 bfr = *(const bf16x8*)(const void*)(x2s + (n2 * 16 + lr) * X2S + kk * 32 + lh * 8);
        acc2[n2] = __builtin_amdgcn_mfma_f32_16x16x32_bf16(af2[kk], bfr, acc2[n2], 0, 0, 0);
      }
#pragma unroll
    for (int n2 = 0; n2 < 4; ++n2) {
      f32x4 v = acc2[n2];
#pragma unroll
      for (int r = 0; r < 4; ++r) { float x = v[r]; ssum[r] += x; sssq[r] = fmaf(x, x, sssq[r]); }
    }
    __syncthreads();
    unsigned short* dst = h ? ldss : y3a;
#pragma unroll
    for (int n2 = 0; n2 < 4; ++n2) {
      f32x4 v = acc2[n2];
      uint2 pk;
      pk.x = pkbf(v[0], v[1]);
      pk.y = pkbf(v[2], v[3]);
      *(uint2*)(dst + (n2 * 16 + lr) * Y3S + o2 + lh * 4) = pk;
    }
  }
#pragma unroll
  for (int msk = 1; msk < 16; msk <<= 1)
#pragma unroll
    for (int i = 0; i < 4; ++i) { ssum[i] += __shfl_xor(ssum[i], msk); sssq[i] += __shfl_xor(sssq[i], msk); }
  if (lr == 0) {
#pragma unroll
    for (int r = 0; r < 4; ++r) {
      int o = o2 + lh * 4 + r;
      atomicAdd(&ws[S3SUM + slot * C3 + o], ssum[r]);
      atomicAdd(&ws[S3SSQ + slot * C3 + o], sssq[r]);
    }
  }
  __syncthreads();
  {
    int row = t >> 1, hf = t & 1;
    const unsigned short* src = (row < 64) ? (y3a + row * Y3S) : (ldss + (row - 64) * Y3S);
    const uint4* s4 = (const uint4*)(src + hf * 32);
    uint4* dst = (uint4*)(y3 + (n0 + row) * 64 + hf * 32);
#pragma unroll
    for (int j = 0; j < 4; ++j) dst[j] = s4[j];
  }
}

// layer4: cost = w4 . relu(bn3(y3)) + b4
__global__ __launch_bounds__(256) void k_layer4(const unsigned short* __restrict__ y3,
                                                float* __restrict__ ws,
                                                const float* __restrict__ w4,
                                                const float* __restrict__ b4) {
  int n = blockIdx.x * 256 + threadIdx.x;
  const float* s3p = ws + S3Sc;
  const float* t3p = ws + S3Tc;
  const uint4* row = (const uint4*)(y3 + (size_t)n * C3);
  float acc = 0.f;
#pragma unroll
  for (int j = 0; j < 8; ++j) {
    uint4 v = row[j];
    unsigned arr[4] = {v.x, v.y, v.z, v.w};
#pragma unroll
    for (int e = 0; e < 4; ++e) {
      int c = j * 8 + e * 2;
      acc += fmaxf(0.f, fmaf(s3p[c], bflo(arr[e]), t3p[c])) * w4[c];
      acc += fmaxf(0.f, fmaf(s3p[c + 1], bfhi(arr[e]), t3p[c + 1])) * w4[c + 1];
    }
  }
  ws[COST_OFF + n] = acc + b4[0];
}

// DAP
__global__ __launch_bounds__(256) void k_dap(const float* __restrict__ ws,
                                             const float* __restrict__ wdap,
                                             float* __restrict__ out) {
  __shared__ float wd[DD * DD];
  int t = threadIdx.x;
  for (int i = t; i < DD * DD; i += 256) wd[i] = wdap[i];
  __syncthreads();
  int p = blockIdx.x * 32 + (t & 31);
  int lg = t >> 5;
  const float* cost = ws + COST_OFF;
  float cr[81];
#pragma unroll
  for (int kk = 0; kk < 81; ++kk) cr[kk] = cost[kk * P + p];
  for (int l = lg; l < 81; l += 8) {
    float acc = 0.f;
#pragma unroll
    for (int kk = 0; kk < 81; ++kk) acc = fmaf(wd[l * 81 + kk], cr[kk], acc);
    out[(size_t)l * P + p] = acc;
  }
}

__global__ void k_marker(float* out) { out[0] = 1.0e30f; }

extern "C" void kernel_launch(void* const* d_in, const int* in_sizes, int n_in,
                              void* d_out, int out_size, void* d_ws, size_t ws_size,
                              hipStream_t stream) {
  const float* f1 = (const float*)d_in[0];
  const float* f2 = (const float*)d_in[1];
  const float* coords = (const float*)d_in[2];
  const float* w1 = (const float*)d_in[3];
  const float* g1 = (const float*)d_in[4];
  const float* be1 = (const float*)d_in[5];
  const float* w2 = (const float*)d_in[6];
  const float* g2 = (const float*)d_in[7];
  const float* be2 = (const float*)d_in[8];
  const float* w3 = (const float*)d_in[9];
  const float* g3 = (const float*)d_in[10];
  const float* be3 = (const float*)d_in[11];
  const float* w4 = (const float*)d_in[12];
  const float* b4 = (const float*)d_in[13];
  const float* wdap = (const float*)d_in[14];
  float* out = (float*)d_out;
  float* ws = (float*)d_ws;

  if (ws_size < WS_NEEDED) {
    k_marker<<<1, 1, 0, stream>>>(out);
    return;
  }
  unsigned short* aT = (unsigned short*)((char*)d_ws + A_BYTE);
  unsigned short* gT = (unsigned short*)((char*)d_ws + G_BYTE);
  unsigned short* w2bf = (unsigned short*)((char*)d_ws + W2BF_BYTE);
  unsigned short* w3bf = (unsigned short*)((char*)d_ws + W3BF_BYTE);
  unsigned short* y1T = (unsigned short*)((char*)d_ws + Y1_BYTE);
  unsigned short* y3 = (unsigned short*)((char*)d_ws + Y3_BYTE);

  hipMemsetAsync(d_ws, 0, (size_t)STATS_ZERO_FLOATS * 4, stream);
  k_prep<<<128, 256, 0, stream>>>(f1, f2, w1, aT, gT);
  k_wprep<<<80, 256, 0, stream>>>(w2, w3, w2bf, w3bf);
  k_sample<<<768, 256, 0, stream>>>(coords, ws, aT, gT, y1T);
  k_finalize<<<1, 128, 0, stream>>>(ws, S1SUM, S1SSQ, g1, be1, S1Sc, S1Tc, C1);
  k_l2stats<<<5184, 256, 0, stream>>>(y1T, ws, w2bf);
  k_finalize<<<1, 128, 0, stream>>>(ws, S2SUM, S2SSQ, g2, be2, S2Sc, S2Tc, C2);
  k_l23<<<5184, 256, 0, stream>>>(y1T, ws, w2bf, w3bf, y3);
  k_finalize<<<1, 128, 0, stream>>>(ws, S3SUM, S3SSQ, g3, be3, S3Sc, S3Tc, C3);
  k_layer4<<<2592, 256, 0, stream>>>(y3, ws, w4, b4);
  k_dap<<<256, 256, 0, stream>>>(ws, wdap, out);
}

// Round 8
// 329.088 us; speedup vs baseline: 5.6281x; 1.0031x over previous
//
#include <hip/hip_runtime.h>
#include <hip/hip_bf16.h>

#define H 64
#define W 128
#define P 8192        // H*W
#define DD 81
#define NS 663552     // DD*P
#define C1 96
#define C2 128
#define C3 64
#define EPSF 1e-5f
#define NSLOT 128

// LDS row strides in shorts (odd multiples of 8 shorts = odd x 16B -> even bank phases)
#define X1S 104       // 208B = 13*16B
#define X2S 136       // 272B = 17*16B
#define Y3S 72        // 144B = 9*16B
#define X1TS 136      // gram transposed tile stride: 272B = 17*16B

#define NGB 648       // gram blocks (x8 tiles each = 5184)

typedef __attribute__((ext_vector_type(8))) short bf16x8;
typedef __attribute__((ext_vector_type(4))) float f32x4;

// ---- workspace layout ----
#define S1SUM 0
#define S1SSQ (S1SUM + NSLOT * C1)
#define M1SUM (S1SSQ + NSLOT * C1)              // 96 x NSLOT slots (x1 channel sums)
#define GOFF  (M1SUM + NSLOT * C2)              // 9216 floats: reduced Gram
#define S3SUM (GOFF + NSLOT * C2)
#define S3SSQ (S3SUM + NSLOT * C3)
#define STATS_ZERO_FLOATS (S3SSQ + NSLOT * C3)  // 73728
#define S1Sc 73728
#define S1Tc (S1Sc + C1)
#define S2Sc (S1Tc + C1)
#define S2Tc (S2Sc + C2)
#define S3Sc (S2Tc + C2)
#define S3Tc (S3Sc + C3)
#define COST_OFF 74304
#define FLOAT_END (COST_OFF + NS)
// byte-indexed region. aT/gT/y1T transposed: [chunk of 4ch][pixel][4]
#define A_BYTE   ((size_t)FLOAT_END * 4)
#define G_BYTE   (A_BYTE + (size_t)P * 96 * 2)
#define W2BF_BYTE (G_BYTE + (size_t)P * 96 * 2)
#define W3BF_BYTE (W2BF_BYTE + (size_t)C2 * C1 * 2)
#define Y1_BYTE  (W3BF_BYTE + (size_t)C3 * C2 * 2)
#define Y3_BYTE  (Y1_BYTE + (size_t)NS * C1 * 2)
#define WS_NEEDED (Y3_BYTE + (size_t)NS * C3 * 2)
// gram partials (648 x 9216 f32 = 23.9MB) overlay the y3 region: y3 is written
// only by k_l23, which runs after k_greduce has consumed the partials.
#define GPART_BYTE Y3_BYTE

__device__ __forceinline__ float bflo(unsigned u) { return __uint_as_float(u << 16); }
__device__ __forceinline__ float bfhi(unsigned u) { return __uint_as_float(u & 0xffff0000u); }
__device__ __forceinline__ float bfu(unsigned short v) { return __uint_as_float((unsigned)v << 16); }

__device__ __forceinline__ unsigned pkbf(float a, float b) {
  __hip_bfloat162 h = __float22bfloat162_rn(make_float2(a, b));
  unsigned u; __builtin_memcpy(&u, &h, 4);
  return u;
}

// a = w1[:, :128] @ f1, g = w1[:, 128:] @ f2  -> bf16, transposed [c4][p][4]
__global__ __launch_bounds__(256) void k_prep(const float* __restrict__ f1,
                                              const float* __restrict__ f2,
                                              const float* __restrict__ w1,
                                              unsigned short* __restrict__ aT,
                                              unsigned short* __restrict__ gT) {
  __shared__ float tile[128][64];
  int t = threadIdx.x;
  int p0 = blockIdx.x * 64;
  int px = t & 63, q = t >> 6;
  int c0 = q * 24;
  for (int pass = 0; pass < 2; ++pass) {
    const float* src = pass ? f2 : f1;
    unsigned short* dst = pass ? gT : aT;
    int koff = pass ? 128 : 0;
    __syncthreads();
    for (int idx = t; idx < 8192; idx += 256) {
      int kk = idx >> 6, xx = idx & 63;
      tile[kk][xx] = src[kk * P + p0 + xx];
    }
    __syncthreads();
    float acc[24];
#pragma unroll
    for (int i = 0; i < 24; ++i) acc[i] = 0.f;
    for (int kk = 0; kk < 128; ++kk) {
      float fv = tile[kk][px];
#pragma unroll
      for (int i = 0; i < 24; ++i)
        acc[i] += w1[(c0 + i) * 256 + koff + kk] * fv;
    }
#pragma unroll
    for (int i = 0; i < 24; i += 4) {
      uint2 pk;
      pk.x = pkbf(acc[i + 0], acc[i + 1]);
      pk.y = pkbf(acc[i + 2], acc[i + 3]);
      *(uint2*)(dst + ((size_t)((c0 + i) >> 2) * P + p0 + px) * 4) = pk;
    }
  }
}

__global__ void k_wprep(const float* __restrict__ w2, const float* __restrict__ w3,
                        unsigned short* __restrict__ w2bf, unsigned short* __restrict__ w3bf) {
  int idx = blockIdx.x * 256 + threadIdx.x;
  if (idx < C2 * C1) {
    w2bf[idx] = (unsigned short)(pkbf(w2[idx], 0.f) & 0xffffu);
  } else if (idx < C2 * C1 + C3 * C2) {
    w3bf[idx - C2 * C1] = (unsigned short)(pkbf(w3[idx - C2 * C1], 0.f) & 0xffffu);
  }
}

// separable gather: per pixel, 10x10 g-neighborhood -> H-pass -> V-pass -> 81 outputs
__global__ __launch_bounds__(256) void k_sample(const float* __restrict__ coords,
                                                float* __restrict__ ws,
                                                const unsigned short* __restrict__ aT,
                                                const unsigned short* __restrict__ gT,
                                                unsigned short* __restrict__ y1T) {
  int t = threadIdx.x, b = blockIdx.x;
  int cg = b % 6;
  int ptile = b / 6;
  int c = cg * 4 + (t >> 6);   // chunk 0..23, uniform per wave
  int px = t & 63;
  int p = ptile * 64 + px;
  float cx = coords[p], cy = coords[P + p];
  float fx0 = floorf(cx), fy0 = floorf(cy);
  float wx1 = cx - fx0, wx0 = 1.f - wx1;
  float wy1 = cy - fy0, wy0 = 1.f - wy1;
  int ixb = (int)fx0 - 4, iyb = (int)fy0 - 4;
  int colOff[10];
  float vx[10];
#pragma unroll
  for (int j = 0; j < 10; ++j) {
    int ix = ixb + j;
    vx[j] = (ix >= 0 && ix < W) ? 1.f : 0.f;
    colOff[j] = min(max(ix, 0), W - 1);
  }
  float ewx0[9], ewx1[9];
#pragma unroll
  for (int j = 0; j < 9; ++j) { ewx0[j] = wx0 * vx[j]; ewx1[j] = wx1 * vx[j + 1]; }
  int rowOff[10];
  float vy[10];
#pragma unroll
  for (int dy = 0; dy < 10; ++dy) {
    int iy = iyb + dy;
    vy[dy] = (iy >= 0 && iy < H) ? 1.f : 0.f;
    rowOff[dy] = min(max(iy, 0), H - 1) * W;
  }
  float ewy0[9], ewy1[9];
#pragma unroll
  for (int d = 0; d < 9; ++d) { ewy0[d] = wy0 * vy[d]; ewy1[d] = wy1 * vy[d + 1]; }
  float av[4];
  {
    uint2 a2 = *(const uint2*)(aT + ((size_t)c * P + p) * 4);
    av[0] = bflo(a2.x); av[1] = bfhi(a2.x); av[2] = bflo(a2.y); av[3] = bfhi(a2.y);
  }
  const unsigned short* gc = gT + (size_t)c * P * 4;
  float Hb[2][9][4];
  float sum[4] = {0.f, 0.f, 0.f, 0.f}, ssq[4] = {0.f, 0.f, 0.f, 0.f};
#pragma unroll
  for (int dy = 0; dy < 10; ++dy) {
    const int cur = dy & 1, prv = cur ^ 1;
    uint2 gv[10];
    const unsigned short* grow = gc + (size_t)rowOff[dy] * 4;
#pragma unroll
    for (int j = 0; j < 10; ++j) gv[j] = *(const uint2*)(grow + colOff[j] * 4);
#pragma unroll
    for (int j = 0; j < 9; ++j) {
      Hb[cur][j][0] = fmaf(ewx1[j], bflo(gv[j + 1].x), ewx0[j] * bflo(gv[j].x));
      Hb[cur][j][1] = fmaf(ewx1[j], bfhi(gv[j + 1].x), ewx0[j] * bfhi(gv[j].x));
      Hb[cur][j][2] = fmaf(ewx1[j], bflo(gv[j + 1].y), ewx0[j] * bflo(gv[j].y));
      Hb[cur][j][3] = fmaf(ewx1[j], bfhi(gv[j + 1].y), ewx0[j] * bfhi(gv[j].y));
    }
    if (dy >= 1) {
      const int dyk = dy - 1;
      float e0 = ewy0[dyk], e1 = ewy1[dyk];
#pragma unroll
      for (int j = 0; j < 9; ++j) {
        float o0 = fmaf(e0, Hb[prv][j][0], fmaf(e1, Hb[cur][j][0], av[0]));
        float o1 = fmaf(e0, Hb[prv][j][1], fmaf(e1, Hb[cur][j][1], av[1]));
        float o2 = fmaf(e0, Hb[prv][j][2], fmaf(e1, Hb[cur][j][2], av[2]));
        float o3 = fmaf(e0, Hb[prv][j][3], fmaf(e1, Hb[cur][j][3], av[3]));
        sum[0] += o0; ssq[0] = fmaf(o0, o0, ssq[0]);
        sum[1] += o1; ssq[1] = fmaf(o1, o1, ssq[1]);
        sum[2] += o2; ssq[2] = fmaf(o2, o2, ssq[2]);
        sum[3] += o3; ssq[3] = fmaf(o3, o3, ssq[3]);
        uint2 pk;
        pk.x = pkbf(o0, o1);
        pk.y = pkbf(o2, o3);
        int kk = j * 9 + dyk;   // k = xdisp*9 + ydisp (reference order)
        *(uint2*)(y1T + (((size_t)kk * 24 + c) * P + p) * 4) = pk;
      }
    }
  }
#pragma unroll
  for (int m = 1; m < 64; m <<= 1) {
#pragma unroll
    for (int e = 0; e < 4; ++e) {
      sum[e] += __shfl_xor(sum[e], m);
      ssq[e] += __shfl_xor(ssq[e], m);
    }
  }
  if ((t & 63) == 0) {
    int slot = b & (NSLOT - 1);
#pragma unroll
    for (int e = 0; e < 4; ++e) {
      atomicAdd(&ws[S1SUM + slot * C1 + c * 4 + e], sum[e]);
      atomicAdd(&ws[S1SSQ + slot * C1 + c * 4 + e], ssq[e]);
    }
  }
}

__global__ void k_finalize(float* __restrict__ ws, int sumO, int ssqO,
                           const float* __restrict__ gamma, const float* __restrict__ beta,
                           int sO, int tO, int C) {
  int c = threadIdx.x;
  if (c < C) {
    float su = 0.f, sq = 0.f;
    for (int s = 0; s < NSLOT; ++s) { su += ws[sumO + s * C + c]; sq += ws[ssqO + s * C + c]; }
    float mean = su * (1.0f / (float)NS);
    float var = sq * (1.0f / (float)NS) - mean * mean;
    float sc = gamma[c] * rsqrtf(var + EPSF);
    ws[sO + c] = sc;
    ws[tO + c] = beta[c] - mean * sc;
  }
}

// Gram pass: x1 = bn1+relu(y1) -> G += x1^T x1 (96x96, over pixels) + m1 = sum(x1)
// 648 blocks x 8 tiles of 128px. x1 staged TRANSPOSED [96ch][128px] for both MFMA operands.
__global__ __launch_bounds__(256) void k_gram(const unsigned short* __restrict__ y1T,
                                              float* __restrict__ ws,
                                              float* __restrict__ gpart) {
  __shared__ unsigned short x1t[96 * X1TS];   // 26112B
  int t = threadIdx.x, b = blockIdx.x;
  int w = t >> 6, l = t & 63;
  int lr = l & 15, lh = l >> 4;
  int i0 = (w >> 1) * 48, j0 = (w & 1) * 48;  // each wave owns a 3x3 block of 16-tiles
  f32x4 acc[9];
  f32x4 zero4 = {0.f, 0.f, 0.f, 0.f};
#pragma unroll
  for (int q = 0; q < 9; ++q) acc[q] = zero4;
  int c = t >> 3, pg = t & 7;   // build mapping: chunk c (0..23 active), pixel group pg
  float s1v[4], t1v[4];
  if (c < 24) {
#pragma unroll
    for (int e = 0; e < 4; ++e) { s1v[e] = ws[S1Sc + c * 4 + e]; t1v[e] = ws[S1Tc + c * 4 + e]; }
  }
  float msum[4] = {0.f, 0.f, 0.f, 0.f};
  for (int it = 0; it < 8; ++it) {
    int idx = b * 8 + it;
    int k = idx >> 6, p0 = (idx & 63) << 7;
    const unsigned short* y1k = y1T + (size_t)k * P * 96;
    __syncthreads();   // previous iteration's Gram reads done
    if (c < 24) {
      int pbase = p0 + pg * 16;
      unsigned rowu[4][8];
#pragma unroll
      for (int ii = 0; ii < 8; ++ii) {
        uint4 v = *(const uint4*)(y1k + ((size_t)c * P + pbase + ii * 2) * 4);
        float x00 = fmaxf(0.f, fmaf(s1v[0], bflo(v.x), t1v[0]));
        float x10 = fmaxf(0.f, fmaf(s1v[1], bfhi(v.x), t1v[1]));
        float x20 = fmaxf(0.f, fmaf(s1v[2], bflo(v.y), t1v[2]));
        float x30 = fmaxf(0.f, fmaf(s1v[3], bfhi(v.y), t1v[3]));
        float x01 = fmaxf(0.f, fmaf(s1v[0], bflo(v.z), t1v[0]));
        float x11 = fmaxf(0.f, fmaf(s1v[1], bfhi(v.z), t1v[1]));
        float x21 = fmaxf(0.f, fmaf(s1v[2], bflo(v.w), t1v[2]));
        float x31 = fmaxf(0.f, fmaf(s1v[3], bfhi(v.w), t1v[3]));
        msum[0] += x00 + x01; msum[1] += x10 + x11;
        msum[2] += x20 + x21; msum[3] += x30 + x31;
        rowu[0][ii] = pkbf(x00, x01);
        rowu[1][ii] = pkbf(x10, x11);
        rowu[2][ii] = pkbf(x20, x21);
        rowu[3][ii] = pkbf(x30, x31);
      }
#pragma unroll
      for (int e = 0; e < 4; ++e) {
        unsigned short* dst = x1t + (c * 4 + e) * X1TS + pg * 16;
        uint4 pk0; pk0.x = rowu[e][0]; pk0.y = rowu[e][1]; pk0.z = rowu[e][2]; pk0.w = rowu[e][3];
        uint4 pk1; pk1.x = rowu[e][4]; pk1.y = rowu[e][5]; pk1.z = rowu[e][6]; pk1.w = rowu[e][7];
        *(uint4*)dst = pk0;
        *(uint4*)(dst + 8) = pk1;
      }
    }
    __syncthreads();
#pragma unroll
    for (int kk = 0; kk < 4; ++kk) {
      bf16x8 a3[3], b3[3];
#pragma unroll
      for (int a = 0; a < 3; ++a)
        a3[a] = *(const bf16x8*)(const void*)(x1t + (i0 + a * 16 + lr) * X1TS + kk * 32 + lh * 8);
#pragma unroll
      for (int bb = 0; bb < 3; ++bb)
        b3[bb] = *(const bf16x8*)(const void*)(x1t + (j0 + bb * 16 + lr) * X1TS + kk * 32 + lh * 8);
#pragma unroll
      for (int a = 0; a < 3; ++a)
#pragma unroll
        for (int bb = 0; bb < 3; ++bb)
          acc[a * 3 + bb] = __builtin_amdgcn_mfma_f32_16x16x32_bf16(a3[a], b3[bb], acc[a * 3 + bb], 0, 0, 0);
    }
  }
  // write partial G: gpart[b][row*96+col]
  {
    float* gp = gpart + (size_t)b * 9216;
#pragma unroll
    for (int a = 0; a < 3; ++a)
#pragma unroll
      for (int bb = 0; bb < 3; ++bb) {
        int ti = (w >> 1) * 3 + a, tj = (w & 1) * 3 + bb;
        f32x4 v = acc[a * 3 + bb];
#pragma unroll
        for (int r = 0; r < 4; ++r)
          gp[(ti * 16 + lh * 4 + r) * 96 + tj * 16 + lr] = v[r];
      }
  }
  // m1 partial sums (channel sums of x1)
  if (c < 24) {
#pragma unroll
    for (int m = 1; m < 8; m <<= 1)
#pragma unroll
      for (int e = 0; e < 4; ++e) msum[e] += __shfl_xor(msum[e], m);
    if (pg == 0) {
      int slot = b & (NSLOT - 1);
#pragma unroll
      for (int e = 0; e < 4; ++e) atomicAdd(&ws[M1SUM + slot * 96 + c * 4 + e], msum[e]);
    }
  }
}

// reduce 648 partial Grams -> ws[GOFF + 9216]
__global__ void k_greduce(const float* __restrict__ gpart, float* __restrict__ ws) {
  int e = blockIdx.x * 256 + threadIdx.x;   // 36 blocks
  float s = 0.f;
  for (int b = 0; b < NGB; ++b) s += gpart[(size_t)b * 9216 + e];
  ws[GOFF + e] = s;
}

// stats2 from Gram: mean_o = w2_o.m1/N; E[y2^2]_o = w2_o^T G w2_o / N
__global__ __launch_bounds__(256) void k_fin2g(float* __restrict__ ws,
                                               const unsigned short* __restrict__ w2bf,
                                               const float* __restrict__ g2,
                                               const float* __restrict__ be2) {
  __shared__ float wrow[96];
  __shared__ float m1f[96];
  __shared__ float red[8];
  int o = blockIdx.x, t = threadIdx.x;
  if (t < 96) {
    wrow[t] = bfu(w2bf[o * 96 + t]);
    float s = 0.f;
    for (int sl = 0; sl < NSLOT; ++sl) s += ws[M1SUM + sl * 96 + t];
    m1f[t] = s;
  }
  __syncthreads();
  float quad = 0.f;
  for (int e = t; e < 9216; e += 256) {
    int i = e / 96, j = e - i * 96;
    quad = fmaf(wrow[i] * wrow[j], ws[GOFF + e], quad);
  }
  float msm = (t < 96) ? wrow[t] * m1f[t] : 0.f;
#pragma unroll
  for (int m = 1; m < 64; m <<= 1) { quad += __shfl_xor(quad, m); msm += __shfl_xor(msm, m); }
  if ((t & 63) == 0) { red[t >> 6] = quad; red[4 + (t >> 6)] = msm; }
  __syncthreads();
  if (t == 0) {
    float q = red[0] + red[1] + red[2] + red[3];
    float mm = red[4] + red[5] + red[6] + red[7];
    float mean = mm * (1.0f / (float)NS);
    float var = q * (1.0f / (float)NS) - mean * mean;
    float sc = g2[o] * rsqrtf(var + EPSF);
    ws[S2Sc + o] = sc;
    ws[S2Tc + o] = be2[o] - mean * sc;
  }
}

// build x1 (bn1+relu of y1T) into [128][X1S] LDS tile; y1k = k-plane base
__device__ __forceinline__ void build_x1(const unsigned short* __restrict__ y1k,
                                         const float* __restrict__ ws,
                                         unsigned short* lds, int p0, int t) {
  int s = t >> 1, hh = t & 1;
  int p = p0 + s;
  const float* s1p = ws + S1Sc;
  const float* t1p = ws + S1Tc;
  unsigned short* base = lds + s * X1S + hh * 48;
#pragma unroll
  for (int i2 = 0; i2 < 6; ++i2) {
    int c0 = hh * 12 + i2 * 2;
    uint2 va = *(const uint2*)(y1k + ((size_t)c0 * P + p) * 4);
    uint2 vb = *(const uint2*)(y1k + ((size_t)(c0 + 1) * P + p) * 4);
    int cb = c0 * 4;
    float x0 = fmaxf(0.f, fmaf(s1p[cb + 0], bflo(va.x), t1p[cb + 0]));
    float x1 = fmaxf(0.f, fmaf(s1p[cb + 1], bfhi(va.x), t1p[cb + 1]));
    float x2 = fmaxf(0.f, fmaf(s1p[cb + 2], bflo(va.y), t1p[cb + 2]));
    float x3 = fmaxf(0.f, fmaf(s1p[cb + 3], bfhi(va.y), t1p[cb + 3]));
    float x4 = fmaxf(0.f, fmaf(s1p[cb + 4], bflo(vb.x), t1p[cb + 4]));
    float x5 = fmaxf(0.f, fmaf(s1p[cb + 5], bfhi(vb.x), t1p[cb + 5]));
    float x6 = fmaxf(0.f, fmaf(s1p[cb + 6], bflo(vb.y), t1p[cb + 6]));
    float x7 = fmaxf(0.f, fmaf(s1p[cb + 7], bfhi(vb.y), t1p[cb + 7]));
    uint4 pk;
    pk.x = pkbf(x0, x1); pk.y = pkbf(x2, x3); pk.z = pkbf(x4, x5); pk.w = pkbf(x6, x7);
    *(uint4*)(base + i2 * 8) = pk;
  }
}

// fused layers 2+3
__global__ __launch_bounds__(256) void k_l23(const unsigned short* __restrict__ y1T,
                                             float* __restrict__ ws,
                                             const unsigned short* __restrict__ w2bf,
                                             const unsigned short* __restrict__ w3bf,
                                             unsigned short* __restrict__ y3) {
  __shared__ unsigned short ldss[128 * X1S];
  int t = threadIdx.x, b = blockIdx.x;
  int k = b >> 6, p0 = (b & 63) << 7;
  size_t n0 = (size_t)k * P + p0;
  int slot = b & (NSLOT - 1);
  const unsigned short* y1k = y1T + (size_t)k * P * 96;
  build_x1(y1k, ws, ldss, p0, t);
  __syncthreads();
  int l = t & 63, wv = t >> 6;
  int o0w = wv * 32;
  int lr = l & 15, lh = l >> 4;
  bf16x8 af[2][3];
#pragma unroll
  for (int m = 0; m < 2; ++m)
#pragma unroll
    for (int kk = 0; kk < 3; ++kk)
      af[m][kk] = *(const bf16x8*)(const void*)(w2bf + (size_t)(o0w + m * 16 + lr) * 96 + kk * 32 + lh * 8);
  f32x4 acc[2][8];
  f32x4 zero4 = {0.f, 0.f, 0.f, 0.f};
#pragma unroll
  for (int m = 0; m < 2; ++m)
#pragma unroll
    for (int n = 0; n < 8; ++n) acc[m][n] = zero4;
#pragma unroll
  for (int kk = 0; kk < 3; ++kk)
#pragma unroll
    for (int n = 0; n < 8; ++n) {
      bf16x8 bfr = *(const bf16x8*)(const void*)(ldss + (n * 16 + lr) * X1S + kk * 32 + lh * 8);
      acc[0][n] = __builtin_amdgcn_mfma_f32_16x16x32_bf16(af[0][kk], bfr, acc[0][n], 0, 0, 0);
      acc[1][n] = __builtin_amdgcn_mfma_f32_16x16x32_bf16(af[1][kk], bfr, acc[1][n], 0, 0, 0);
    }
  float s2v[2][4], t2v[2][4];
#pragma unroll
  for (int m = 0; m < 2; ++m)
#pragma unroll
    for (int r = 0; r < 4; ++r) {
      int cc = o0w + m * 16 + lh * 4 + r;
      s2v[m][r] = ws[S2Sc + cc];
      t2v[m][r] = ws[S2Tc + cc];
    }
  int o2 = wv * 16;
  bf16x8 af2[4];
#pragma unroll
  for (int kk = 0; kk < 4; ++kk)
    af2[kk] = *(const bf16x8*)(const void*)(w3bf + (size_t)(o2 + lr) * 128 + kk * 32 + lh * 8);
  unsigned short* x2s = ldss;               // [64][X2S]
  unsigned short* y3a = ldss + 8704;        // [64][Y3S] at byte 17408
  float ssum[4] = {0.f, 0.f, 0.f, 0.f}, sssq[4] = {0.f, 0.f, 0.f, 0.f};
#pragma unroll
  for (int h = 0; h < 2; ++h) {
    __syncthreads();
#pragma unroll
    for (int m = 0; m < 2; ++m)
#pragma unroll
      for (int n2 = 0; n2 < 4; ++n2) {
        f32x4 v = acc[m][h * 4 + n2];
        float x0 = fmaxf(0.f, fmaf(s2v[m][0], v[0], t2v[m][0]));
        float x1v = fmaxf(0.f, fmaf(s2v[m][1], v[1], t2v[m][1]));
        float x2v = fmaxf(0.f, fmaf(s2v[m][2], v[2], t2v[m][2]));
        float x3 = fmaxf(0.f, fmaf(s2v[m][3], v[3], t2v[m][3]));
        uint2 pk;
        pk.x = pkbf(x0, x1v);
        pk.y = pkbf(x2v, x3);
        *(uint2*)(x2s + (n2 * 16 + lr) * X2S + o0w + m * 16 + lh * 4) = pk;
      }
    __syncthreads();
    f32x4 acc2[4];
#pragma unroll
    for (int n2 = 0; n2 < 4; ++n2) acc2[n2] = zero4;
#pragma unroll
    for (int kk = 0; kk < 4; ++kk)
#pragma unroll
      for (int n2 = 0; n2 < 4; ++n2) {
        bf16x8 bfr = *(const bf16x8*)(const void*)(x2s + (n2 * 16 + lr) * X2S + kk * 32 + lh * 8);
        acc2[n2] = __builtin_amdgcn_mfma_f32_16x16x32_bf16(af2[kk], bfr, acc2[n2], 0, 0, 0);
      }
#pragma unroll
    for (int n2 = 0; n2 < 4; ++n2) {
      f32x4 v = acc2[n2];
#pragma unroll
      for (int r = 0; r < 4; ++r) { float x = v[r]; ssum[r] += x; sssq[r] = fmaf(x, x, sssq[r]); }
    }
    __syncthreads();
    unsigned short* dst = h ? ldss : y3a;
#pragma unroll
    for (int n2 = 0; n2 < 4; ++n2) {
      f32x4 v = acc2[n2];
      uint2 pk;
      pk.x = pkbf(v[0], v[1]);
      pk.y = pkbf(v[2], v[3]);
      *(uint2*)(dst + (n2 * 16 + lr) * Y3S + o2 + lh * 4) = pk;
    }
  }
#pragma unroll
  for (int msk = 1; msk < 16; msk <<= 1)
#pragma unroll
    for (int i = 0; i < 4; ++i) { ssum[i] += __shfl_xor(ssum[i], msk); sssq[i] += __shfl_xor(sssq[i], msk); }
  if (lr == 0) {
#pragma unroll
    for (int r = 0; r < 4; ++r) {
      int o = o2 + lh * 4 + r;
      atomicAdd(&ws[S3SUM + slot * C3 + o], ssum[r]);
      atomicAdd(&ws[S3SSQ + slot * C3 + o], sssq[r]);
    }
  }
  __syncthreads();
  {
    int row = t >> 1, hf = t & 1;
    const unsigned short* src = (row < 64) ? (y3a + row * Y3S) : (ldss + (row - 64) * Y3S);
    const uint4* s4 = (const uint4*)(src + hf * 32);
    uint4* dst = (uint4*)(y3 + (n0 + row) * 64 + hf * 32);
#pragma unroll
    for (int j = 0; j < 4; ++j) dst[j] = s4[j];
  }
}

// layer4: cost = w4 . relu(bn3(y3)) + b4
__global__ __launch_bounds__(256) void k_layer4(const unsigned short* __restrict__ y3,
                                                float* __restrict__ ws,
                                                const float* __restrict__ w4,
                                                const float* __restrict__ b4) {
  int n = blockIdx.x * 256 + threadIdx.x;
  const float* s3p = ws + S3Sc;
  const float* t3p = ws + S3Tc;
  const uint4* row = (const uint4*)(y3 + (size_t)n * C3);
  float acc = 0.f;
#pragma unroll
  for (int j = 0; j < 8; ++j) {
    uint4 v = row[j];
    unsigned arr[4] = {v.x, v.y, v.z, v.w};
#pragma unroll
    for (int e = 0; e < 4; ++e) {
      int c = j * 8 + e * 2;
      acc += fmaxf(0.f, fmaf(s3p[c], bflo(arr[e]), t3p[c])) * w4[c];
      acc += fmaxf(0.f, fmaf(s3p[c + 1], bfhi(arr[e]), t3p[c + 1])) * w4[c + 1];
    }
  }
  ws[COST_OFF + n] = acc + b4[0];
}

// DAP
__global__ __launch_bounds__(256) void k_dap(const float* __restrict__ ws,
                                             const float* __restrict__ wdap,
                                             float* __restrict__ out) {
  __shared__ float wd[DD * DD];
  int t = threadIdx.x;
  for (int i = t; i < DD * DD; i += 256) wd[i] = wdap[i];
  __syncthreads();
  int p = blockIdx.x * 32 + (t & 31);
  int lg = t >> 5;
  const float* cost = ws + COST_OFF;
  float cr[81];
#pragma unroll
  for (int kk = 0; kk < 81; ++kk) cr[kk] = cost[kk * P + p];
  for (int l = lg; l < 81; l += 8) {
    float acc = 0.f;
#pragma unroll
    for (int kk = 0; kk < 81; ++kk) acc = fmaf(wd[l * 81 + kk], cr[kk], acc);
    out[(size_t)l * P + p] = acc;
  }
}

__global__ void k_marker(float* out) { out[0] = 1.0e30f; }

extern "C" void kernel_launch(void* const* d_in, const int* in_sizes, int n_in,
                              void* d_out, int out_size, void* d_ws, size_t ws_size,
                              hipStream_t stream) {
  const float* f1 = (const float*)d_in[0];
  const float* f2 = (const float*)d_in[1];
  const float* coords = (const float*)d_in[2];
  const float* w1 = (const float*)d_in[3];
  const float* g1 = (const float*)d_in[4];
  const float* be1 = (const float*)d_in[5];
  const float* w2 = (const float*)d_in[6];
  const float* g2 = (const float*)d_in[7];
  const float* be2 = (const float*)d_in[8];
  const float* w3 = (const float*)d_in[9];
  const float* g3 = (const float*)d_in[10];
  const float* be3 = (const float*)d_in[11];
  const float* w4 = (const float*)d_in[12];
  const float* b4 = (const float*)d_in[13];
  const float* wdap = (const float*)d_in[14];
  float* out = (float*)d_out;
  float* ws = (float*)d_ws;

  if (ws_size < WS_NEEDED) {
    k_marker<<<1, 1, 0, stream>>>(out);
    return;
  }
  unsigned short* aT = (unsigned short*)((char*)d_ws + A_BYTE);
  unsigned short* gT = (unsigned short*)((char*)d_ws + G_BYTE);
  unsigned short* w2bf = (unsigned short*)((char*)d_ws + W2BF_BYTE);
  unsigned short* w3bf = (unsigned short*)((char*)d_ws + W3BF_BYTE);
  unsigned short* y1T = (unsigned short*)((char*)d_ws + Y1_BYTE);
  unsigned short* y3 = (unsigned short*)((char*)d_ws + Y3_BYTE);
  float* gpart = (float*)((char*)d_ws + GPART_BYTE);   // overlays y3 (dead until k_l23)

  hipMemsetAsync(d_ws, 0, (size_t)STATS_ZERO_FLOATS * 4, stream);
  k_prep<<<128, 256, 0, stream>>>(f1, f2, w1, aT, gT);
  k_wprep<<<80, 256, 0, stream>>>(w2, w3, w2bf, w3bf);
  k_sample<<<768, 256, 0, stream>>>(coords, ws, aT, gT, y1T);
  k_finalize<<<1, 128, 0, stream>>>(ws, S1SUM, S1SSQ, g1, be1, S1Sc, S1Tc, C1);
  k_gram<<<NGB, 256, 0, stream>>>(y1T, ws, gpart);
  k_greduce<<<36, 256, 0, stream>>>(gpart, ws);
  k_fin2g<<<128, 256, 0, stream>>>(ws, w2bf, g2, be2);
  k_l23<<<5184, 256, 0, stream>>>(y1T, ws, w2bf, w3bf, y3);
  k_finalize<<<1, 128, 0, stream>>>(ws, S3SUM, S3SSQ, g3, be3, S3Sc, S3Tc, C3);
  k_layer4<<<2592, 256, 0, stream>>>(y3, ws, w4, b4);
  k_dap<<<256, 256, 0, stream>>>(ws, wdap, out);
}

// Round 9
// 294.130 us; speedup vs baseline: 6.2970x; 1.1189x over previous
//
#include <hip/hip_runtime.h>
#include <hip/hip_bf16.h>

#define H 64
#define W 128
#define P 8192        // H*W
#define DD 81
#define NS 663552     // DD*P
#define C1 96
#define C2 128
#define C3 64
#define EPSF 1e-5f
#define NSLOT 128

// LDS row strides in shorts (odd multiples of 8 shorts = odd x 16B -> even bank phases)
#define X1S 104       // 208B = 13*16B
#define X2S 136       // 272B = 17*16B
#define X1TS 136      // gram transposed tile stride

#define NGB 324       // gram blocks (x16 tiles each = 5184)
#define NGSLOT 8

typedef __attribute__((ext_vector_type(8))) short bf16x8;
typedef __attribute__((ext_vector_type(4))) float f32x4;

// ---- workspace layout (floats) ----
#define S1SUM 0                                  // 128*96
#define S1SSQ (S1SUM + NSLOT * C1)               // 12288
#define M1SUM (S1SSQ + NSLOT * C1)               // 24576, 128*96
#define S3SUM (M1SUM + NSLOT * C1)               // 36864, 128*64
#define S3SSQ (S3SUM + NSLOT * C3)               // 45056
#define GSLOT (S3SSQ + NSLOT * C3)               // 53248, 8*9216
#define STATS_ZERO_FLOATS (GSLOT + NGSLOT * 9216)  // 126976
#define S1Sc 126976
#define S1Tc (S1Sc + C1)
#define S2Sc (S1Tc + C1)
#define S2Tc (S2Sc + C2)
#define S3Sc (S2Tc + C2)
#define S3Tc (S3Sc + C3)
#define GOFF 127552                              // 9216 reduced Gram
#define COST_OFF (GOFF + 9216)                   // 136768
#define FLOAT_END (COST_OFF + NS)                // 800320
// byte-indexed region. aT/gT/y1T/y3T transposed: [chunk of 4ch][sample][4]
#define A_BYTE   ((size_t)FLOAT_END * 4)
#define G_BYTE   (A_BYTE + (size_t)P * 96 * 2)
#define W2BF_BYTE (G_BYTE + (size_t)P * 96 * 2)
#define W3BF_BYTE (W2BF_BYTE + (size_t)C2 * C1 * 2)
#define Y1_BYTE  (W3BF_BYTE + (size_t)C3 * C2 * 2)
#define Y3_BYTE  (Y1_BYTE + (size_t)NS * C1 * 2)
#define WS_NEEDED (Y3_BYTE + (size_t)NS * C3 * 2)

__device__ __forceinline__ float bflo(unsigned u) { return __uint_as_float(u << 16); }
__device__ __forceinline__ float bfhi(unsigned u) { return __uint_as_float(u & 0xffff0000u); }
__device__ __forceinline__ float bfu(unsigned short v) { return __uint_as_float((unsigned)v << 16); }

__device__ __forceinline__ unsigned pkbf(float a, float b) {
  __hip_bfloat162 h = __float22bfloat162_rn(make_float2(a, b));
  unsigned u; __builtin_memcpy(&u, &h, 4);
  return u;
}

// a = w1[:, :128] @ f1, g = w1[:, 128:] @ f2  -> bf16, transposed [c4][p][4]
__global__ __launch_bounds__(256) void k_prep(const float* __restrict__ f1,
                                              const float* __restrict__ f2,
                                              const float* __restrict__ w1,
                                              unsigned short* __restrict__ aT,
                                              unsigned short* __restrict__ gT) {
  __shared__ float tile[128][64];
  int t = threadIdx.x;
  int p0 = blockIdx.x * 64;
  int px = t & 63, q = t >> 6;
  int c0 = q * 24;
  for (int pass = 0; pass < 2; ++pass) {
    const float* src = pass ? f2 : f1;
    unsigned short* dst = pass ? gT : aT;
    int koff = pass ? 128 : 0;
    __syncthreads();
    for (int idx = t; idx < 8192; idx += 256) {
      int kk = idx >> 6, xx = idx & 63;
      tile[kk][xx] = src[kk * P + p0 + xx];
    }
    __syncthreads();
    float acc[24];
#pragma unroll
    for (int i = 0; i < 24; ++i) acc[i] = 0.f;
    for (int kk = 0; kk < 128; ++kk) {
      float fv = tile[kk][px];
#pragma unroll
      for (int i = 0; i < 24; ++i)
        acc[i] += w1[(c0 + i) * 256 + koff + kk] * fv;
    }
#pragma unroll
    for (int i = 0; i < 24; i += 4) {
      uint2 pk;
      pk.x = pkbf(acc[i + 0], acc[i + 1]);
      pk.y = pkbf(acc[i + 2], acc[i + 3]);
      *(uint2*)(dst + ((size_t)((c0 + i) >> 2) * P + p0 + px) * 4) = pk;
    }
  }
}

__global__ void k_wprep(const float* __restrict__ w2, const float* __restrict__ w3,
                        unsigned short* __restrict__ w2bf, unsigned short* __restrict__ w3bf) {
  int idx = blockIdx.x * 256 + threadIdx.x;
  if (idx < C2 * C1) {
    w2bf[idx] = (unsigned short)(pkbf(w2[idx], 0.f) & 0xffffu);
  } else if (idx < C2 * C1 + C3 * C2) {
    w3bf[idx - C2 * C1] = (unsigned short)(pkbf(w3[idx - C2 * C1], 0.f) & 0xffffu);
  }
}

// separable gather: per pixel, 10x10 g-neighborhood -> H-pass -> V-pass -> 81 outputs
__global__ __launch_bounds__(256) void k_sample(const float* __restrict__ coords,
                                                float* __restrict__ ws,
                                                const unsigned short* __restrict__ aT,
                                                const unsigned short* __restrict__ gT,
                                                unsigned short* __restrict__ y1T) {
  int t = threadIdx.x, b = blockIdx.x;
  int cg = b % 6;
  int ptile = b / 6;
  int c = cg * 4 + (t >> 6);   // chunk 0..23, uniform per wave
  int px = t & 63;
  int p = ptile * 64 + px;
  float cx = coords[p], cy = coords[P + p];
  float fx0 = floorf(cx), fy0 = floorf(cy);
  float wx1 = cx - fx0, wx0 = 1.f - wx1;
  float wy1 = cy - fy0, wy0 = 1.f - wy1;
  int ixb = (int)fx0 - 4, iyb = (int)fy0 - 4;
  int colOff[10];
  float vx[10];
#pragma unroll
  for (int j = 0; j < 10; ++j) {
    int ix = ixb + j;
    vx[j] = (ix >= 0 && ix < W) ? 1.f : 0.f;
    colOff[j] = min(max(ix, 0), W - 1);
  }
  float ewx0[9], ewx1[9];
#pragma unroll
  for (int j = 0; j < 9; ++j) { ewx0[j] = wx0 * vx[j]; ewx1[j] = wx1 * vx[j + 1]; }
  int rowOff[10];
  float vy[10];
#pragma unroll
  for (int dy = 0; dy < 10; ++dy) {
    int iy = iyb + dy;
    vy[dy] = (iy >= 0 && iy < H) ? 1.f : 0.f;
    rowOff[dy] = min(max(iy, 0), H - 1) * W;
  }
  float ewy0[9], ewy1[9];
#pragma unroll
  for (int d = 0; d < 9; ++d) { ewy0[d] = wy0 * vy[d]; ewy1[d] = wy1 * vy[d + 1]; }
  float av[4];
  {
    uint2 a2 = *(const uint2*)(aT + ((size_t)c * P + p) * 4);
    av[0] = bflo(a2.x); av[1] = bfhi(a2.x); av[2] = bflo(a2.y); av[3] = bfhi(a2.y);
  }
  const unsigned short* gc = gT + (size_t)c * P * 4;
  float Hb[2][9][4];
  float sum[4] = {0.f, 0.f, 0.f, 0.f}, ssq[4] = {0.f, 0.f, 0.f, 0.f};
#pragma unroll
  for (int dy = 0; dy < 10; ++dy) {
    const int cur = dy & 1, prv = cur ^ 1;
    uint2 gv[10];
    const unsigned short* grow = gc + (size_t)rowOff[dy] * 4;
#pragma unroll
    for (int j = 0; j < 10; ++j) gv[j] = *(const uint2*)(grow + colOff[j] * 4);
#pragma unroll
    for (int j = 0; j < 9; ++j) {
      Hb[cur][j][0] = fmaf(ewx1[j], bflo(gv[j + 1].x), ewx0[j] * bflo(gv[j].x));
      Hb[cur][j][1] = fmaf(ewx1[j], bfhi(gv[j + 1].x), ewx0[j] * bfhi(gv[j].x));
      Hb[cur][j][2] = fmaf(ewx1[j], bflo(gv[j + 1].y), ewx0[j] * bflo(gv[j].y));
      Hb[cur][j][3] = fmaf(ewx1[j], bfhi(gv[j + 1].y), ewx0[j] * bfhi(gv[j].y));
    }
    if (dy >= 1) {
      const int dyk = dy - 1;
      float e0 = ewy0[dyk], e1 = ewy1[dyk];
#pragma unroll
      for (int j = 0; j < 9; ++j) {
        float o0 = fmaf(e0, Hb[prv][j][0], fmaf(e1, Hb[cur][j][0], av[0]));
        float o1 = fmaf(e0, Hb[prv][j][1], fmaf(e1, Hb[cur][j][1], av[1]));
        float o2 = fmaf(e0, Hb[prv][j][2], fmaf(e1, Hb[cur][j][2], av[2]));
        float o3 = fmaf(e0, Hb[prv][j][3], fmaf(e1, Hb[cur][j][3], av[3]));
        sum[0] += o0; ssq[0] = fmaf(o0, o0, ssq[0]);
        sum[1] += o1; ssq[1] = fmaf(o1, o1, ssq[1]);
        sum[2] += o2; ssq[2] = fmaf(o2, o2, ssq[2]);
        sum[3] += o3; ssq[3] = fmaf(o3, o3, ssq[3]);
        uint2 pk;
        pk.x = pkbf(o0, o1);
        pk.y = pkbf(o2, o3);
        int kk = j * 9 + dyk;   // k = xdisp*9 + ydisp (reference order)
        *(uint2*)(y1T + (((size_t)kk * 24 + c) * P + p) * 4) = pk;
      }
    }
  }
#pragma unroll
  for (int m = 1; m < 64; m <<= 1) {
#pragma unroll
    for (int e = 0; e < 4; ++e) {
      sum[e] += __shfl_xor(sum[e], m);
      ssq[e] += __shfl_xor(ssq[e], m);
    }
  }
  if ((t & 63) == 0) {
    int slot = b & (NSLOT - 1);
#pragma unroll
    for (int e = 0; e < 4; ++e) {
      atomicAdd(&ws[S1SUM + slot * C1 + c * 4 + e], sum[e]);
      atomicAdd(&ws[S1SSQ + slot * C1 + c * 4 + e], ssq[e]);
    }
  }
}

__global__ void k_finalize(float* __restrict__ ws, int sumO, int ssqO,
                           const float* __restrict__ gamma, const float* __restrict__ beta,
                           int sO, int tO, int C) {
  int c = threadIdx.x;
  if (c < C) {
    float su = 0.f, sq = 0.f;
    for (int s = 0; s < NSLOT; ++s) { su += ws[sumO + s * C + c]; sq += ws[ssqO + s * C + c]; }
    float mean = su * (1.0f / (float)NS);
    float var = sq * (1.0f / (float)NS) - mean * mean;
    float sc = gamma[c] * rsqrtf(var + EPSF);
    ws[sO + c] = sc;
    ws[tO + c] = beta[c] - mean * sc;
  }
}

// Gram pass: x1 = bn1+relu(y1) -> G += x1^T x1 + m1 = sum(x1); atomics into 8 G-slots
__global__ __launch_bounds__(256) void k_gram(const unsigned short* __restrict__ y1T,
                                              float* __restrict__ ws) {
  __shared__ unsigned short x1t[96 * X1TS];   // 26112B
  int t = threadIdx.x, b = blockIdx.x;
  int w = t >> 6, l = t & 63;
  int lr = l & 15, lh = l >> 4;
  int i0 = (w >> 1) * 48, j0 = (w & 1) * 48;  // each wave owns a 3x3 block of 16-tiles
  f32x4 acc[9];
  f32x4 zero4 = {0.f, 0.f, 0.f, 0.f};
#pragma unroll
  for (int q = 0; q < 9; ++q) acc[q] = zero4;
  int c = t >> 3, pg = t & 7;   // build mapping: chunk c (0..23 active), pixel group pg
  float s1v[4], t1v[4];
  if (c < 24) {
#pragma unroll
    for (int e = 0; e < 4; ++e) { s1v[e] = ws[S1Sc + c * 4 + e]; t1v[e] = ws[S1Tc + c * 4 + e]; }
  }
  float msum[4] = {0.f, 0.f, 0.f, 0.f};
  for (int it = 0; it < 16; ++it) {
    int idx = b * 16 + it;
    int k = idx >> 6, p0 = (idx & 63) << 7;
    const unsigned short* y1k = y1T + (size_t)k * P * 96;
    __syncthreads();   // previous iteration's Gram reads done
    if (c < 24) {
      int pbase = p0 + pg * 16;
      unsigned rowu[4][8];
#pragma unroll
      for (int ii = 0; ii < 8; ++ii) {
        uint4 v = *(const uint4*)(y1k + ((size_t)c * P + pbase + ii * 2) * 4);
        float x00 = fmaxf(0.f, fmaf(s1v[0], bflo(v.x), t1v[0]));
        float x10 = fmaxf(0.f, fmaf(s1v[1], bfhi(v.x), t1v[1]));
        float x20 = fmaxf(0.f, fmaf(s1v[2], bflo(v.y), t1v[2]));
        float x30 = fmaxf(0.f, fmaf(s1v[3], bfhi(v.y), t1v[3]));
        float x01 = fmaxf(0.f, fmaf(s1v[0], bflo(v.z), t1v[0]));
        float x11 = fmaxf(0.f, fmaf(s1v[1], bfhi(v.z), t1v[1]));
        float x21 = fmaxf(0.f, fmaf(s1v[2], bflo(v.w), t1v[2]));
        float x31 = fmaxf(0.f, fmaf(s1v[3], bfhi(v.w), t1v[3]));
        msum[0] += x00 + x01; msum[1] += x10 + x11;
        msum[2] += x20 + x21; msum[3] += x30 + x31;
        rowu[0][ii] = pkbf(x00, x01);
        rowu[1][ii] = pkbf(x10, x11);
        rowu[2][ii] = pkbf(x20, x21);
        rowu[3][ii] = pkbf(x30, x31);
      }
#pragma unroll
      for (int e = 0; e < 4; ++e) {
        unsigned short* dst = x1t + (c * 4 + e) * X1TS + pg * 16;
        uint4 pk0; pk0.x = rowu[e][0]; pk0.y = rowu[e][1]; pk0.z = rowu[e][2]; pk0.w = rowu[e][3];
        uint4 pk1; pk1.x = rowu[e][4]; pk1.y = rowu[e][5]; pk1.z = rowu[e][6]; pk1.w = rowu[e][7];
        *(uint4*)dst = pk0;
        *(uint4*)(dst + 8) = pk1;
      }
    }
    __syncthreads();
#pragma unroll
    for (int kk = 0; kk < 4; ++kk) {
      bf16x8 a3[3], b3[3];
#pragma unroll
      for (int a = 0; a < 3; ++a)
        a3[a] = *(const bf16x8*)(const void*)(x1t + (i0 + a * 16 + lr) * X1TS + kk * 32 + lh * 8);
#pragma unroll
      for (int bb = 0; bb < 3; ++bb)
        b3[bb] = *(const bf16x8*)(const void*)(x1t + (j0 + bb * 16 + lr) * X1TS + kk * 32 + lh * 8);
#pragma unroll
      for (int a = 0; a < 3; ++a)
#pragma unroll
        for (int bb = 0; bb < 3; ++bb)
          acc[a * 3 + bb] = __builtin_amdgcn_mfma_f32_16x16x32_bf16(a3[a], b3[bb], acc[a * 3 + bb], 0, 0, 0);
    }
  }
  // accumulate partial G into L2-resident slot copies
  {
    float* gp = ws + GSLOT + (b & (NGSLOT - 1)) * 9216;
#pragma unroll
    for (int a = 0; a < 3; ++a)
#pragma unroll
      for (int bb = 0; bb < 3; ++bb) {
        int ti = (w >> 1) * 3 + a, tj = (w & 1) * 3 + bb;
        f32x4 v = acc[a * 3 + bb];
#pragma unroll
        for (int r = 0; r < 4; ++r)
          atomicAdd(&gp[(ti * 16 + lh * 4 + r) * 96 + tj * 16 + lr], v[r]);
      }
  }
  if (c < 24) {
#pragma unroll
    for (int m = 1; m < 8; m <<= 1)
#pragma unroll
      for (int e = 0; e < 4; ++e) msum[e] += __shfl_xor(msum[e], m);
    if (pg == 0) {
      int slot = b & (NSLOT - 1);
#pragma unroll
      for (int e = 0; e < 4; ++e) atomicAdd(&ws[M1SUM + slot * C1 + c * 4 + e], msum[e]);
    }
  }
}

// fold 8 G-slots -> GOFF
__global__ void k_greduce(float* __restrict__ ws) {
  int e = blockIdx.x * 256 + threadIdx.x;   // 36 blocks
  float s = 0.f;
#pragma unroll
  for (int g = 0; g < NGSLOT; ++g) s += ws[GSLOT + g * 9216 + e];
  ws[GOFF + e] = s;
}

// stats2 from Gram: mean_o = w2_o.m1/N; E[y2^2]_o = w2_o^T G w2_o / N
__global__ __launch_bounds__(256) void k_fin2g(float* __restrict__ ws,
                                               const unsigned short* __restrict__ w2bf,
                                               const float* __restrict__ g2,
                                               const float* __restrict__ be2) {
  __shared__ float wrow[96];
  __shared__ float m1f[96];
  __shared__ float red[8];
  int o = blockIdx.x, t = threadIdx.x;
  if (t < 96) {
    wrow[t] = bfu(w2bf[o * 96 + t]);
    float s = 0.f;
    for (int sl = 0; sl < NSLOT; ++sl) s += ws[M1SUM + sl * C1 + t];
    m1f[t] = s;
  }
  __syncthreads();
  float quad = 0.f;
  for (int e = t; e < 9216; e += 256) {
    int i = e / 96, j = e - i * 96;
    quad = fmaf(wrow[i] * wrow[j], ws[GOFF + e], quad);
  }
  float msm = (t < 96) ? wrow[t] * m1f[t] : 0.f;
#pragma unroll
  for (int m = 1; m < 64; m <<= 1) { quad += __shfl_xor(quad, m); msm += __shfl_xor(msm, m); }
  if ((t & 63) == 0) { red[t >> 6] = quad; red[4 + (t >> 6)] = msm; }
  __syncthreads();
  if (t == 0) {
    float q = red[0] + red[1] + red[2] + red[3];
    float mm = red[4] + red[5] + red[6] + red[7];
    float mean = mm * (1.0f / (float)NS);
    float var = q * (1.0f / (float)NS) - mean * mean;
    float sc = g2[o] * rsqrtf(var + EPSF);
    ws[S2Sc + o] = sc;
    ws[S2Tc + o] = be2[o] - mean * sc;
  }
}

// build x1 (bn1+relu of y1T) into [128][X1S] LDS tile; y1k = k-plane base
__device__ __forceinline__ void build_x1(const unsigned short* __restrict__ y1k,
                                         const float* __restrict__ ws,
                                         unsigned short* lds, int p0, int t) {
  int s = t >> 1, hh = t & 1;
  int p = p0 + s;
  const float* s1p = ws + S1Sc;
  const float* t1p = ws + S1Tc;
  unsigned short* base = lds + s * X1S + hh * 48;
#pragma unroll
  for (int i2 = 0; i2 < 6; ++i2) {
    int c0 = hh * 12 + i2 * 2;
    uint2 va = *(const uint2*)(y1k + ((size_t)c0 * P + p) * 4);
    uint2 vb = *(const uint2*)(y1k + ((size_t)(c0 + 1) * P + p) * 4);
    int cb = c0 * 4;
    float x0 = fmaxf(0.f, fmaf(s1p[cb + 0], bflo(va.x), t1p[cb + 0]));
    float x1 = fmaxf(0.f, fmaf(s1p[cb + 1], bfhi(va.x), t1p[cb + 1]));
    float x2 = fmaxf(0.f, fmaf(s1p[cb + 2], bflo(va.y), t1p[cb + 2]));
    float x3 = fmaxf(0.f, fmaf(s1p[cb + 3], bfhi(va.y), t1p[cb + 3]));
    float x4 = fmaxf(0.f, fmaf(s1p[cb + 4], bflo(vb.x), t1p[cb + 4]));
    float x5 = fmaxf(0.f, fmaf(s1p[cb + 5], bfhi(vb.x), t1p[cb + 5]));
    float x6 = fmaxf(0.f, fmaf(s1p[cb + 6], bflo(vb.y), t1p[cb + 6]));
    float x7 = fmaxf(0.f, fmaf(s1p[cb + 7], bfhi(vb.y), t1p[cb + 7]));
    uint4 pk;
    pk.x = pkbf(x0, x1); pk.y = pkbf(x2, x3); pk.z = pkbf(x4, x5); pk.w = pkbf(x6, x7);
    *(uint4*)(base + i2 * 8) = pk;
  }
}

// fused layers 2+3; y3 stored transposed [chunk4][n][4] directly from accumulators
__global__ __launch_bounds__(256) void k_l23(const unsigned short* __restrict__ y1T,
                                             float* __restrict__ ws,
                                             const unsigned short* __restrict__ w2bf,
                                             const unsigned short* __restrict__ w3bf,
                                             unsigned short* __restrict__ y3T) {
  __shared__ unsigned short ldss[128 * X1S];
  int t = threadIdx.x, b = blockIdx.x;
  int k = b >> 6, p0 = (b & 63) << 7;
  size_t n0 = (size_t)k * P + p0;
  int slot = b & (NSLOT - 1);
  const unsigned short* y1k = y1T + (size_t)k * P * 96;
  build_x1(y1k, ws, ldss, p0, t);
  __syncthreads();
  int l = t & 63, wv = t >> 6;
  int o0w = wv * 32;
  int lr = l & 15, lh = l >> 4;
  bf16x8 af[2][3];
#pragma unroll
  for (int m = 0; m < 2; ++m)
#pragma unroll
    for (int kk = 0; kk < 3; ++kk)
      af[m][kk] = *(const bf16x8*)(const void*)(w2bf + (size_t)(o0w + m * 16 + lr) * 96 + kk * 32 + lh * 8);
  f32x4 acc[2][8];
  f32x4 zero4 = {0.f, 0.f, 0.f, 0.f};
#pragma unroll
  for (int m = 0; m < 2; ++m)
#pragma unroll
    for (int n = 0; n < 8; ++n) acc[m][n] = zero4;
#pragma unroll
  for (int kk = 0; kk < 3; ++kk)
#pragma unroll
    for (int n = 0; n < 8; ++n) {
      bf16x8 bfr = *(const bf16x8*)(const void*)(ldss + (n * 16 + lr) * X1S + kk * 32 + lh * 8);
      acc[0][n] = __builtin_amdgcn_mfma_f32_16x16x32_bf16(af[0][kk], bfr, acc[0][n], 0, 0, 0);
      acc[1][n] = __builtin_amdgcn_mfma_f32_16x16x32_bf16(af[1][kk], bfr, acc[1][n], 0, 0, 0);
    }
  float s2v[2][4], t2v[2][4];
#pragma unroll
  for (int m = 0; m < 2; ++m)
#pragma unroll
    for (int r = 0; r < 4; ++r) {
      int cc = o0w + m * 16 + lh * 4 + r;
      s2v[m][r] = ws[S2Sc + cc];
      t2v[m][r] = ws[S2Tc + cc];
    }
  int o2 = wv * 16;
  int ch4 = wv * 4 + lh;   // y3T chunk this lane writes
  bf16x8 af2[4];
#pragma unroll
  for (int kk = 0; kk < 4; ++kk)
    af2[kk] = *(const bf16x8*)(const void*)(w3bf + (size_t)(o2 + lr) * 128 + kk * 32 + lh * 8);
  unsigned short* x2s = ldss;               // [64][X2S] = 17408B (aliases x1)
  float ssum[4] = {0.f, 0.f, 0.f, 0.f}, sssq[4] = {0.f, 0.f, 0.f, 0.f};
#pragma unroll
  for (int h = 0; h < 2; ++h) {
    __syncthreads();   // h0: MFMA1 x1-reads done; h1: MFMA2(h0) x2-reads done
#pragma unroll
    for (int m = 0; m < 2; ++m)
#pragma unroll
      for (int n2 = 0; n2 < 4; ++n2) {
        f32x4 v = acc[m][h * 4 + n2];
        float x0 = fmaxf(0.f, fmaf(s2v[m][0], v[0], t2v[m][0]));
        float x1v = fmaxf(0.f, fmaf(s2v[m][1], v[1], t2v[m][1]));
        float x2v = fmaxf(0.f, fmaf(s2v[m][2], v[2], t2v[m][2]));
        float x3 = fmaxf(0.f, fmaf(s2v[m][3], v[3], t2v[m][3]));
        uint2 pk;
        pk.x = pkbf(x0, x1v);
        pk.y = pkbf(x2v, x3);
        *(uint2*)(x2s + (n2 * 16 + lr) * X2S + o0w + m * 16 + lh * 4) = pk;
      }
    __syncthreads();
    f32x4 acc2[4];
#pragma unroll
    for (int n2 = 0; n2 < 4; ++n2) acc2[n2] = zero4;
#pragma unroll
    for (int kk = 0; kk < 4; ++kk)
#pragma unroll
      for (int n2 = 0; n2 < 4; ++n2) {
        bf16x8 bfr = *(const bf16x8*)(const void*)(x2s + (n2 * 16 + lr) * X2S + kk * 32 + lh * 8);
        acc2[n2] = __builtin_amdgcn_mfma_f32_16x16x32_bf16(af2[kk], bfr, acc2[n2], 0, 0, 0);
      }
    // stats3 + direct transposed store
#pragma unroll
    for (int n2 = 0; n2 < 4; ++n2) {
      f32x4 v = acc2[n2];
#pragma unroll
      for (int r = 0; r < 4; ++r) { float x = v[r]; ssum[r] += x; sssq[r] = fmaf(x, x, sssq[r]); }
      uint2 pk;
      pk.x = pkbf(v[0], v[1]);
      pk.y = pkbf(v[2], v[3]);
      size_t n = n0 + h * 64 + n2 * 16 + lr;
      *(uint2*)(y3T + ((size_t)ch4 * NS + n) * 4) = pk;
    }
  }
#pragma unroll
  for (int msk = 1; msk < 16; msk <<= 1)
#pragma unroll
    for (int i = 0; i < 4; ++i) { ssum[i] += __shfl_xor(ssum[i], msk); sssq[i] += __shfl_xor(sssq[i], msk); }
  if (lr == 0) {
#pragma unroll
    for (int r = 0; r < 4; ++r) {
      int o = o2 + lh * 4 + r;
      atomicAdd(&ws[S3SUM + slot * C3 + o], ssum[r]);
      atomicAdd(&ws[S3SSQ + slot * C3 + o], sssq[r]);
    }
  }
}

// layer4: cost = w4 . relu(bn3(y3T)) + b4
__global__ __launch_bounds__(256) void k_layer4(const unsigned short* __restrict__ y3T,
                                                float* __restrict__ ws,
                                                const float* __restrict__ w4,
                                                const float* __restrict__ b4) {
  size_t n = (size_t)blockIdx.x * 256 + threadIdx.x;
  const float* s3p = ws + S3Sc;
  const float* t3p = ws + S3Tc;
  float acc = 0.f;
#pragma unroll
  for (int c16 = 0; c16 < 16; ++c16) {
    uint2 v = *(const uint2*)(y3T + ((size_t)c16 * NS + n) * 4);
    int c = c16 * 4;
    acc += fmaxf(0.f, fmaf(s3p[c + 0], bflo(v.x), t3p[c + 0])) * w4[c + 0];
    acc += fmaxf(0.f, fmaf(s3p[c + 1], bfhi(v.x), t3p[c + 1])) * w4[c + 1];
    acc += fmaxf(0.f, fmaf(s3p[c + 2], bflo(v.y), t3p[c + 2])) * w4[c + 2];
    acc += fmaxf(0.f, fmaf(s3p[c + 3], bfhi(v.y), t3p[c + 3])) * w4[c + 3];
  }
  ws[COST_OFF + n] = acc + b4[0];
}

// DAP
__global__ __launch_bounds__(256) void k_dap(const float* __restrict__ ws,
                                             const float* __restrict__ wdap,
                                             float* __restrict__ out) {
  __shared__ float wd[DD * DD];
  int t = threadIdx.x;
  for (int i = t; i < DD * DD; i += 256) wd[i] = wdap[i];
  __syncthreads();
  int p = blockIdx.x * 32 + (t & 31);
  int lg = t >> 5;
  const float* cost = ws + COST_OFF;
  float cr[81];
#pragma unroll
  for (int kk = 0; kk < 81; ++kk) cr[kk] = cost[kk * P + p];
  for (int l = lg; l < 81; l += 8) {
    float acc = 0.f;
#pragma unroll
    for (int kk = 0; kk < 81; ++kk) acc = fmaf(wd[l * 81 + kk], cr[kk], acc);
    out[(size_t)l * P + p] = acc;
  }
}

__global__ void k_marker(float* out) { out[0] = 1.0e30f; }

extern "C" void kernel_launch(void* const* d_in, const int* in_sizes, int n_in,
                              void* d_out, int out_size, void* d_ws, size_t ws_size,
                              hipStream_t stream) {
  const float* f1 = (const float*)d_in[0];
  const float* f2 = (const float*)d_in[1];
  const float* coords = (const float*)d_in[2];
  const float* w1 = (const float*)d_in[3];
  const float* g1 = (const float*)d_in[4];
  const float* be1 = (const float*)d_in[5];
  const float* w2 = (const float*)d_in[6];
  const float* g2 = (const float*)d_in[7];
  const float* be2 = (const float*)d_in[8];
  const float* w3 = (const float*)d_in[9];
  const float* g3 = (const float*)d_in[10];
  const float* be3 = (const float*)d_in[11];
  const float* w4 = (const float*)d_in[12];
  const float* b4 = (const float*)d_in[13];
  const float* wdap = (const float*)d_in[14];
  float* out = (float*)d_out;
  float* ws = (float*)d_ws;

  if (ws_size < WS_NEEDED) {
    k_marker<<<1, 1, 0, stream>>>(out);
    return;
  }
  unsigned short* aT = (unsigned short*)((char*)d_ws + A_BYTE);
  unsigned short* gT = (unsigned short*)((char*)d_ws + G_BYTE);
  unsigned short* w2bf = (unsigned short*)((char*)d_ws + W2BF_BYTE);
  unsigned short* w3bf = (unsigned short*)((char*)d_ws + W3BF_BYTE);
  unsigned short* y1T = (unsigned short*)((char*)d_ws + Y1_BYTE);
  unsigned short* y3T = (unsigned short*)((char*)d_ws + Y3_BYTE);

  hipMemsetAsync(d_ws, 0, (size_t)STATS_ZERO_FLOATS * 4, stream);
  k_prep<<<128, 256, 0, stream>>>(f1, f2, w1, aT, gT);
  k_wprep<<<80, 256, 0, stream>>>(w2, w3, w2bf, w3bf);
  k_sample<<<768, 256, 0, stream>>>(coords, ws, aT, gT, y1T);
  k_finalize<<<1, 128, 0, stream>>>(ws, S1SUM, S1SSQ, g1, be1, S1Sc, S1Tc, C1);
  k_gram<<<NGB, 256, 0, stream>>>(y1T, ws);
  k_greduce<<<36, 256, 0, stream>>>(ws);
  k_fin2g<<<128, 256, 0, stream>>>(ws, w2bf, g2, be2);
  k_l23<<<5184, 256, 0, stream>>>(y1T, ws, w2bf, w3bf, y3T);
  k_finalize<<<1, 128, 0, stream>>>(ws, S3SUM, S3SSQ, g3, be3, S3Sc, S3Tc, C3);
  k_layer4<<<2592, 256, 0, stream>>>(y3T, ws, w4, b4);
  k_dap<<<256, 256, 0, stream>>>(ws, wdap, out);
}